// Round 15
// baseline (1908.236 us; speedup 1.0000x reference)
//
#include <hip/hip_runtime.h>

// Problem constants
#define BB 16
#define NN 2048
#define KK 20

#define NEG_INF (-3.402823466e+38f)
#define DNEG (-1.0e300)

// ---------------------------------------------------------------------------
// Weight prep (f32 transposes, used by conv3): offsets in wb:
//   w5lo[64][64]@16768 w5hi[64][64]@20864
// ---------------------------------------------------------------------------
__global__ void prep_wf(const float* __restrict__ w1, const float* __restrict__ w2,
                        const float* __restrict__ w3, const float* __restrict__ w4,
                        const float* __restrict__ w5, float* __restrict__ wb) {
    int t = threadIdx.x;
    for (int i = t; i < 4096; i += 256) {
        int a = i >> 6, q = i & 63;
        wb[16768 + i] = w5[q * 128 + a];       // w5lo[c=a][o=q]
        wb[20864 + i] = w5[q * 128 + 64 + a];  // w5hi[c=a][o=q]
    }
}

// ---------------------------------------------------------------------------
// Composed fp64 weights:
//  M1[3][64]@0  Mh1[3][64]@192  g01[64]@384
//  M2[64][64]@448  Mh2[64][64]@4544  g02[64]@8640     (8704 doubles)
// ---------------------------------------------------------------------------
__global__ void prep_cmp(const float* __restrict__ w1, const float* __restrict__ b1,
                         const float* __restrict__ w2, const float* __restrict__ b2,
                         const float* __restrict__ w3, const float* __restrict__ b3,
                         const float* __restrict__ w4, const float* __restrict__ b4,
                         double* __restrict__ wd2) {
    int t = threadIdx.x;
    for (int i = t; i < 192; i += 256) {
        int c = i >> 6, o = i & 63;
        double s = 0, sh = 0;
        for (int j = 0; j < 64; ++j) {
            double w2v = (double)w2[o * 64 + j];
            s  = fma(w2v, (double)w1[j * 6 + c], s);
            sh = fma(w2v, (double)w1[j * 6 + 3 + c], sh);
        }
        wd2[i] = s;
        wd2[192 + i] = sh;
    }
    for (int i = t; i < 64; i += 256) {
        double s = (double)b2[i];
        for (int j = 0; j < 64; ++j)
            s = fma((double)w2[i * 64 + j], (double)b1[j], s);
        wd2[384 + i] = s;
        double s2 = (double)b4[i];
        for (int j = 0; j < 64; ++j)
            s2 = fma((double)w4[i * 64 + j], (double)b3[j], s2);
        wd2[8640 + i] = s2;
    }
    for (int i = t; i < 4096; i += 256) {
        int c = i >> 6, o = i & 63;
        double s = 0, sh = 0;
        for (int j = 0; j < 64; ++j) {
            double w4v = (double)w4[o * 64 + j];
            s  = fma(w4v, (double)w3[j * 128 + c], s);
            sh = fma(w4v, (double)w3[j * 128 + 64 + c], sh);
        }
        wd2[448 + i] = s;    // M2[c][o]
        wd2[4544 + i] = sh;  // Mh2[c][o]
    }
}

// ---------------------------------------------------------------------------
// Top-20 selection over 2048 f32 candidates in a per-wave LDS row.
// FROZEN: stable ties -> lowest index.
// ---------------------------------------------------------------------------
__device__ __forceinline__ void top2_upd(float v, int g, float& av, int& ai,
                                         float& bv, int& bi) {
    bool gta = v > av;
    bool gtb = v > bv;
    float nbv = gta ? av : (gtb ? v : bv);
    int   nbi = gta ? ai : (gtb ? g : bi);
    av = gta ? v : av;
    ai = gta ? g : ai;
    bv = nbv;
    bi = nbi;
}

__device__ __forceinline__ void topk20_run(float* vrow, int lane, float av, int ai,
                                           float bv, int bi, int* outp) {
    int myout = 0;
    #pragma unroll 1
    for (int it = 0; it < 20; ++it) {
        float wv = av;
        #pragma unroll
        for (int d = 32; d; d >>= 1) wv = fmaxf(wv, __shfl_xor(wv, d));
        unsigned long long bal = __ballot(av == wv);
        int widx;
        if (__popcll(bal) == 1) {
            widx = __shfl(ai, __ffsll(bal) - 1);
        } else {  // exact tie across lanes: lowest global index wins
            int tt = (av == wv) ? ai : 0x7fffffff;
            #pragma unroll
            for (int d = 32; d; d >>= 1) tt = min(tt, __shfl_xor(tt, d));
            widx = tt;
        }
        if (lane == it) myout = widx;
        if (lane == 0) vrow[widx] = NEG_INF;   // remove winner
        if (ai == widx) { av = bv; ai = bi; bv = NEG_INF; bi = 0x7fffffff; }
        if (av == NEG_INF) {                   // rare: lane's top-2 exhausted
            ai = 0x7fffffff; bv = NEG_INF; bi = 0x7fffffff;
            #pragma unroll 1
            for (int s = 0; s < 32; ++s) {
                int col = s * 64 + lane;
                top2_upd(vrow[col], col, av, ai, bv, bi);
            }
        }
    }
    if (lane < 20) outp[lane] = myout;
}

// ---------------------------------------------------------------------------
// knn1: numpy-f32 mirror, FROZEN arithmetic.
// ---------------------------------------------------------------------------
__global__ void knn1_k(const float* __restrict__ x, int* __restrict__ idx) {
    __shared__ float vlds[2][2048];
    int lane = threadIdx.x & 63, w = threadIdx.x >> 6;
    int b = blockIdx.y, r = blockIdx.x * 2 + w;
    const float* xb = x + (size_t)b * 3 * NN;
    float rx = xb[r], ry = xb[NN + r], rz = xb[2 * NN + r];
    float xxi = __fadd_rn(__fadd_rn(__fmul_rn(rx, rx), __fmul_rn(ry, ry)),
                          __fmul_rn(rz, rz));
    float* vrow = vlds[w];
    float av = NEG_INF, bv = NEG_INF;
    int ai = 0x7fffffff, bi = 0x7fffffff;
    #pragma unroll 1
    for (int s = 0; s < 32; ++s) {
        int col = s * 64 + lane;
        float cx = xb[col], cy = xb[NN + col], cz = xb[2 * NN + col];
        float xxj = __fadd_rn(__fadd_rn(__fmul_rn(cx, cx), __fmul_rn(cy, cy)),
                              __fmul_rn(cz, cz));
        float dot = fmaf(rz, cz, fmaf(ry, cy, __fmul_rn(rx, cx)));
        float inner = __fmul_rn(-2.f, dot);
        float t1 = __fsub_rn(-xxj, inner);
        float nd = __fsub_rn(t1, xxi);
        vrow[col] = nd;
        top2_upd(nd, col, av, ai, bv, bi);
    }
    topk20_run(vrow, lane, av, ai, bv, bi, idx + ((size_t)b * NN + r) * KK);
}

// xx for a 64-channel slice. FROZEN.
__global__ void norms23_k(const float* __restrict__ x123t, int coff,
                          float* __restrict__ nrm) {
    int t = blockIdx.x * 256 + threadIdx.x;   // 32768 points
    const float* r = x123t + (size_t)t * 192 + coff;
    float acc = 0.f;
    #pragma unroll 1
    for (int c = 0; c < 64; ++c)
        acc = __fadd_rn(acc, __fmul_rn(r[c], r[c]));
    nrm[t] = acc;
}

// ---------------------------------------------------------------------------
// pd GEMM (knn2/3 distances): 64x64 output tile per block, K=64 single tile.
// Each acc[i][j] gets one fmaf per ascending c  -> FROZEN chain preserved.
// ---------------------------------------------------------------------------
__global__ __launch_bounds__(256) void gemm_pd_k(const float* __restrict__ dout,
        int coff, const float* __restrict__ nrm, float* __restrict__ pd, int b0) {
    __shared__ float As[64][68];
    __shared__ float Bs[64][68];
    int b = b0 + blockIdx.z;
    int rb = blockIdx.y * 64, cb = blockIdx.x * 64;
    const float* doutc = dout + (size_t)(b * 192 + coff) * NN;
    int tid = threadIdx.x;
    int cq = tid >> 4, qd = (tid & 15) * 4;
    #pragma unroll
    for (int cc = 0; cc < 64; cc += 16) {
        float4 a = *(const float4*)(doutc + (size_t)(cc + cq) * NN + rb + qd);
        As[cc + cq][qd + 0] = a.x; As[cc + cq][qd + 1] = a.y;
        As[cc + cq][qd + 2] = a.z; As[cc + cq][qd + 3] = a.w;
        float4 bv = *(const float4*)(doutc + (size_t)(cc + cq) * NN + cb + qd);
        Bs[cc + cq][qd + 0] = bv.x; Bs[cc + cq][qd + 1] = bv.y;
        Bs[cc + cq][qd + 2] = bv.z; Bs[cc + cq][qd + 3] = bv.w;
    }
    __syncthreads();
    int tx = tid & 15, ty = tid >> 4;
    float acc[4][4];
    #pragma unroll
    for (int i = 0; i < 4; ++i)
        #pragma unroll
        for (int j = 0; j < 4; ++j) acc[i][j] = 0.f;
    #pragma unroll 4
    for (int c = 0; c < 64; ++c) {
        float4 av4 = *(const float4*)&As[c][ty * 4];
        float4 bv4 = *(const float4*)&Bs[c][tx * 4];
        float aa[4] = {av4.x, av4.y, av4.z, av4.w};
        float bb[4] = {bv4.x, bv4.y, bv4.z, bv4.w};
        #pragma unroll
        for (int i = 0; i < 4; ++i)
            #pragma unroll
            for (int j = 0; j < 4; ++j)
                acc[i][j] = fmaf(aa[i], bb[j], acc[i][j]);  // ascending-c chain
    }
    const float* nb_ = nrm + (size_t)b * NN;
    #pragma unroll
    for (int i = 0; i < 4; ++i) {
        int r = rb + ty * 4 + i;
        float xxi = nb_[r];
        float4 o4;
        float* o = (float*)&o4;
        #pragma unroll
        for (int j = 0; j < 4; ++j) {
            float xxj = nb_[cb + tx * 4 + j];
            float inner = __fmul_rn(-2.f, acc[i][j]);
            float t1 = __fsub_rn(-xxj, inner);
            o[j] = __fsub_rn(t1, xxi);
        }
        *(float4*)(pd + ((size_t)blockIdx.z * NN + r) * NN + cb + tx * 4) = o4;
    }
}

// selection from materialized pd chunk (same frozen helpers as knn1)
__global__ void select_k(const float* __restrict__ pd, int* __restrict__ idx, int b0) {
    __shared__ float vlds[4][2048];
    int lane = threadIdx.x & 63, w = threadIdx.x >> 6;
    int bb = blockIdx.y, r = blockIdx.x * 4 + w;
    const float* row = pd + ((size_t)bb * NN + r) * NN;
    float* vrow = vlds[w];
    float av = NEG_INF, bv = NEG_INF;
    int ai = 0x7fffffff, bi = 0x7fffffff;
    #pragma unroll 1
    for (int s = 0; s < 32; ++s) {
        int col = s * 64 + lane;
        float v = row[col];
        vrow[col] = v;
        top2_upd(v, col, av, ai, bv, bi);
    }
    topk20_run(vrow, lane, av, ai, bv, bi, idx + ((size_t)(b0 + bb) * NN + r) * KK);
}

// ---------------------------------------------------------------------------
// EdgeConv blocks with composed fp64 weights, neighbor prefetch,
// and 2 points per wave (halves LDS weight-read traffic per FMA).
// ---------------------------------------------------------------------------
__global__ __launch_bounds__(256) void conv1_k(const float* __restrict__ x,
        const int* __restrict__ idxb, const double* __restrict__ wd2,
        float* __restrict__ dout, float* __restrict__ x123t) {
    int tid = threadIdx.x, lane = tid & 63, w = tid >> 6;
    int p = blockIdx.x * 4 + w, b = p >> 11, n = p & 2047;
    const float* xb = x + (size_t)b * 3 * NN;
    double c0 = (double)xb[n], c1 = (double)xb[NN + n], c2 = (double)xb[2 * NN + n];
    double m10 = wd2[lane], m11 = wd2[64 + lane], m12 = wd2[128 + lane];
    double g = wd2[384 + lane];
    g = fma(wd2[192 + lane], c0, g);
    g = fma(wd2[256 + lane], c1, g);
    g = fma(wd2[320 + lane], c2, g);
    const int* ip = idxb + (size_t)p * KK;
    int nb = ip[0];
    float f0 = xb[nb], f1 = xb[NN + nb], f2 = xb[2 * NN + nb];
    double m = DNEG;
    #pragma unroll 1
    for (int kk = 0; kk < KK; ++kk) {
        double d0 = (double)f0 - c0, d1 = (double)f1 - c1, d2 = (double)f2 - c2;
        if (kk < KK - 1) {
            int nb2 = ip[kk + 1];
            f0 = xb[nb2]; f1 = xb[NN + nb2]; f2 = xb[2 * NN + nb2];
        }
        double h = g;
        h = fma(m10, d0, h);
        h = fma(m11, d1, h);
        h = fma(m12, d2, h);
        m = fmax(m, h);
    }
    dout[((size_t)b * 192 + lane) * NN + n] = (float)m;
    x123t[((size_t)b * NN + n) * 192 + lane] = (float)m;
}

__global__ __launch_bounds__(256) void conv2_k(const float* __restrict__ x123t,
        const int* __restrict__ idxb, const double* __restrict__ wd2,
        float* __restrict__ dout, float* __restrict__ x123t_o) {
    __shared__ double M2s[4096];      // 32 KB
    __shared__ double dbs[4][2][64];  // 4 KB
    int tid = threadIdx.x, lane = tid & 63, w = tid >> 6;
    for (int i = tid; i < 4096; i += 256) M2s[i] = wd2[448 + i];
    __syncthreads();
    int p0 = blockIdx.x * 8 + w * 2, b = p0 >> 11;
    int n0 = p0 & 2047, n1 = n0 + 1;
    const float* base = x123t + (size_t)b * NN * 192;
    double ctr0 = (double)base[(size_t)n0 * 192 + lane];
    double ctr1 = (double)base[(size_t)n1 * 192 + lane];
    dbs[w][0][lane] = ctr0;
    dbs[w][1][lane] = ctr1;
    double g0 = wd2[8640 + lane], g1 = g0;
    #pragma unroll 4
    for (int c = 0; c < 64; ++c) {
        double mh = wd2[4544 + c * 64 + lane];
        g0 = fma(mh, dbs[w][0][c], g0);
        g1 = fma(mh, dbs[w][1][c], g1);
    }
    const int* ip0 = idxb + (size_t)p0 * KK;
    const int* ip1 = idxb + (size_t)(p0 + 1) * KK;
    float nbreg0 = base[(size_t)ip0[0] * 192 + lane];
    float nbreg1 = base[(size_t)ip1[0] * 192 + lane];
    double m0 = DNEG, m1 = DNEG;
    #pragma unroll 1
    for (int kk = 0; kk < KK; ++kk) {
        dbs[w][0][lane] = (double)nbreg0 - ctr0;
        dbs[w][1][lane] = (double)nbreg1 - ctr1;
        if (kk < KK - 1) {
            nbreg0 = base[(size_t)ip0[kk + 1] * 192 + lane];
            nbreg1 = base[(size_t)ip1[kk + 1] * 192 + lane];
        }
        double a0 = g0, a1 = 0, a2 = 0, a3 = 0;
        double q0 = g1, q1 = 0, q2 = 0, q3 = 0;
        #pragma unroll
        for (int c = 0; c < 64; c += 4) {
            double m2v0 = M2s[(c + 0) * 64 + lane];
            double m2v1 = M2s[(c + 1) * 64 + lane];
            double m2v2 = M2s[(c + 2) * 64 + lane];
            double m2v3 = M2s[(c + 3) * 64 + lane];
            a0 = fma(m2v0, dbs[w][0][c + 0], a0);
            a1 = fma(m2v1, dbs[w][0][c + 1], a1);
            a2 = fma(m2v2, dbs[w][0][c + 2], a2);
            a3 = fma(m2v3, dbs[w][0][c + 3], a3);
            q0 = fma(m2v0, dbs[w][1][c + 0], q0);
            q1 = fma(m2v1, dbs[w][1][c + 1], q1);
            q2 = fma(m2v2, dbs[w][1][c + 2], q2);
            q3 = fma(m2v3, dbs[w][1][c + 3], q3);
        }
        m0 = fmax(m0, (a0 + a1) + (a2 + a3));
        m1 = fmax(m1, (q0 + q1) + (q2 + q3));
    }
    dout[((size_t)b * 192 + 64 + lane) * NN + n0] = (float)m0;
    dout[((size_t)b * 192 + 64 + lane) * NN + n1] = (float)m1;
    x123t_o[((size_t)b * NN + n0) * 192 + 64 + lane] = (float)m0;
    x123t_o[((size_t)b * NN + n1) * 192 + 64 + lane] = (float)m1;
}

__global__ __launch_bounds__(256) void conv3_k(const float* __restrict__ x123t,
        const int* __restrict__ idxb, const float* __restrict__ wb,
        const float* __restrict__ b5,
        float* __restrict__ dout, float* __restrict__ x123t_o) {
    __shared__ float w5s[4096];       // 16 KB
    __shared__ double dbs[4][2][64];  // 4 KB
    int tid = threadIdx.x, lane = tid & 63, w = tid >> 6;
    for (int i = tid; i < 4096; i += 256) w5s[i] = wb[16768 + i];
    __syncthreads();
    int p0 = blockIdx.x * 8 + w * 2, b = p0 >> 11;
    int n0 = p0 & 2047, n1 = n0 + 1;
    const float* base = x123t + (size_t)b * NN * 192 + 64;  // x2 slice
    double ctr0 = (double)base[(size_t)n0 * 192 + lane];
    double ctr1 = (double)base[(size_t)n1 * 192 + lane];
    dbs[w][0][lane] = ctr0;
    dbs[w][1][lane] = ctr1;
    double g0a = (double)b5[lane], g1a = 0, g2a = 0, g3a = 0;
    double h0a = g0a, h1b = 0, h2b = 0, h3b = 0;
    #pragma unroll 4
    for (int c = 0; c < 64; c += 4) {
        double w0 = (double)wb[20864 + (c + 0) * 64 + lane];
        double w1v = (double)wb[20864 + (c + 1) * 64 + lane];
        double w2v = (double)wb[20864 + (c + 2) * 64 + lane];
        double w3v = (double)wb[20864 + (c + 3) * 64 + lane];
        g0a = fma(w0, dbs[w][0][c + 0], g0a);
        g1a = fma(w1v, dbs[w][0][c + 1], g1a);
        g2a = fma(w2v, dbs[w][0][c + 2], g2a);
        g3a = fma(w3v, dbs[w][0][c + 3], g3a);
        h0a = fma(w0, dbs[w][1][c + 0], h0a);
        h1b = fma(w1v, dbs[w][1][c + 1], h1b);
        h2b = fma(w2v, dbs[w][1][c + 2], h2b);
        h3b = fma(w3v, dbs[w][1][c + 3], h3b);
    }
    double hc0 = (g0a + g1a) + (g2a + g3a);
    double hc1 = (h0a + h1b) + (h2b + h3b);
    const int* ip0 = idxb + (size_t)p0 * KK;
    const int* ip1 = idxb + (size_t)(p0 + 1) * KK;
    float nbreg0 = base[(size_t)ip0[0] * 192 + lane];
    float nbreg1 = base[(size_t)ip1[0] * 192 + lane];
    double m0 = DNEG, m1 = DNEG;
    #pragma unroll 1
    for (int kk = 0; kk < KK; ++kk) {
        dbs[w][0][lane] = (double)nbreg0 - ctr0;
        dbs[w][1][lane] = (double)nbreg1 - ctr1;
        if (kk < KK - 1) {
            nbreg0 = base[(size_t)ip0[kk + 1] * 192 + lane];
            nbreg1 = base[(size_t)ip1[kk + 1] * 192 + lane];
        }
        double a0 = hc0, a1 = 0, a2 = 0, a3 = 0;
        double q0 = hc1, q1 = 0, q2 = 0, q3 = 0;
        #pragma unroll
        for (int c = 0; c < 64; c += 4) {
            double w0 = (double)w5s[(c + 0) * 64 + lane];
            double w1v = (double)w5s[(c + 1) * 64 + lane];
            double w2v = (double)w5s[(c + 2) * 64 + lane];
            double w3v = (double)w5s[(c + 3) * 64 + lane];
            a0 = fma(w0, dbs[w][0][c + 0], a0);
            a1 = fma(w1v, dbs[w][0][c + 1], a1);
            a2 = fma(w2v, dbs[w][0][c + 2], a2);
            a3 = fma(w3v, dbs[w][0][c + 3], a3);
            q0 = fma(w0, dbs[w][1][c + 0], q0);
            q1 = fma(w1v, dbs[w][1][c + 1], q1);
            q2 = fma(w2v, dbs[w][1][c + 2], q2);
            q3 = fma(w3v, dbs[w][1][c + 3], q3);
        }
        m0 = fmax(m0, (a0 + a1) + (a2 + a3));
        m1 = fmax(m1, (q0 + q1) + (q2 + q3));
    }
    dout[((size_t)b * 192 + 128 + lane) * NN + n0] = (float)m0;
    dout[((size_t)b * 192 + 128 + lane) * NN + n1] = (float)m1;
    x123t_o[((size_t)b * NN + n0) * 192 + 128 + lane] = (float)m0;
    x123t_o[((size_t)b * NN + n1) * 192 + 128 + lane] = (float)m1;
}

// ---------------------------------------------------------------------------
// Final conv1d (1024x192) as LDS-tiled f32 GEMM, 64o x 64n per block, KC=32.
// ---------------------------------------------------------------------------
#define KC 32
__global__ __launch_bounds__(256) void w6_k(const float* __restrict__ x123t,
                                            const float* __restrict__ w6,
                                            float* __restrict__ partial6) {
    __shared__ float xs[KC][68];
    __shared__ float wsb[KC][68];
    __shared__ float red[64][17];
    int tid = threadIdx.x;
    int ntile = blockIdx.x & 31, ot = (blockIdx.x >> 5) & 15, b = blockIdx.x >> 9;
    int n0 = ntile * 64, o0 = ot * 64;
    int ln = tid >> 2, lc = (tid & 3) * 8;
    const float* xrow = x123t + ((size_t)b * NN + n0 + ln) * 192 + lc;
    const float* wrow = w6 + (size_t)(o0 + ln) * 192 + lc;
    float acc[4][4];
    #pragma unroll
    for (int i = 0; i < 4; ++i)
        #pragma unroll
        for (int j = 0; j < 4; ++j) acc[i][j] = 0.f;
    int to = tid & 15, tn = tid >> 4;
    for (int cc = 0; cc < 192; cc += KC) {
        float4 xa = *(const float4*)(xrow + cc);
        float4 xb4 = *(const float4*)(xrow + cc + 4);
        float4 wa = *(const float4*)(wrow + cc);
        float4 wb4 = *(const float4*)(wrow + cc + 4);
        __syncthreads();
        xs[lc + 0][ln] = xa.x; xs[lc + 1][ln] = xa.y;
        xs[lc + 2][ln] = xa.z; xs[lc + 3][ln] = xa.w;
        xs[lc + 4][ln] = xb4.x; xs[lc + 5][ln] = xb4.y;
        xs[lc + 6][ln] = xb4.z; xs[lc + 7][ln] = xb4.w;
        wsb[lc + 0][ln] = wa.x; wsb[lc + 1][ln] = wa.y;
        wsb[lc + 2][ln] = wa.z; wsb[lc + 3][ln] = wa.w;
        wsb[lc + 4][ln] = wb4.x; wsb[lc + 5][ln] = wb4.y;
        wsb[lc + 6][ln] = wb4.z; wsb[lc + 7][ln] = wb4.w;
        __syncthreads();
        #pragma unroll
        for (int k = 0; k < KC; ++k) {
            float4 wv = *(const float4*)&wsb[k][to * 4];
            float4 xv = *(const float4*)&xs[k][tn * 4];
            float wr[4] = {wv.x, wv.y, wv.z, wv.w};
            float xr[4] = {xv.x, xv.y, xv.z, xv.w};
            #pragma unroll
            for (int i = 0; i < 4; ++i)
                #pragma unroll
                for (int j = 0; j < 4; ++j)
                    acc[i][j] = fmaf(wr[i], xr[j], acc[i][j]);
        }
    }
    #pragma unroll
    for (int i = 0; i < 4; ++i) {
        float mm = fmaxf(fmaxf(acc[i][0], acc[i][1]), fmaxf(acc[i][2], acc[i][3]));
        red[to * 4 + i][tn] = mm;
    }
    __syncthreads();
    if (tid < 64) {
        float mm = red[tid][0];
        #pragma unroll
        for (int t = 1; t < 16; ++t) mm = fmaxf(mm, red[tid][t]);
        partial6[((size_t)b * 1024 + o0 + tid) * 32 + ntile] = mm;
    }
}

__global__ void final_k(const float* __restrict__ partial6, const float* __restrict__ b6,
                        float* __restrict__ dout) {
    int t = blockIdx.x * 256 + threadIdx.x;  // < 16*1024
    int o = t & 1023;
    float m = NEG_INF;
    #pragma unroll 1
    for (int nt = 0; nt < 32; ++nt) m = fmaxf(m, partial6[(size_t)t * 32 + nt]);
    dout[(size_t)BB * 192 * NN + t] = m + b6[o];
}

// ---------------------------------------------------------------------------
extern "C" void kernel_launch(void* const* d_in, const int* in_sizes, int n_in,
                              void* d_out_, int out_size, void* d_ws, size_t ws_size,
                              hipStream_t stream) {
    (void)in_sizes; (void)n_in; (void)out_size;
    const float* x  = (const float*)d_in[0];
    const float* w1 = (const float*)d_in[1];
    const float* b1 = (const float*)d_in[2];
    const float* w2 = (const float*)d_in[3];
    const float* b2 = (const float*)d_in[4];
    const float* w3 = (const float*)d_in[5];
    const float* b3 = (const float*)d_in[6];
    const float* w4 = (const float*)d_in[7];
    const float* b4 = (const float*)d_in[8];
    const float* w5 = (const float*)d_in[9];
    const float* b5 = (const float*)d_in[10];
    const float* w6 = (const float*)d_in[11];
    const float* b6 = (const float*)d_in[12];
    float* dout = (float*)d_out_;

    char* ws = (char*)d_ws;
    float*  x123t    = (float*)(ws + 0);           // 25,165,824 B
    int*    idxb     = (int*)(ws + 25165824);      //  2,621,440 B
    float*  wbuf     = (float*)(ws + 27787264);    //     99,840 B
    float*  nrm      = (float*)(ws + 27887104);    //    131,072 B
    float*  partial6 = (float*)(ws + 28018176);    //  2,097,152 B
    double* wd2      = (double*)(ws + 30115328);   //     69,632 B
    float*  pd       = (float*)(ws + 30212096);    //  nb * 16 MiB
    long long avail = (long long)ws_size - 30212096LL;
    int nb = (int)(avail / 16777216LL);
    if (nb < 1) nb = 1;
    if (nb > 4) nb = 4;   // 64 MB chunks: keep pd L3-resident between gemm & select

    prep_wf<<<1, 256, 0, stream>>>(w1, w2, w3, w4, w5, wbuf);
    prep_cmp<<<1, 256, 0, stream>>>(w1, b1, w2, b2, w3, b3, w4, b4, wd2);

    // ---- block 1 ----
    knn1_k<<<dim3(1024, BB), 128, 0, stream>>>(x, idxb);
    conv1_k<<<8192, 256, 0, stream>>>(x, idxb, wd2, dout, x123t);

    // ---- knn on x1 (tiled GEMM + select, frozen arithmetic) ----
    norms23_k<<<128, 256, 0, stream>>>(x123t, 0, nrm);
    for (int b0 = 0; b0 < BB; b0 += nb) {
        int cur = (BB - b0 < nb) ? (BB - b0) : nb;
        gemm_pd_k<<<dim3(32, 32, cur), 256, 0, stream>>>(dout, 0, nrm, pd, b0);
        select_k<<<dim3(512, cur), 256, 0, stream>>>(pd, idxb, b0);
    }
    conv2_k<<<4096, 256, 0, stream>>>(x123t, idxb, wd2, dout, x123t);

    // ---- knn on x2 ----
    norms23_k<<<128, 256, 0, stream>>>(x123t, 64, nrm);
    for (int b0 = 0; b0 < BB; b0 += nb) {
        int cur = (BB - b0 < nb) ? (BB - b0) : nb;
        gemm_pd_k<<<dim3(32, 32, cur), 256, 0, stream>>>(dout, 64, nrm, pd, b0);
        select_k<<<dim3(512, cur), 256, 0, stream>>>(pd, idxb, b0);
    }
    conv3_k<<<4096, 256, 0, stream>>>(x123t, idxb, wbuf, b5, dout, x123t);

    // ---- final conv1d + global max ----
    w6_k<<<8192, 256, 0, stream>>>(x123t, w6, partial6);
    final_k<<<64, 256, 0, stream>>>(partial6, b6, dout);
}

// Round 16
// 1741.801 us; speedup vs baseline: 1.0956x; 1.0956x over previous
//
#include <hip/hip_runtime.h>

// Problem constants
#define BB 16
#define NN 2048
#define KK 20

#define NEG_INF (-3.402823466e+38f)
#define DNEG (-1.0e300)

// ---------------------------------------------------------------------------
// Composed fp64 weights (layout in wd2, doubles):
//  M1[3][64]@0   Md1[3][64]@192 (=Mh1-M1)   g01[64]@384
//  M2[64][64]@448   Md2[64][64]@4544 (=Mh2-M2)   g02[64]@8640
//  W5[64][64]@8704 (=w5lo[c][o])  W5d[64][64]@12800 (=w5hi-w5lo)  b5d[64]@16896
// ---------------------------------------------------------------------------
__global__ void prep_cmp(const float* __restrict__ w1, const float* __restrict__ b1,
                         const float* __restrict__ w2, const float* __restrict__ b2,
                         const float* __restrict__ w3, const float* __restrict__ b3,
                         const float* __restrict__ w4, const float* __restrict__ b4,
                         const float* __restrict__ w5, const float* __restrict__ b5,
                         double* __restrict__ wd2) {
    int t = threadIdx.x;
    for (int i = t; i < 192; i += 256) {
        int c = i >> 6, o = i & 63;
        double s = 0, sh = 0;
        for (int j = 0; j < 64; ++j) {
            double w2v = (double)w2[o * 64 + j];
            s  = fma(w2v, (double)w1[j * 6 + c], s);
            sh = fma(w2v, (double)w1[j * 6 + 3 + c], sh);
        }
        wd2[i] = s;
        wd2[192 + i] = sh - s;
    }
    for (int i = t; i < 64; i += 256) {
        double s = (double)b2[i];
        for (int j = 0; j < 64; ++j)
            s = fma((double)w2[i * 64 + j], (double)b1[j], s);
        wd2[384 + i] = s;
        double s2 = (double)b4[i];
        for (int j = 0; j < 64; ++j)
            s2 = fma((double)w4[i * 64 + j], (double)b3[j], s2);
        wd2[8640 + i] = s2;
        wd2[16896 + i] = (double)b5[i];
    }
    for (int i = t; i < 4096; i += 256) {
        int c = i >> 6, o = i & 63;
        double s = 0, sh = 0;
        for (int j = 0; j < 64; ++j) {
            double w4v = (double)w4[o * 64 + j];
            s  = fma(w4v, (double)w3[j * 128 + c], s);
            sh = fma(w4v, (double)w3[j * 128 + 64 + c], sh);
        }
        wd2[448 + i] = s;         // M2[c][o]
        wd2[4544 + i] = sh - s;   // Md2[c][o]
        double lo = (double)w5[o * 128 + c];
        wd2[8704 + i] = lo;                                  // W5[c][o]
        wd2[12800 + i] = (double)w5[o * 128 + 64 + c] - lo;  // W5d[c][o]
    }
}

// ---------------------------------------------------------------------------
// Top-20 selection over 2048 f32 candidates in a per-wave LDS row.
// FROZEN: stable ties -> lowest index.
// ---------------------------------------------------------------------------
__device__ __forceinline__ void top2_upd(float v, int g, float& av, int& ai,
                                         float& bv, int& bi) {
    bool gta = v > av;
    bool gtb = v > bv;
    float nbv = gta ? av : (gtb ? v : bv);
    int   nbi = gta ? ai : (gtb ? g : bi);
    av = gta ? v : av;
    ai = gta ? g : ai;
    bv = nbv;
    bi = nbi;
}

__device__ __forceinline__ void topk20_run(float* vrow, int lane, float av, int ai,
                                           float bv, int bi, int* outp) {
    int myout = 0;
    #pragma unroll 1
    for (int it = 0; it < 20; ++it) {
        float wv = av;
        #pragma unroll
        for (int d = 32; d; d >>= 1) wv = fmaxf(wv, __shfl_xor(wv, d));
        unsigned long long bal = __ballot(av == wv);
        int widx;
        if (__popcll(bal) == 1) {
            widx = __shfl(ai, __ffsll(bal) - 1);
        } else {  // exact tie across lanes: lowest global index wins
            int tt = (av == wv) ? ai : 0x7fffffff;
            #pragma unroll
            for (int d = 32; d; d >>= 1) tt = min(tt, __shfl_xor(tt, d));
            widx = tt;
        }
        if (lane == it) myout = widx;
        if (lane == 0) vrow[widx] = NEG_INF;   // remove winner
        if (ai == widx) { av = bv; ai = bi; bv = NEG_INF; bi = 0x7fffffff; }
        if (av == NEG_INF) {                   // rare: lane's top-2 exhausted
            ai = 0x7fffffff; bv = NEG_INF; bi = 0x7fffffff;
            #pragma unroll 1
            for (int s = 0; s < 32; ++s) {
                int col = s * 64 + lane;
                top2_upd(vrow[col], col, av, ai, bv, bi);
            }
        }
    }
    if (lane < 20) outp[lane] = myout;
}

// ---------------------------------------------------------------------------
// knn1: numpy-f32 mirror, FROZEN arithmetic.
// ---------------------------------------------------------------------------
__global__ void knn1_k(const float* __restrict__ x, int* __restrict__ idx) {
    __shared__ float vlds[2][2048];
    int lane = threadIdx.x & 63, w = threadIdx.x >> 6;
    int b = blockIdx.y, r = blockIdx.x * 2 + w;
    const float* xb = x + (size_t)b * 3 * NN;
    float rx = xb[r], ry = xb[NN + r], rz = xb[2 * NN + r];
    float xxi = __fadd_rn(__fadd_rn(__fmul_rn(rx, rx), __fmul_rn(ry, ry)),
                          __fmul_rn(rz, rz));
    float* vrow = vlds[w];
    float av = NEG_INF, bv = NEG_INF;
    int ai = 0x7fffffff, bi = 0x7fffffff;
    #pragma unroll 1
    for (int s = 0; s < 32; ++s) {
        int col = s * 64 + lane;
        float cx = xb[col], cy = xb[NN + col], cz = xb[2 * NN + col];
        float xxj = __fadd_rn(__fadd_rn(__fmul_rn(cx, cx), __fmul_rn(cy, cy)),
                              __fmul_rn(cz, cz));
        float dot = fmaf(rz, cz, fmaf(ry, cy, __fmul_rn(rx, cx)));
        float inner = __fmul_rn(-2.f, dot);
        float t1 = __fsub_rn(-xxj, inner);
        float nd = __fsub_rn(t1, xxi);
        vrow[col] = nd;
        top2_upd(nd, col, av, ai, bv, bi);
    }
    topk20_run(vrow, lane, av, ai, bv, bi, idx + ((size_t)b * NN + r) * KK);
}

// xx for a 64-channel slice. FROZEN.
__global__ void norms23_k(const float* __restrict__ x123t, int coff,
                          float* __restrict__ nrm) {
    int t = blockIdx.x * 256 + threadIdx.x;   // 32768 points
    const float* r = x123t + (size_t)t * 192 + coff;
    float acc = 0.f;
    #pragma unroll 1
    for (int c = 0; c < 64; ++c)
        acc = __fadd_rn(acc, __fmul_rn(r[c], r[c]));
    nrm[t] = acc;
}

// ---------------------------------------------------------------------------
// pd GEMM (knn2/3 distances). FROZEN chain + epilogue.
// ---------------------------------------------------------------------------
__global__ __launch_bounds__(256) void gemm_pd_k(const float* __restrict__ dout,
        int coff, const float* __restrict__ nrm, float* __restrict__ pd, int b0) {
    __shared__ float As[64][68];
    __shared__ float Bs[64][68];
    int b = b0 + blockIdx.z;
    int rb = blockIdx.y * 64, cb = blockIdx.x * 64;
    const float* doutc = dout + (size_t)(b * 192 + coff) * NN;
    int tid = threadIdx.x;
    int cq = tid >> 4, qd = (tid & 15) * 4;
    #pragma unroll
    for (int cc = 0; cc < 64; cc += 16) {
        float4 a = *(const float4*)(doutc + (size_t)(cc + cq) * NN + rb + qd);
        As[cc + cq][qd + 0] = a.x; As[cc + cq][qd + 1] = a.y;
        As[cc + cq][qd + 2] = a.z; As[cc + cq][qd + 3] = a.w;
        float4 bv = *(const float4*)(doutc + (size_t)(cc + cq) * NN + cb + qd);
        Bs[cc + cq][qd + 0] = bv.x; Bs[cc + cq][qd + 1] = bv.y;
        Bs[cc + cq][qd + 2] = bv.z; Bs[cc + cq][qd + 3] = bv.w;
    }
    __syncthreads();
    int tx = tid & 15, ty = tid >> 4;
    float acc[4][4];
    #pragma unroll
    for (int i = 0; i < 4; ++i)
        #pragma unroll
        for (int j = 0; j < 4; ++j) acc[i][j] = 0.f;
    #pragma unroll 4
    for (int c = 0; c < 64; ++c) {
        float4 av4 = *(const float4*)&As[c][ty * 4];
        float4 bv4 = *(const float4*)&Bs[c][tx * 4];
        float aa[4] = {av4.x, av4.y, av4.z, av4.w};
        float bb[4] = {bv4.x, bv4.y, bv4.z, bv4.w};
        #pragma unroll
        for (int i = 0; i < 4; ++i)
            #pragma unroll
            for (int j = 0; j < 4; ++j)
                acc[i][j] = fmaf(aa[i], bb[j], acc[i][j]);  // ascending-c chain
    }
    const float* nb_ = nrm + (size_t)b * NN;
    #pragma unroll
    for (int i = 0; i < 4; ++i) {
        int r = rb + ty * 4 + i;
        float xxi = nb_[r];
        float4 o4;
        float* o = (float*)&o4;
        #pragma unroll
        for (int j = 0; j < 4; ++j) {
            float xxj = nb_[cb + tx * 4 + j];
            float inner = __fmul_rn(-2.f, acc[i][j]);
            float t1 = __fsub_rn(-xxj, inner);
            o[j] = __fsub_rn(t1, xxi);
        }
        *(float4*)(pd + ((size_t)blockIdx.z * NN + r) * NN + cb + tx * 4) = o4;
    }
}

// selection from materialized pd chunk (FROZEN helpers)
__global__ void select_k(const float* __restrict__ pd, int* __restrict__ idx, int b0) {
    __shared__ float vlds[4][2048];
    int lane = threadIdx.x & 63, w = threadIdx.x >> 6;
    int bb = blockIdx.y, r = blockIdx.x * 4 + w;
    const float* row = pd + ((size_t)bb * NN + r) * NN;
    float* vrow = vlds[w];
    float av = NEG_INF, bv = NEG_INF;
    int ai = 0x7fffffff, bi = 0x7fffffff;
    #pragma unroll 1
    for (int s = 0; s < 32; ++s) {
        int col = s * 64 + lane;
        float v = row[col];
        vrow[col] = v;
        top2_upd(v, col, av, ai, bv, bi);
    }
    topk20_run(vrow, lane, av, ai, bv, bi, idx + ((size_t)(b0 + bb) * NN + r) * KK);
}

// ---------------------------------------------------------------------------
// EdgeConv via A/B decomposition:
//   h[n,k,o] = A[n][o] + B[idx[n][k]][o];  max_k commutes with + (monotone).
// ab*: per-point fp64 matvecs. gmax: gather 20 B-rows, elementwise max, +A.
// ---------------------------------------------------------------------------
__global__ __launch_bounds__(256) void ab1_k(const float* __restrict__ x,
        const double* __restrict__ wd2, double* __restrict__ Ad,
        double* __restrict__ Bd) {
    int tid = threadIdx.x, lane = tid & 63, w = tid >> 6;
    int p = blockIdx.x * 4 + w, b = p >> 11, n = p & 2047;
    const float* xb = x + (size_t)b * 3 * NN;
    double c0 = (double)xb[n], c1 = (double)xb[NN + n], c2 = (double)xb[2 * NN + n];
    double A = wd2[384 + lane];
    A = fma(wd2[192 + 0 * 64 + lane], c0, A);
    A = fma(wd2[192 + 1 * 64 + lane], c1, A);
    A = fma(wd2[192 + 2 * 64 + lane], c2, A);
    double B = wd2[0 * 64 + lane] * c0;
    B = fma(wd2[1 * 64 + lane], c1, B);
    B = fma(wd2[2 * 64 + lane], c2, B);
    Ad[(size_t)p * 64 + lane] = A;
    Bd[(size_t)p * 64 + lane] = B;
}

// conv2/conv3 A/B: block = 4 waves x 16 points. W (main) staged in LDS;
// Wd (delta) read from global (L1/L2-hot).
__global__ __launch_bounds__(256) void ab23_k(const float* __restrict__ x123t,
        const double* __restrict__ wd2, int coff, int woffW, int woffWd, int goff,
        double* __restrict__ Ad, double* __restrict__ Bd) {
    __shared__ double Ws[4096];      // 32 KB
    __shared__ double ctr[4][64];    // 2 KB
    int tid = threadIdx.x, lane = tid & 63, w = tid >> 6;
    for (int i = tid; i < 4096; i += 256) Ws[i] = wd2[woffW + i];
    __syncthreads();
    int p0 = blockIdx.x * 64 + w * 16;
    #pragma unroll 1
    for (int it = 0; it < 16; ++it) {
        int p = p0 + it, b = p >> 11, n = p & 2047;
        ctr[w][lane] = (double)x123t[((size_t)b * NN + n) * 192 + coff + lane];
        double a0 = wd2[goff + lane], a1 = 0, a2 = 0, a3 = 0;
        double q0 = 0, q1 = 0, q2 = 0, q3 = 0;
        #pragma unroll
        for (int c = 0; c < 64; c += 4) {
            double x0 = ctr[w][c + 0], x1 = ctr[w][c + 1];
            double x2 = ctr[w][c + 2], x3 = ctr[w][c + 3];
            a0 = fma(wd2[woffWd + (c + 0) * 64 + lane], x0, a0);
            a1 = fma(wd2[woffWd + (c + 1) * 64 + lane], x1, a1);
            a2 = fma(wd2[woffWd + (c + 2) * 64 + lane], x2, a2);
            a3 = fma(wd2[woffWd + (c + 3) * 64 + lane], x3, a3);
            q0 = fma(Ws[(c + 0) * 64 + lane], x0, q0);
            q1 = fma(Ws[(c + 1) * 64 + lane], x1, q1);
            q2 = fma(Ws[(c + 2) * 64 + lane], x2, q2);
            q3 = fma(Ws[(c + 3) * 64 + lane], x3, q3);
        }
        Ad[(size_t)p * 64 + lane] = (a0 + a1) + (a2 + a3);
        Bd[(size_t)p * 64 + lane] = (q0 + q1) + (q2 + q3);
    }
}

__global__ __launch_bounds__(256) void gmax_k(const double* __restrict__ Ad,
        const double* __restrict__ Bd, const int* __restrict__ idxb, int cho,
        float* __restrict__ dout, float* __restrict__ x123t_o) {
    int tid = threadIdx.x, lane = tid & 63, w = tid >> 6;
    int p = blockIdx.x * 4 + w, b = p >> 11, n = p & 2047;
    const int* ip = idxb + (size_t)p * KK;
    size_t boff = (size_t)(b << 11);
    double m = DNEG;
    int nbc = ip[0];
    double v = Bd[(boff + nbc) * 64 + lane];
    #pragma unroll 1
    for (int kk = 0; kk < KK; ++kk) {
        double cur = v;
        if (kk < KK - 1) {
            int nbn = ip[kk + 1];
            v = Bd[(boff + nbn) * 64 + lane];
        }
        m = fmax(m, cur);
    }
    double out = Ad[(size_t)p * 64 + lane] + m;
    dout[((size_t)b * 192 + cho + lane) * NN + n] = (float)out;
    x123t_o[((size_t)b * NN + n) * 192 + cho + lane] = (float)out;
}

// ---------------------------------------------------------------------------
// Final conv1d (1024x192) as LDS-tiled f32 GEMM, 64o x 64n per block, KC=32.
// ---------------------------------------------------------------------------
#define KC 32
__global__ __launch_bounds__(256) void w6_k(const float* __restrict__ x123t,
                                            const float* __restrict__ w6,
                                            float* __restrict__ partial6) {
    __shared__ float xs[KC][68];
    __shared__ float wsb[KC][68];
    __shared__ float red[64][17];
    int tid = threadIdx.x;
    int ntile = blockIdx.x & 31, ot = (blockIdx.x >> 5) & 15, b = blockIdx.x >> 9;
    int n0 = ntile * 64, o0 = ot * 64;
    int ln = tid >> 2, lc = (tid & 3) * 8;
    const float* xrow = x123t + ((size_t)b * NN + n0 + ln) * 192 + lc;
    const float* wrow = w6 + (size_t)(o0 + ln) * 192 + lc;
    float acc[4][4];
    #pragma unroll
    for (int i = 0; i < 4; ++i)
        #pragma unroll
        for (int j = 0; j < 4; ++j) acc[i][j] = 0.f;
    int to = tid & 15, tn = tid >> 4;
    for (int cc = 0; cc < 192; cc += KC) {
        float4 xa = *(const float4*)(xrow + cc);
        float4 xb4 = *(const float4*)(xrow + cc + 4);
        float4 wa = *(const float4*)(wrow + cc);
        float4 wb4 = *(const float4*)(wrow + cc + 4);
        __syncthreads();
        xs[lc + 0][ln] = xa.x; xs[lc + 1][ln] = xa.y;
        xs[lc + 2][ln] = xa.z; xs[lc + 3][ln] = xa.w;
        xs[lc + 4][ln] = xb4.x; xs[lc + 5][ln] = xb4.y;
        xs[lc + 6][ln] = xb4.z; xs[lc + 7][ln] = xb4.w;
        wsb[lc + 0][ln] = wa.x; wsb[lc + 1][ln] = wa.y;
        wsb[lc + 2][ln] = wa.z; wsb[lc + 3][ln] = wa.w;
        wsb[lc + 4][ln] = wb4.x; wsb[lc + 5][ln] = wb4.y;
        wsb[lc + 6][ln] = wb4.z; wsb[lc + 7][ln] = wb4.w;
        __syncthreads();
        #pragma unroll
        for (int k = 0; k < KC; ++k) {
            float4 wv = *(const float4*)&wsb[k][to * 4];
            float4 xv = *(const float4*)&xs[k][tn * 4];
            float wr[4] = {wv.x, wv.y, wv.z, wv.w};
            float xr[4] = {xv.x, xv.y, xv.z, xv.w};
            #pragma unroll
            for (int i = 0; i < 4; ++i)
                #pragma unroll
                for (int j = 0; j < 4; ++j)
                    acc[i][j] = fmaf(wr[i], xr[j], acc[i][j]);
        }
    }
    #pragma unroll
    for (int i = 0; i < 4; ++i) {
        float mm = fmaxf(fmaxf(acc[i][0], acc[i][1]), fmaxf(acc[i][2], acc[i][3]));
        red[to * 4 + i][tn] = mm;
    }
    __syncthreads();
    if (tid < 64) {
        float mm = red[tid][0];
        #pragma unroll
        for (int t = 1; t < 16; ++t) mm = fmaxf(mm, red[tid][t]);
        partial6[((size_t)b * 1024 + o0 + tid) * 32 + ntile] = mm;
    }
}

__global__ void final_k(const float* __restrict__ partial6, const float* __restrict__ b6,
                        float* __restrict__ dout) {
    int t = blockIdx.x * 256 + threadIdx.x;  // < 16*1024
    int o = t & 1023;
    float m = NEG_INF;
    #pragma unroll 1
    for (int nt = 0; nt < 32; ++nt) m = fmaxf(m, partial6[(size_t)t * 32 + nt]);
    dout[(size_t)BB * 192 * NN + t] = m + b6[o];
}

// ---------------------------------------------------------------------------
extern "C" void kernel_launch(void* const* d_in, const int* in_sizes, int n_in,
                              void* d_out_, int out_size, void* d_ws, size_t ws_size,
                              hipStream_t stream) {
    (void)in_sizes; (void)n_in; (void)out_size; (void)ws_size;
    const float* x  = (const float*)d_in[0];
    const float* w1 = (const float*)d_in[1];
    const float* b1 = (const float*)d_in[2];
    const float* w2 = (const float*)d_in[3];
    const float* b2 = (const float*)d_in[4];
    const float* w3 = (const float*)d_in[5];
    const float* b3 = (const float*)d_in[6];
    const float* w4 = (const float*)d_in[7];
    const float* b4 = (const float*)d_in[8];
    const float* w5 = (const float*)d_in[9];
    const float* b5 = (const float*)d_in[10];
    const float* w6 = (const float*)d_in[11];
    const float* b6 = (const float*)d_in[12];
    float* dout = (float*)d_out_;

    char* ws = (char*)d_ws;
    float*  x123t    = (float*)(ws + 0);           // 25,165,824 B
    int*    idxb     = (int*)(ws + 25165824);      //  2,621,440 B
    float*  nrm      = (float*)(ws + 27787264);    //    131,072 B
    float*  partial6 = (float*)(ws + 27918336);    //  2,097,152 B
    double* wd2      = (double*)(ws + 30015488);   //    135,680 B
    // region: pd (2 batches x 16MB) OR Ad+Bd (16MB each). Never live together.
    char*   region   = ws + 30151168;              // 33,554,432 B  (total ~60.8 MB)
    float*  pd = (float*)region;
    double* Ad = (double*)region;
    double* Bd = (double*)(region + 16777216);
    const int nb = 2;

    prep_cmp<<<1, 256, 0, stream>>>(w1, b1, w2, b2, w3, b3, w4, b4, w5, b5, wd2);

    // ---- block 1 ----
    knn1_k<<<dim3(1024, BB), 128, 0, stream>>>(x, idxb);
    ab1_k<<<8192, 256, 0, stream>>>(x, wd2, Ad, Bd);
    gmax_k<<<8192, 256, 0, stream>>>(Ad, Bd, idxb, 0, dout, x123t);

    // ---- knn on x1 (tiled GEMM + select, frozen arithmetic) ----
    norms23_k<<<128, 256, 0, stream>>>(x123t, 0, nrm);
    for (int b0 = 0; b0 < BB; b0 += nb) {
        gemm_pd_k<<<dim3(32, 32, nb), 256, 0, stream>>>(dout, 0, nrm, pd, b0);
        select_k<<<dim3(512, nb), 256, 0, stream>>>(pd, idxb, b0);
    }
    // ---- block 2 (A/B overwrite pd region; pd dead after select) ----
    ab23_k<<<512, 256, 0, stream>>>(x123t, wd2, 0, 448, 4544, 8640, Ad, Bd);
    gmax_k<<<8192, 256, 0, stream>>>(Ad, Bd, idxb, 64, dout, x123t);

    // ---- knn on x2 ----
    norms23_k<<<128, 256, 0, stream>>>(x123t, 64, nrm);
    for (int b0 = 0; b0 < BB; b0 += nb) {
        gemm_pd_k<<<dim3(32, 32, nb), 256, 0, stream>>>(dout, 64, nrm, pd, b0);
        select_k<<<dim3(512, nb), 256, 0, stream>>>(pd, idxb, b0);
    }
    // ---- block 3 ----
    ab23_k<<<512, 256, 0, stream>>>(x123t, wd2, 64, 8704, 12800, 16896, Ad, Bd);
    gmax_k<<<8192, 256, 0, stream>>>(Ad, Bd, idxb, 128, dout, x123t);

    // ---- final conv1d + global max ----
    w6_k<<<8192, 256, 0, stream>>>(x123t, w6, partial6);
    final_k<<<64, 256, 0, stream>>>(partial6, b6, dout);
}

// Round 17
// 1657.328 us; speedup vs baseline: 1.1514x; 1.0510x over previous
//
#include <hip/hip_runtime.h>

// Problem constants
#define BB 16
#define NN 2048
#define KK 20

#define NEG_INF (-3.402823466e+38f)
#define DNEG (-1.0e300)

// ---------------------------------------------------------------------------
// Composed fp64 weights (layout in wd2, doubles):
//  M1[3][64]@0   Md1[3][64]@192 (=Mh1-M1)   g01[64]@384
//  M2[64][64]@448   Md2[64][64]@4544 (=Mh2-M2)   g02[64]@8640
//  W5[64][64]@8704 (=w5lo[c][o])  W5d[64][64]@12800 (=w5hi-w5lo)  b5d[64]@16896
// ---------------------------------------------------------------------------
__global__ void prep_cmp(const float* __restrict__ w1, const float* __restrict__ b1,
                         const float* __restrict__ w2, const float* __restrict__ b2,
                         const float* __restrict__ w3, const float* __restrict__ b3,
                         const float* __restrict__ w4, const float* __restrict__ b4,
                         const float* __restrict__ w5, const float* __restrict__ b5,
                         double* __restrict__ wd2) {
    int t = threadIdx.x;
    for (int i = t; i < 192; i += 256) {
        int c = i >> 6, o = i & 63;
        double s = 0, sh = 0;
        for (int j = 0; j < 64; ++j) {
            double w2v = (double)w2[o * 64 + j];
            s  = fma(w2v, (double)w1[j * 6 + c], s);
            sh = fma(w2v, (double)w1[j * 6 + 3 + c], sh);
        }
        wd2[i] = s;
        wd2[192 + i] = sh - s;
    }
    for (int i = t; i < 64; i += 256) {
        double s = (double)b2[i];
        for (int j = 0; j < 64; ++j)
            s = fma((double)w2[i * 64 + j], (double)b1[j], s);
        wd2[384 + i] = s;
        double s2 = (double)b4[i];
        for (int j = 0; j < 64; ++j)
            s2 = fma((double)w4[i * 64 + j], (double)b3[j], s2);
        wd2[8640 + i] = s2;
        wd2[16896 + i] = (double)b5[i];
    }
    for (int i = t; i < 4096; i += 256) {
        int c = i >> 6, o = i & 63;
        double s = 0, sh = 0;
        for (int j = 0; j < 64; ++j) {
            double w4v = (double)w4[o * 64 + j];
            s  = fma(w4v, (double)w3[j * 128 + c], s);
            sh = fma(w4v, (double)w3[j * 128 + 64 + c], sh);
        }
        wd2[448 + i] = s;         // M2[c][o]
        wd2[4544 + i] = sh - s;   // Md2[c][o]
        double lo = (double)w5[o * 128 + c];
        wd2[8704 + i] = lo;                                  // W5[c][o]
        wd2[12800 + i] = (double)w5[o * 128 + 64 + c] - lo;  // W5d[c][o]
    }
}

// ---------------------------------------------------------------------------
// Packed-key top-20 selection. key = (orderable(value) << 32) | (2047 - col).
// Max key == max value with lowest-col tie-break (identical to frozen float
// semantics; __fadd_rn(v,0) canonicalizes -0 -> +0 so +-0 ties match float
// compare). Keys unique (col embedded) -> exactly one owner lane per winner.
// ---------------------------------------------------------------------------
__device__ __forceinline__ unsigned long long pkey(float v, int col) {
    float vc = __fadd_rn(v, 0.0f);   // -0 -> +0 (real instruction)
    unsigned u = __float_as_uint(vc);
    unsigned s = (unsigned)((int)u >> 31);
    unsigned m = u ^ (s | 0x80000000u);
    return ((unsigned long long)m << 32) | (unsigned)(2047 - col);
}

__device__ __forceinline__ void top2k_upd(unsigned long long k,
        unsigned long long& ka, unsigned long long& kb) {
    bool gta = k > ka;
    bool gtb = k > kb;
    unsigned long long nkb = gta ? ka : (gtb ? k : kb);
    ka = gta ? k : ka;
    kb = nkb;
}

__device__ __forceinline__ void topk20_key(float* vrow, int lane,
        unsigned long long ka, unsigned long long kb, int* outp) {
    int myout = 0;
    #pragma unroll 1
    for (int it = 0; it < 20; ++it) {
        unsigned long long wk = ka;
        #pragma unroll
        for (int d = 32; d; d >>= 1) {
            unsigned long long o = __shfl_xor(wk, d);
            wk = (o > wk) ? o : wk;
        }
        int widx = 2047 - (int)(wk & 0xFFFFFFFFull);
        if (lane == it) myout = widx;
        if (ka == wk) {                  // unique owner pops + marks removed
            vrow[widx] = NEG_INF;
            ka = kb;
            kb = 0ULL;
        }
        if (ka == 0ULL) {                // rare: lane's top-2 exhausted
            kb = 0ULL;
            #pragma unroll 1
            for (int s = 0; s < 32; ++s) {
                int col = s * 64 + lane;
                top2k_upd(pkey(vrow[col], col), ka, kb);
            }
        }
    }
    if (lane < 20) outp[lane] = myout;
}

// ---------------------------------------------------------------------------
// knn1: numpy-f32 mirror, FROZEN distance arithmetic.
// ---------------------------------------------------------------------------
__global__ void knn1_k(const float* __restrict__ x, int* __restrict__ idx) {
    __shared__ float vlds[2][2048];
    int lane = threadIdx.x & 63, w = threadIdx.x >> 6;
    int b = blockIdx.y, r = blockIdx.x * 2 + w;
    const float* xb = x + (size_t)b * 3 * NN;
    float rx = xb[r], ry = xb[NN + r], rz = xb[2 * NN + r];
    float xxi = __fadd_rn(__fadd_rn(__fmul_rn(rx, rx), __fmul_rn(ry, ry)),
                          __fmul_rn(rz, rz));
    float* vrow = vlds[w];
    unsigned long long ka = 0ULL, kb = 0ULL;
    #pragma unroll 1
    for (int s = 0; s < 32; ++s) {
        int col = s * 64 + lane;
        float cx = xb[col], cy = xb[NN + col], cz = xb[2 * NN + col];
        float xxj = __fadd_rn(__fadd_rn(__fmul_rn(cx, cx), __fmul_rn(cy, cy)),
                              __fmul_rn(cz, cz));
        float dot = fmaf(rz, cz, fmaf(ry, cy, __fmul_rn(rx, cx)));
        float inner = __fmul_rn(-2.f, dot);
        float t1 = __fsub_rn(-xxj, inner);
        float nd = __fsub_rn(t1, xxi);
        vrow[col] = nd;
        top2k_upd(pkey(nd, col), ka, kb);
    }
    topk20_key(vrow, lane, ka, kb, idx + ((size_t)b * NN + r) * KK);
}

// xx for a 64-channel slice. FROZEN.
__global__ void norms23_k(const float* __restrict__ x123t, int coff,
                          float* __restrict__ nrm) {
    int t = blockIdx.x * 256 + threadIdx.x;   // 32768 points
    const float* r = x123t + (size_t)t * 192 + coff;
    float acc = 0.f;
    #pragma unroll 1
    for (int c = 0; c < 64; ++c)
        acc = __fadd_rn(acc, __fmul_rn(r[c], r[c]));
    nrm[t] = acc;
}

// ---------------------------------------------------------------------------
// pd GEMM (knn2/3 distances). FROZEN chain + epilogue.
// ---------------------------------------------------------------------------
__global__ __launch_bounds__(256) void gemm_pd_k(const float* __restrict__ dout,
        int coff, const float* __restrict__ nrm, float* __restrict__ pd, int b0) {
    __shared__ float As[64][68];
    __shared__ float Bs[64][68];
    int b = b0 + blockIdx.z;
    int rb = blockIdx.y * 64, cb = blockIdx.x * 64;
    const float* doutc = dout + (size_t)(b * 192 + coff) * NN;
    int tid = threadIdx.x;
    int cq = tid >> 4, qd = (tid & 15) * 4;
    #pragma unroll
    for (int cc = 0; cc < 64; cc += 16) {
        float4 a = *(const float4*)(doutc + (size_t)(cc + cq) * NN + rb + qd);
        As[cc + cq][qd + 0] = a.x; As[cc + cq][qd + 1] = a.y;
        As[cc + cq][qd + 2] = a.z; As[cc + cq][qd + 3] = a.w;
        float4 bv = *(const float4*)(doutc + (size_t)(cc + cq) * NN + cb + qd);
        Bs[cc + cq][qd + 0] = bv.x; Bs[cc + cq][qd + 1] = bv.y;
        Bs[cc + cq][qd + 2] = bv.z; Bs[cc + cq][qd + 3] = bv.w;
    }
    __syncthreads();
    int tx = tid & 15, ty = tid >> 4;
    float acc[4][4];
    #pragma unroll
    for (int i = 0; i < 4; ++i)
        #pragma unroll
        for (int j = 0; j < 4; ++j) acc[i][j] = 0.f;
    #pragma unroll 4
    for (int c = 0; c < 64; ++c) {
        float4 av4 = *(const float4*)&As[c][ty * 4];
        float4 bv4 = *(const float4*)&Bs[c][tx * 4];
        float aa[4] = {av4.x, av4.y, av4.z, av4.w};
        float bb[4] = {bv4.x, bv4.y, bv4.z, bv4.w};
        #pragma unroll
        for (int i = 0; i < 4; ++i)
            #pragma unroll
            for (int j = 0; j < 4; ++j)
                acc[i][j] = fmaf(aa[i], bb[j], acc[i][j]);  // ascending-c chain
    }
    const float* nb_ = nrm + (size_t)b * NN;
    #pragma unroll
    for (int i = 0; i < 4; ++i) {
        int r = rb + ty * 4 + i;
        float xxi = nb_[r];
        float4 o4;
        float* o = (float*)&o4;
        #pragma unroll
        for (int j = 0; j < 4; ++j) {
            float xxj = nb_[cb + tx * 4 + j];
            float inner = __fmul_rn(-2.f, acc[i][j]);
            float t1 = __fsub_rn(-xxj, inner);
            o[j] = __fsub_rn(t1, xxi);
        }
        *(float4*)(pd + ((size_t)blockIdx.z * NN + r) * NN + cb + tx * 4) = o4;
    }
}

// selection from materialized pd chunk (packed-key, same semantics)
__global__ void select_k(const float* __restrict__ pd, int* __restrict__ idx, int b0) {
    __shared__ float vlds[4][2048];
    int lane = threadIdx.x & 63, w = threadIdx.x >> 6;
    int bb = blockIdx.y, r = blockIdx.x * 4 + w;
    const float* row = pd + ((size_t)bb * NN + r) * NN;
    float* vrow = vlds[w];
    unsigned long long ka = 0ULL, kb = 0ULL;
    #pragma unroll 1
    for (int s = 0; s < 32; ++s) {
        int col = s * 64 + lane;
        float v = row[col];
        vrow[col] = v;
        top2k_upd(pkey(v, col), ka, kb);
    }
    topk20_key(vrow, lane, ka, kb, idx + ((size_t)(b0 + bb) * NN + r) * KK);
}

// ---------------------------------------------------------------------------
// EdgeConv via A/B decomposition:
//   h[n,k,o] = A[n][o] + B[idx[n][k]][o];  max_k commutes with + (monotone).
// ab*: per-point fp64 matvecs. gmax: gather 20 B-rows, elementwise max, +A.
// ---------------------------------------------------------------------------
__global__ __launch_bounds__(256) void ab1_k(const float* __restrict__ x,
        const double* __restrict__ wd2, double* __restrict__ Ad,
        double* __restrict__ Bd) {
    int tid = threadIdx.x, lane = tid & 63, w = tid >> 6;
    int p = blockIdx.x * 4 + w, b = p >> 11, n = p & 2047;
    const float* xb = x + (size_t)b * 3 * NN;
    double c0 = (double)xb[n], c1 = (double)xb[NN + n], c2 = (double)xb[2 * NN + n];
    double A = wd2[384 + lane];
    A = fma(wd2[192 + 0 * 64 + lane], c0, A);
    A = fma(wd2[192 + 1 * 64 + lane], c1, A);
    A = fma(wd2[192 + 2 * 64 + lane], c2, A);
    double B = wd2[0 * 64 + lane] * c0;
    B = fma(wd2[1 * 64 + lane], c1, B);
    B = fma(wd2[2 * 64 + lane], c2, B);
    Ad[(size_t)p * 64 + lane] = A;
    Bd[(size_t)p * 64 + lane] = B;
}

// conv2/conv3 A/B: block = 4 waves x 16 points. W (main) staged in LDS;
// Wd (delta) read from global (L1/L2-hot).
__global__ __launch_bounds__(256) void ab23_k(const float* __restrict__ x123t,
        const double* __restrict__ wd2, int coff, int woffW, int woffWd, int goff,
        double* __restrict__ Ad, double* __restrict__ Bd) {
    __shared__ double Ws[4096];      // 32 KB
    __shared__ double ctr[4][64];    // 2 KB
    int tid = threadIdx.x, lane = tid & 63, w = tid >> 6;
    for (int i = tid; i < 4096; i += 256) Ws[i] = wd2[woffW + i];
    __syncthreads();
    int p0 = blockIdx.x * 64 + w * 16;
    #pragma unroll 1
    for (int it = 0; it < 16; ++it) {
        int p = p0 + it, b = p >> 11, n = p & 2047;
        ctr[w][lane] = (double)x123t[((size_t)b * NN + n) * 192 + coff + lane];
        double a0 = wd2[goff + lane], a1 = 0, a2 = 0, a3 = 0;
        double q0 = 0, q1 = 0, q2 = 0, q3 = 0;
        #pragma unroll
        for (int c = 0; c < 64; c += 4) {
            double x0 = ctr[w][c + 0], x1 = ctr[w][c + 1];
            double x2 = ctr[w][c + 2], x3 = ctr[w][c + 3];
            a0 = fma(wd2[woffWd + (c + 0) * 64 + lane], x0, a0);
            a1 = fma(wd2[woffWd + (c + 1) * 64 + lane], x1, a1);
            a2 = fma(wd2[woffWd + (c + 2) * 64 + lane], x2, a2);
            a3 = fma(wd2[woffWd + (c + 3) * 64 + lane], x3, a3);
            q0 = fma(Ws[(c + 0) * 64 + lane], x0, q0);
            q1 = fma(Ws[(c + 1) * 64 + lane], x1, q1);
            q2 = fma(Ws[(c + 2) * 64 + lane], x2, q2);
            q3 = fma(Ws[(c + 3) * 64 + lane], x3, q3);
        }
        Ad[(size_t)p * 64 + lane] = (a0 + a1) + (a2 + a3);
        Bd[(size_t)p * 64 + lane] = (q0 + q1) + (q2 + q3);
    }
}

__global__ __launch_bounds__(256) void gmax_k(const double* __restrict__ Ad,
        const double* __restrict__ Bd, const int* __restrict__ idxb, int cho,
        float* __restrict__ dout, float* __restrict__ x123t_o) {
    int tid = threadIdx.x, lane = tid & 63, w = tid >> 6;
    int p = blockIdx.x * 4 + w, b = p >> 11, n = p & 2047;
    const int* ip = idxb + (size_t)p * KK;
    size_t boff = (size_t)(b << 11);
    double m = DNEG;
    int nbc = ip[0];
    double v = Bd[(boff + nbc) * 64 + lane];
    #pragma unroll 1
    for (int kk = 0; kk < KK; ++kk) {
        double cur = v;
        if (kk < KK - 1) {
            int nbn = ip[kk + 1];
            v = Bd[(boff + nbn) * 64 + lane];
        }
        m = fmax(m, cur);
    }
    double out = Ad[(size_t)p * 64 + lane] + m;
    dout[((size_t)b * 192 + cho + lane) * NN + n] = (float)out;
    x123t_o[((size_t)b * NN + n) * 192 + cho + lane] = (float)out;
}

// ---------------------------------------------------------------------------
// Final conv1d (1024x192) as LDS-tiled f32 GEMM, 64o x 64n per block, KC=32.
// ---------------------------------------------------------------------------
#define KC 32
__global__ __launch_bounds__(256) void w6_k(const float* __restrict__ x123t,
                                            const float* __restrict__ w6,
                                            float* __restrict__ partial6) {
    __shared__ float xs[KC][68];
    __shared__ float wsb[KC][68];
    __shared__ float red[64][17];
    int tid = threadIdx.x;
    int ntile = blockIdx.x & 31, ot = (blockIdx.x >> 5) & 15, b = blockIdx.x >> 9;
    int n0 = ntile * 64, o0 = ot * 64;
    int ln = tid >> 2, lc = (tid & 3) * 8;
    const float* xrow = x123t + ((size_t)b * NN + n0 + ln) * 192 + lc;
    const float* wrow = w6 + (size_t)(o0 + ln) * 192 + lc;
    float acc[4][4];
    #pragma unroll
    for (int i = 0; i < 4; ++i)
        #pragma unroll
        for (int j = 0; j < 4; ++j) acc[i][j] = 0.f;
    int to = tid & 15, tn = tid >> 4;
    for (int cc = 0; cc < 192; cc += KC) {
        float4 xa = *(const float4*)(xrow + cc);
        float4 xb4 = *(const float4*)(xrow + cc + 4);
        float4 wa = *(const float4*)(wrow + cc);
        float4 wb4 = *(const float4*)(wrow + cc + 4);
        __syncthreads();
        xs[lc + 0][ln] = xa.x; xs[lc + 1][ln] = xa.y;
        xs[lc + 2][ln] = xa.z; xs[lc + 3][ln] = xa.w;
        xs[lc + 4][ln] = xb4.x; xs[lc + 5][ln] = xb4.y;
        xs[lc + 6][ln] = xb4.z; xs[lc + 7][ln] = xb4.w;
        wsb[lc + 0][ln] = wa.x; wsb[lc + 1][ln] = wa.y;
        wsb[lc + 2][ln] = wa.z; wsb[lc + 3][ln] = wa.w;
        wsb[lc + 4][ln] = wb4.x; wsb[lc + 5][ln] = wb4.y;
        wsb[lc + 6][ln] = wb4.z; wsb[lc + 7][ln] = wb4.w;
        __syncthreads();
        #pragma unroll
        for (int k = 0; k < KC; ++k) {
            float4 wv = *(const float4*)&wsb[k][to * 4];
            float4 xv = *(const float4*)&xs[k][tn * 4];
            float wr[4] = {wv.x, wv.y, wv.z, wv.w};
            float xr[4] = {xv.x, xv.y, xv.z, xv.w};
            #pragma unroll
            for (int i = 0; i < 4; ++i)
                #pragma unroll
                for (int j = 0; j < 4; ++j)
                    acc[i][j] = fmaf(wr[i], xr[j], acc[i][j]);
        }
    }
    #pragma unroll
    for (int i = 0; i < 4; ++i) {
        float mm = fmaxf(fmaxf(acc[i][0], acc[i][1]), fmaxf(acc[i][2], acc[i][3]));
        red[to * 4 + i][tn] = mm;
    }
    __syncthreads();
    if (tid < 64) {
        float mm = red[tid][0];
        #pragma unroll
        for (int t = 1; t < 16; ++t) mm = fmaxf(mm, red[tid][t]);
        partial6[((size_t)b * 1024 + o0 + tid) * 32 + ntile] = mm;
    }
}

__global__ void final_k(const float* __restrict__ partial6, const float* __restrict__ b6,
                        float* __restrict__ dout) {
    int t = blockIdx.x * 256 + threadIdx.x;  // < 16*1024
    int o = t & 1023;
    float m = NEG_INF;
    #pragma unroll 1
    for (int nt = 0; nt < 32; ++nt) m = fmaxf(m, partial6[(size_t)t * 32 + nt]);
    dout[(size_t)BB * 192 * NN + t] = m + b6[o];
}

// ---------------------------------------------------------------------------
extern "C" void kernel_launch(void* const* d_in, const int* in_sizes, int n_in,
                              void* d_out_, int out_size, void* d_ws, size_t ws_size,
                              hipStream_t stream) {
    (void)in_sizes; (void)n_in; (void)out_size; (void)ws_size;
    const float* x  = (const float*)d_in[0];
    const float* w1 = (const float*)d_in[1];
    const float* b1 = (const float*)d_in[2];
    const float* w2 = (const float*)d_in[3];
    const float* b2 = (const float*)d_in[4];
    const float* w3 = (const float*)d_in[5];
    const float* b3 = (const float*)d_in[6];
    const float* w4 = (const float*)d_in[7];
    const float* b4 = (const float*)d_in[8];
    const float* w5 = (const float*)d_in[9];
    const float* b5 = (const float*)d_in[10];
    const float* w6 = (const float*)d_in[11];
    const float* b6 = (const float*)d_in[12];
    float* dout = (float*)d_out_;

    char* ws = (char*)d_ws;
    float*  x123t    = (float*)(ws + 0);           // 25,165,824 B
    int*    idxb     = (int*)(ws + 25165824);      //  2,621,440 B
    float*  nrm      = (float*)(ws + 27787264);    //    131,072 B
    float*  partial6 = (float*)(ws + 27918336);    //  2,097,152 B
    double* wd2      = (double*)(ws + 30015488);   //    135,680 B
    // region: pd (2 batches x 16MB) OR Ad+Bd (16MB each). Never live together.
    char*   region   = ws + 30151168;              // 33,554,432 B  (total ~60.8 MB)
    float*  pd = (float*)region;
    double* Ad = (double*)region;
    double* Bd = (double*)(region + 16777216);
    const int nb = 2;

    prep_cmp<<<1, 256, 0, stream>>>(w1, b1, w2, b2, w3, b3, w4, b4, w5, b5, wd2);

    // ---- block 1 ----
    knn1_k<<<dim3(1024, BB), 128, 0, stream>>>(x, idxb);
    ab1_k<<<8192, 256, 0, stream>>>(x, wd2, Ad, Bd);
    gmax_k<<<8192, 256, 0, stream>>>(Ad, Bd, idxb, 0, dout, x123t);

    // ---- knn on x1 (tiled GEMM + select, frozen arithmetic) ----
    norms23_k<<<128, 256, 0, stream>>>(x123t, 0, nrm);
    for (int b0 = 0; b0 < BB; b0 += nb) {
        gemm_pd_k<<<dim3(32, 32, nb), 256, 0, stream>>>(dout, 0, nrm, pd, b0);
        select_k<<<dim3(512, nb), 256, 0, stream>>>(pd, idxb, b0);
    }
    // ---- block 2 (A/B overwrite pd region; pd dead after select) ----
    ab23_k<<<512, 256, 0, stream>>>(x123t, wd2, 0, 448, 4544, 8640, Ad, Bd);
    gmax_k<<<8192, 256, 0, stream>>>(Ad, Bd, idxb, 64, dout, x123t);

    // ---- knn on x2 ----
    norms23_k<<<128, 256, 0, stream>>>(x123t, 64, nrm);
    for (int b0 = 0; b0 < BB; b0 += nb) {
        gemm_pd_k<<<dim3(32, 32, nb), 256, 0, stream>>>(dout, 64, nrm, pd, b0);
        select_k<<<dim3(512, nb), 256, 0, stream>>>(pd, idxb, b0);
    }
    // ---- block 3 ----
    ab23_k<<<512, 256, 0, stream>>>(x123t, wd2, 64, 8704, 12800, 16896, Ad, Bd);
    gmax_k<<<8192, 256, 0, stream>>>(Ad, Bd, idxb, 128, dout, x123t);

    // ---- final conv1d + global max ----
    w6_k<<<8192, 256, 0, stream>>>(x123t, w6, partial6);
    final_k<<<64, 256, 0, stream>>>(partial6, b6, dout);
}

// Round 18
// 1537.449 us; speedup vs baseline: 1.2412x; 1.0780x over previous
//
#include <hip/hip_runtime.h>

// Problem constants
#define BB 16
#define NN 2048
#define KK 20

#define NEG_INF (-3.402823466e+38f)
#define DNEG (-1.0e300)

// ---------------------------------------------------------------------------
// Composed fp64 weights (layout in wd2, doubles):
//  M1[3][64]@0   Md1[3][64]@192 (=Mh1-M1)   g01[64]@384
//  M2[64][64]@448   Md2[64][64]@4544 (=Mh2-M2)   g02[64]@8640
//  W5[64][64]@8704 (=w5lo[c][o])  W5d[64][64]@12800 (=w5hi-w5lo)  b5d[64]@16896
// ---------------------------------------------------------------------------
__global__ void prep_cmp(const float* __restrict__ w1, const float* __restrict__ b1,
                         const float* __restrict__ w2, const float* __restrict__ b2,
                         const float* __restrict__ w3, const float* __restrict__ b3,
                         const float* __restrict__ w4, const float* __restrict__ b4,
                         const float* __restrict__ w5, const float* __restrict__ b5,
                         double* __restrict__ wd2) {
    int t = threadIdx.x;
    for (int i = t; i < 192; i += 256) {
        int c = i >> 6, o = i & 63;
        double s = 0, sh = 0;
        for (int j = 0; j < 64; ++j) {
            double w2v = (double)w2[o * 64 + j];
            s  = fma(w2v, (double)w1[j * 6 + c], s);
            sh = fma(w2v, (double)w1[j * 6 + 3 + c], sh);
        }
        wd2[i] = s;
        wd2[192 + i] = sh - s;
    }
    for (int i = t; i < 64; i += 256) {
        double s = (double)b2[i];
        for (int j = 0; j < 64; ++j)
            s = fma((double)w2[i * 64 + j], (double)b1[j], s);
        wd2[384 + i] = s;
        double s2 = (double)b4[i];
        for (int j = 0; j < 64; ++j)
            s2 = fma((double)w4[i * 64 + j], (double)b3[j], s2);
        wd2[8640 + i] = s2;
        wd2[16896 + i] = (double)b5[i];
    }
    for (int i = t; i < 4096; i += 256) {
        int c = i >> 6, o = i & 63;
        double s = 0, sh = 0;
        for (int j = 0; j < 64; ++j) {
            double w4v = (double)w4[o * 64 + j];
            s  = fma(w4v, (double)w3[j * 128 + c], s);
            sh = fma(w4v, (double)w3[j * 128 + 64 + c], sh);
        }
        wd2[448 + i] = s;         // M2[c][o]
        wd2[4544 + i] = sh - s;   // Md2[c][o]
        double lo = (double)w5[o * 128 + c];
        wd2[8704 + i] = lo;                                  // W5[c][o]
        wd2[12800 + i] = (double)w5[o * 128 + 64 + c] - lo;  // W5d[c][o]
    }
}

// ---------------------------------------------------------------------------
// Packed-key top-20 selection. key = (orderable(value) << 32) | (2047 - col).
// Max key == max value with lowest-col tie-break (identical to frozen float
// semantics). Keys unique -> exactly one owner lane per winner.
// ---------------------------------------------------------------------------
__device__ __forceinline__ unsigned long long pkey(float v, int col) {
    float vc = __fadd_rn(v, 0.0f);   // -0 -> +0 (real instruction)
    unsigned u = __float_as_uint(vc);
    unsigned s = (unsigned)((int)u >> 31);
    unsigned m = u ^ (s | 0x80000000u);
    return ((unsigned long long)m << 32) | (unsigned)(2047 - col);
}

__device__ __forceinline__ void top2k_upd(unsigned long long k,
        unsigned long long& ka, unsigned long long& kb) {
    bool gta = k > ka;
    bool gtb = k > kb;
    unsigned long long nkb = gta ? ka : (gtb ? k : kb);
    ka = gta ? k : ka;
    kb = nkb;
}

__device__ __forceinline__ void topk20_key(float* vrow, int lane,
        unsigned long long ka, unsigned long long kb, int* outp) {
    int myout = 0;
    #pragma unroll 1
    for (int it = 0; it < 20; ++it) {
        unsigned long long wk = ka;
        #pragma unroll
        for (int d = 32; d; d >>= 1) {
            unsigned long long o = __shfl_xor(wk, d);
            wk = (o > wk) ? o : wk;
        }
        int widx = 2047 - (int)(wk & 0xFFFFFFFFull);
        if (lane == it) myout = widx;
        if (ka == wk) {                  // unique owner pops + marks removed
            vrow[widx] = NEG_INF;
            ka = kb;
            kb = 0ULL;
        }
        if (ka == 0ULL) {                // rare: lane's top-2 exhausted
            kb = 0ULL;
            #pragma unroll 1
            for (int s = 0; s < 32; ++s) {
                int col = s * 64 + lane;
                top2k_upd(pkey(vrow[col], col), ka, kb);
            }
        }
    }
    if (lane < 20) outp[lane] = myout;
}

// ---------------------------------------------------------------------------
// xx for raw x (C=3): FROZEN chain fadd(fadd(mul,mul),mul).
// ---------------------------------------------------------------------------
__global__ void norms1_k(const float* __restrict__ x, float* __restrict__ nrm) {
    int t = blockIdx.x * 256 + threadIdx.x;   // 32768 points
    int b = t >> 11, n = t & 2047;
    const float* xb = x + (size_t)b * 3 * NN;
    float cx = xb[n], cy = xb[NN + n], cz = xb[2 * NN + n];
    nrm[t] = __fadd_rn(__fadd_rn(__fmul_rn(cx, cx), __fmul_rn(cy, cy)),
                       __fmul_rn(cz, cz));
}

// knn1: numpy-f32 mirror, FROZEN distance arithmetic (norms preloaded,
// bit-identical to in-line recompute).
__global__ void knn1_k(const float* __restrict__ x, const float* __restrict__ nrm,
                       int* __restrict__ idx) {
    __shared__ float vlds[2][2048];
    int lane = threadIdx.x & 63, w = threadIdx.x >> 6;
    int b = blockIdx.y, r = blockIdx.x * 2 + w;
    const float* xb = x + (size_t)b * 3 * NN;
    const float* nb_ = nrm + (size_t)b * NN;
    float rx = xb[r], ry = xb[NN + r], rz = xb[2 * NN + r];
    float xxi = nb_[r];
    float* vrow = vlds[w];
    unsigned long long ka = 0ULL, kb = 0ULL;
    #pragma unroll 1
    for (int s = 0; s < 32; ++s) {
        int col = s * 64 + lane;
        float cx = xb[col], cy = xb[NN + col], cz = xb[2 * NN + col];
        float xxj = nb_[col];
        float dot = fmaf(rz, cz, fmaf(ry, cy, __fmul_rn(rx, cx)));
        float inner = __fmul_rn(-2.f, dot);
        float t1 = __fsub_rn(-xxj, inner);
        float nd = __fsub_rn(t1, xxi);
        vrow[col] = nd;
        top2k_upd(pkey(nd, col), ka, kb);
    }
    topk20_key(vrow, lane, ka, kb, idx + ((size_t)b * NN + r) * KK);
}

// xx for a 64-channel slice. FROZEN.
__global__ void norms23_k(const float* __restrict__ x123t, int coff,
                          float* __restrict__ nrm) {
    int t = blockIdx.x * 256 + threadIdx.x;   // 32768 points
    const float* r = x123t + (size_t)t * 192 + coff;
    float acc = 0.f;
    #pragma unroll 1
    for (int c = 0; c < 64; ++c)
        acc = __fadd_rn(acc, __fmul_rn(r[c], r[c]));
    nrm[t] = acc;
}

// ---------------------------------------------------------------------------
// pd GEMM (knn2/3 distances). FROZEN chain + epilogue.
// ---------------------------------------------------------------------------
__global__ __launch_bounds__(256) void gemm_pd_k(const float* __restrict__ dout,
        int coff, const float* __restrict__ nrm, float* __restrict__ pd, int b0) {
    __shared__ float As[64][68];
    __shared__ float Bs[64][68];
    int b = b0 + blockIdx.z;
    int rb = blockIdx.y * 64, cb = blockIdx.x * 64;
    const float* doutc = dout + (size_t)(b * 192 + coff) * NN;
    int tid = threadIdx.x;
    int cq = tid >> 4, qd = (tid & 15) * 4;
    #pragma unroll
    for (int cc = 0; cc < 64; cc += 16) {
        float4 a = *(const float4*)(doutc + (size_t)(cc + cq) * NN + rb + qd);
        As[cc + cq][qd + 0] = a.x; As[cc + cq][qd + 1] = a.y;
        As[cc + cq][qd + 2] = a.z; As[cc + cq][qd + 3] = a.w;
        float4 bv = *(const float4*)(doutc + (size_t)(cc + cq) * NN + cb + qd);
        Bs[cc + cq][qd + 0] = bv.x; Bs[cc + cq][qd + 1] = bv.y;
        Bs[cc + cq][qd + 2] = bv.z; Bs[cc + cq][qd + 3] = bv.w;
    }
    __syncthreads();
    int tx = tid & 15, ty = tid >> 4;
    float acc[4][4];
    #pragma unroll
    for (int i = 0; i < 4; ++i)
        #pragma unroll
        for (int j = 0; j < 4; ++j) acc[i][j] = 0.f;
    #pragma unroll 4
    for (int c = 0; c < 64; ++c) {
        float4 av4 = *(const float4*)&As[c][ty * 4];
        float4 bv4 = *(const float4*)&Bs[c][tx * 4];
        float aa[4] = {av4.x, av4.y, av4.z, av4.w};
        float bb[4] = {bv4.x, bv4.y, bv4.z, bv4.w};
        #pragma unroll
        for (int i = 0; i < 4; ++i)
            #pragma unroll
            for (int j = 0; j < 4; ++j)
                acc[i][j] = fmaf(aa[i], bb[j], acc[i][j]);  // ascending-c chain
    }
    const float* nb_ = nrm + (size_t)b * NN;
    #pragma unroll
    for (int i = 0; i < 4; ++i) {
        int r = rb + ty * 4 + i;
        float xxi = nb_[r];
        float4 o4;
        float* o = (float*)&o4;
        #pragma unroll
        for (int j = 0; j < 4; ++j) {
            float xxj = nb_[cb + tx * 4 + j];
            float inner = __fmul_rn(-2.f, acc[i][j]);
            float t1 = __fsub_rn(-xxj, inner);
            o[j] = __fsub_rn(t1, xxi);
        }
        *(float4*)(pd + ((size_t)blockIdx.z * NN + r) * NN + cb + tx * 4) = o4;
    }
}

// selection from materialized pd chunk (packed-key, frozen semantics)
__global__ void select_k(const float* __restrict__ pd, int* __restrict__ idx, int b0) {
    __shared__ float vlds[4][2048];
    int lane = threadIdx.x & 63, w = threadIdx.x >> 6;
    int bb = blockIdx.y, r = blockIdx.x * 4 + w;
    const float* row = pd + ((size_t)bb * NN + r) * NN;
    float* vrow = vlds[w];
    unsigned long long ka = 0ULL, kb = 0ULL;
    #pragma unroll 1
    for (int s = 0; s < 32; ++s) {
        int col = s * 64 + lane;
        float v = row[col];
        vrow[col] = v;
        top2k_upd(pkey(v, col), ka, kb);
    }
    topk20_key(vrow, lane, ka, kb, idx + ((size_t)(b0 + bb) * NN + r) * KK);
}

// ---------------------------------------------------------------------------
// EdgeConv via A/B decomposition:
//   h[n,k,o] = A[n][o] + B[idx[n][k]][o];  max_k commutes with + (monotone).
// ---------------------------------------------------------------------------
__global__ __launch_bounds__(256) void ab1_k(const float* __restrict__ x,
        const double* __restrict__ wd2, double* __restrict__ Ad,
        double* __restrict__ Bd) {
    int tid = threadIdx.x, lane = tid & 63, w = tid >> 6;
    int p = blockIdx.x * 4 + w, b = p >> 11, n = p & 2047;
    const float* xb = x + (size_t)b * 3 * NN;
    double c0 = (double)xb[n], c1 = (double)xb[NN + n], c2 = (double)xb[2 * NN + n];
    double A = wd2[384 + lane];
    A = fma(wd2[192 + 0 * 64 + lane], c0, A);
    A = fma(wd2[192 + 1 * 64 + lane], c1, A);
    A = fma(wd2[192 + 2 * 64 + lane], c2, A);
    double B = wd2[0 * 64 + lane] * c0;
    B = fma(wd2[1 * 64 + lane], c1, B);
    B = fma(wd2[2 * 64 + lane], c2, B);
    Ad[(size_t)p * 64 + lane] = A;
    Bd[(size_t)p * 64 + lane] = B;
}

// conv2/conv3 A/B: block = 4 waves x 16 points. W (main) staged in LDS;
// Wd (delta) read from global (L1/L2-hot).
__global__ __launch_bounds__(256) void ab23_k(const float* __restrict__ x123t,
        const double* __restrict__ wd2, int coff, int woffW, int woffWd, int goff,
        double* __restrict__ Ad, double* __restrict__ Bd) {
    __shared__ double Ws[4096];      // 32 KB
    __shared__ double ctr[4][64];    // 2 KB
    int tid = threadIdx.x, lane = tid & 63, w = tid >> 6;
    for (int i = tid; i < 4096; i += 256) Ws[i] = wd2[woffW + i];
    __syncthreads();
    int p0 = blockIdx.x * 64 + w * 16;
    #pragma unroll 1
    for (int it = 0; it < 16; ++it) {
        int p = p0 + it, b = p >> 11, n = p & 2047;
        ctr[w][lane] = (double)x123t[((size_t)b * NN + n) * 192 + coff + lane];
        double a0 = wd2[goff + lane], a1 = 0, a2 = 0, a3 = 0;
        double q0 = 0, q1 = 0, q2 = 0, q3 = 0;
        #pragma unroll
        for (int c = 0; c < 64; c += 4) {
            double x0 = ctr[w][c + 0], x1 = ctr[w][c + 1];
            double x2 = ctr[w][c + 2], x3 = ctr[w][c + 3];
            a0 = fma(wd2[woffWd + (c + 0) * 64 + lane], x0, a0);
            a1 = fma(wd2[woffWd + (c + 1) * 64 + lane], x1, a1);
            a2 = fma(wd2[woffWd + (c + 2) * 64 + lane], x2, a2);
            a3 = fma(wd2[woffWd + (c + 3) * 64 + lane], x3, a3);
            q0 = fma(Ws[(c + 0) * 64 + lane], x0, q0);
            q1 = fma(Ws[(c + 1) * 64 + lane], x1, q1);
            q2 = fma(Ws[(c + 2) * 64 + lane], x2, q2);
            q3 = fma(Ws[(c + 3) * 64 + lane], x3, q3);
        }
        Ad[(size_t)p * 64 + lane] = (a0 + a1) + (a2 + a3);
        Bd[(size_t)p * 64 + lane] = (q0 + q1) + (q2 + q3);
    }
}

__global__ __launch_bounds__(256) void gmax_k(const double* __restrict__ Ad,
        const double* __restrict__ Bd, const int* __restrict__ idxb, int cho,
        float* __restrict__ dout, float* __restrict__ x123t_o) {
    int tid = threadIdx.x, lane = tid & 63, w = tid >> 6;
    int p = blockIdx.x * 4 + w, b = p >> 11, n = p & 2047;
    const int* ip = idxb + (size_t)p * KK;
    size_t boff = (size_t)(b << 11);
    double m = DNEG;
    int nbc = ip[0];
    double v = Bd[(boff + nbc) * 64 + lane];
    #pragma unroll 1
    for (int kk = 0; kk < KK; ++kk) {
        double cur = v;
        if (kk < KK - 1) {
            int nbn = ip[kk + 1];
            v = Bd[(boff + nbn) * 64 + lane];
        }
        m = fmax(m, cur);
    }
    double out = Ad[(size_t)p * 64 + lane] + m;
    dout[((size_t)b * 192 + cho + lane) * NN + n] = (float)out;
    x123t_o[((size_t)b * NN + n) * 192 + cho + lane] = (float)out;
}

// ---------------------------------------------------------------------------
// Final conv1d (1024x192) as LDS-tiled f32 GEMM, 64o x 64n per block, KC=32.
// ---------------------------------------------------------------------------
#define KC 32
__global__ __launch_bounds__(256) void w6_k(const float* __restrict__ x123t,
                                            const float* __restrict__ w6,
                                            float* __restrict__ partial6) {
    __shared__ float xs[KC][68];
    __shared__ float wsb[KC][68];
    __shared__ float red[64][17];
    int tid = threadIdx.x;
    int ntile = blockIdx.x & 31, ot = (blockIdx.x >> 5) & 15, b = blockIdx.x >> 9;
    int n0 = ntile * 64, o0 = ot * 64;
    int ln = tid >> 2, lc = (tid & 3) * 8;
    const float* xrow = x123t + ((size_t)b * NN + n0 + ln) * 192 + lc;
    const float* wrow = w6 + (size_t)(o0 + ln) * 192 + lc;
    float acc[4][4];
    #pragma unroll
    for (int i = 0; i < 4; ++i)
        #pragma unroll
        for (int j = 0; j < 4; ++j) acc[i][j] = 0.f;
    int to = tid & 15, tn = tid >> 4;
    for (int cc = 0; cc < 192; cc += KC) {
        float4 xa = *(const float4*)(xrow + cc);
        float4 xb4 = *(const float4*)(xrow + cc + 4);
        float4 wa = *(const float4*)(wrow + cc);
        float4 wb4 = *(const float4*)(wrow + cc + 4);
        __syncthreads();
        xs[lc + 0][ln] = xa.x; xs[lc + 1][ln] = xa.y;
        xs[lc + 2][ln] = xa.z; xs[lc + 3][ln] = xa.w;
        xs[lc + 4][ln] = xb4.x; xs[lc + 5][ln] = xb4.y;
        xs[lc + 6][ln] = xb4.z; xs[lc + 7][ln] = xb4.w;
        wsb[lc + 0][ln] = wa.x; wsb[lc + 1][ln] = wa.y;
        wsb[lc + 2][ln] = wa.z; wsb[lc + 3][ln] = wa.w;
        wsb[lc + 4][ln] = wb4.x; wsb[lc + 5][ln] = wb4.y;
        wsb[lc + 6][ln] = wb4.z; wsb[lc + 7][ln] = wb4.w;
        __syncthreads();
        #pragma unroll
        for (int k = 0; k < KC; ++k) {
            float4 wv = *(const float4*)&wsb[k][to * 4];
            float4 xv = *(const float4*)&xs[k][tn * 4];
            float wr[4] = {wv.x, wv.y, wv.z, wv.w};
            float xr[4] = {xv.x, xv.y, xv.z, xv.w};
            #pragma unroll
            for (int i = 0; i < 4; ++i)
                #pragma unroll
                for (int j = 0; j < 4; ++j)
                    acc[i][j] = fmaf(wr[i], xr[j], acc[i][j]);
        }
    }
    #pragma unroll
    for (int i = 0; i < 4; ++i) {
        float mm = fmaxf(fmaxf(acc[i][0], acc[i][1]), fmaxf(acc[i][2], acc[i][3]));
        red[to * 4 + i][tn] = mm;
    }
    __syncthreads();
    if (tid < 64) {
        float mm = red[tid][0];
        #pragma unroll
        for (int t = 1; t < 16; ++t) mm = fmaxf(mm, red[tid][t]);
        partial6[((size_t)b * 1024 + o0 + tid) * 32 + ntile] = mm;
    }
}

__global__ void final_k(const float* __restrict__ partial6, const float* __restrict__ b6,
                        float* __restrict__ dout) {
    int t = blockIdx.x * 256 + threadIdx.x;  // < 16*1024
    int o = t & 1023;
    float m = NEG_INF;
    #pragma unroll 1
    for (int nt = 0; nt < 32; ++nt) m = fmaxf(m, partial6[(size_t)t * 32 + nt]);
    dout[(size_t)BB * 192 * NN + t] = m + b6[o];
}

// ---------------------------------------------------------------------------
extern "C" void kernel_launch(void* const* d_in, const int* in_sizes, int n_in,
                              void* d_out_, int out_size, void* d_ws, size_t ws_size,
                              hipStream_t stream) {
    (void)in_sizes; (void)n_in; (void)out_size; (void)ws_size;
    const float* x  = (const float*)d_in[0];
    const float* w1 = (const float*)d_in[1];
    const float* b1 = (const float*)d_in[2];
    const float* w2 = (const float*)d_in[3];
    const float* b2 = (const float*)d_in[4];
    const float* w3 = (const float*)d_in[5];
    const float* b3 = (const float*)d_in[6];
    const float* w4 = (const float*)d_in[7];
    const float* b4 = (const float*)d_in[8];
    const float* w5 = (const float*)d_in[9];
    const float* b5 = (const float*)d_in[10];
    const float* w6 = (const float*)d_in[11];
    const float* b6 = (const float*)d_in[12];
    float* dout = (float*)d_out_;

    char* ws = (char*)d_ws;
    float*  x123t    = (float*)(ws + 0);           // 25,165,824 B
    int*    idxb     = (int*)(ws + 25165824);      //  2,621,440 B
    float*  nrm      = (float*)(ws + 27787264);    //    131,072 B
    float*  partial6 = (float*)(ws + 27918336);    //  2,097,152 B
    double* wd2      = (double*)(ws + 30015488);   //    135,680 B
    // region: pd (4 batches x 16MB) OR Ad+Bd (16MB each). Never live together.
    // Total ws use ~92.8 MB (rounds 13/14 proved >= 94 MB available).
    char*   region   = ws + 30151168;              // 67,108,864 B
    float*  pd = (float*)region;
    double* Ad = (double*)region;
    double* Bd = (double*)(region + 16777216);
    const int nb = 4;

    prep_cmp<<<1, 256, 0, stream>>>(w1, b1, w2, b2, w3, b3, w4, b4, w5, b5, wd2);

    // ---- block 1 ----
    norms1_k<<<128, 256, 0, stream>>>(x, nrm);
    knn1_k<<<dim3(1024, BB), 128, 0, stream>>>(x, nrm, idxb);
    ab1_k<<<8192, 256, 0, stream>>>(x, wd2, Ad, Bd);
    gmax_k<<<8192, 256, 0, stream>>>(Ad, Bd, idxb, 0, dout, x123t);

    // ---- knn on x1 (tiled GEMM + select, frozen arithmetic) ----
    norms23_k<<<128, 256, 0, stream>>>(x123t, 0, nrm);
    for (int b0 = 0; b0 < BB; b0 += nb) {
        gemm_pd_k<<<dim3(32, 32, nb), 256, 0, stream>>>(dout, 0, nrm, pd, b0);
        select_k<<<dim3(512, nb), 256, 0, stream>>>(pd, idxb, b0);
    }
    // ---- block 2 (A/B overwrite pd region; pd dead after select) ----
    ab23_k<<<512, 256, 0, stream>>>(x123t, wd2, 0, 448, 4544, 8640, Ad, Bd);
    gmax_k<<<8192, 256, 0, stream>>>(Ad, Bd, idxb, 64, dout, x123t);

    // ---- knn on x2 ----
    norms23_k<<<128, 256, 0, stream>>>(x123t, 64, nrm);
    for (int b0 = 0; b0 < BB; b0 += nb) {
        gemm_pd_k<<<dim3(32, 32, nb), 256, 0, stream>>>(dout, 64, nrm, pd, b0);
        select_k<<<dim3(512, nb), 256, 0, stream>>>(pd, idxb, b0);
    }
    // ---- block 3 ----
    ab23_k<<<512, 256, 0, stream>>>(x123t, wd2, 64, 8704, 12800, 16896, Ad, Bd);
    gmax_k<<<8192, 256, 0, stream>>>(Ad, Bd, idxb, 128, dout, x123t);

    // ---- final conv1d + global max ----
    w6_k<<<8192, 256, 0, stream>>>(x123t, w6, partial6);
    final_k<<<64, 256, 0, stream>>>(partial6, b6, dout);
}

// Round 19
// 1358.182 us; speedup vs baseline: 1.4050x; 1.1320x over previous
//
#include <hip/hip_runtime.h>

// Problem constants
#define BB 16
#define NN 2048
#define KK 20

#define NEG_INF (-3.402823466e+38f)
#define DNEG (-1.0e300)

// ---------------------------------------------------------------------------
// Composed fp64 weights (layout in wd2, doubles):
//  M1[3][64]@0   Md1[3][64]@192 (=Mh1-M1)   g01[64]@384
//  M2[64][64]@448   Md2[64][64]@4544 (=Mh2-M2)   g02[64]@8640
//  W5[64][64]@8704 (=w5lo[c][o])  W5d[64][64]@12800 (=w5hi-w5lo)  b5d[64]@16896
// ---------------------------------------------------------------------------
__global__ void prep_cmp(const float* __restrict__ w1, const float* __restrict__ b1,
                         const float* __restrict__ w2, const float* __restrict__ b2,
                         const float* __restrict__ w3, const float* __restrict__ b3,
                         const float* __restrict__ w4, const float* __restrict__ b4,
                         const float* __restrict__ w5, const float* __restrict__ b5,
                         double* __restrict__ wd2) {
    int t = threadIdx.x;
    for (int i = t; i < 192; i += 256) {
        int c = i >> 6, o = i & 63;
        double s = 0, sh = 0;
        for (int j = 0; j < 64; ++j) {
            double w2v = (double)w2[o * 64 + j];
            s  = fma(w2v, (double)w1[j * 6 + c], s);
            sh = fma(w2v, (double)w1[j * 6 + 3 + c], sh);
        }
        wd2[i] = s;
        wd2[192 + i] = sh - s;
    }
    for (int i = t; i < 64; i += 256) {
        double s = (double)b2[i];
        for (int j = 0; j < 64; ++j)
            s = fma((double)w2[i * 64 + j], (double)b1[j], s);
        wd2[384 + i] = s;
        double s2 = (double)b4[i];
        for (int j = 0; j < 64; ++j)
            s2 = fma((double)w4[i * 64 + j], (double)b3[j], s2);
        wd2[8640 + i] = s2;
        wd2[16896 + i] = (double)b5[i];
    }
    for (int i = t; i < 4096; i += 256) {
        int c = i >> 6, o = i & 63;
        double s = 0, sh = 0;
        for (int j = 0; j < 64; ++j) {
            double w4v = (double)w4[o * 64 + j];
            s  = fma(w4v, (double)w3[j * 128 + c], s);
            sh = fma(w4v, (double)w3[j * 128 + 64 + c], sh);
        }
        wd2[448 + i] = s;         // M2[c][o]
        wd2[4544 + i] = sh - s;   // Md2[c][o]
        double lo = (double)w5[o * 128 + c];
        wd2[8704 + i] = lo;                                  // W5[c][o]
        wd2[12800 + i] = (double)w5[o * 128 + 64 + c] - lo;  // W5d[c][o]
    }
}

// ---------------------------------------------------------------------------
// Packed-key top-20 selection. key = (orderable(value) << 32) | (2047 - col).
// Max key == max value with lowest-col tie-break. Keys unique -> one owner.
// Lane's column set: cols s*256 + lane*4 + q for s in 0..7, q in 0..3
// (blocked float4 mapping; set-max is order-independent, so identical
// winner sequence to any other mapping as long as rescan matches).
// ---------------------------------------------------------------------------
__device__ __forceinline__ unsigned long long pkey(float v, int col) {
    float vc = __fadd_rn(v, 0.0f);   // -0 -> +0 (real instruction)
    unsigned u = __float_as_uint(vc);
    unsigned s = (unsigned)((int)u >> 31);
    unsigned m = u ^ (s | 0x80000000u);
    return ((unsigned long long)m << 32) | (unsigned)(2047 - col);
}

__device__ __forceinline__ void top2k_upd(unsigned long long k,
        unsigned long long& ka, unsigned long long& kb) {
    bool gta = k > ka;
    bool gtb = k > kb;
    unsigned long long nkb = gta ? ka : (gtb ? k : kb);
    ka = gta ? k : ka;
    kb = nkb;
}

__device__ __forceinline__ void topk20_key(float* vrow, int lane,
        unsigned long long ka, unsigned long long kb, int* outp) {
    int myout = 0;
    #pragma unroll 1
    for (int it = 0; it < 20; ++it) {
        unsigned long long wk = ka;
        #pragma unroll
        for (int d = 32; d; d >>= 1) {
            unsigned long long o = __shfl_xor(wk, d);
            wk = (o > wk) ? o : wk;
        }
        int widx = 2047 - (int)(wk & 0xFFFFFFFFull);
        if (lane == it) myout = widx;
        if (ka == wk) {                  // unique owner pops + marks removed
            vrow[widx] = NEG_INF;
            ka = kb;
            kb = 0ULL;
        }
        if (ka == 0ULL) {                // rare: lane's top-2 exhausted
            kb = 0ULL;
            #pragma unroll 1
            for (int s = 0; s < 8; ++s) {    // SAME blocked float4 mapping
                int base = s * 256 + lane * 4;
                float4 v4 = *(const float4*)&vrow[base];
                top2k_upd(pkey(v4.x, base + 0), ka, kb);
                top2k_upd(pkey(v4.y, base + 1), ka, kb);
                top2k_upd(pkey(v4.z, base + 2), ka, kb);
                top2k_upd(pkey(v4.w, base + 3), ka, kb);
            }
        }
    }
    if (lane < 20) outp[lane] = myout;
}

// ---------------------------------------------------------------------------
// xx for raw x (C=3): FROZEN chain fadd(fadd(mul,mul),mul).
// ---------------------------------------------------------------------------
__global__ void norms1_k(const float* __restrict__ x, float* __restrict__ nrm) {
    int t = blockIdx.x * 256 + threadIdx.x;   // 32768 points
    int b = t >> 11, n = t & 2047;
    const float* xb = x + (size_t)b * 3 * NN;
    float cx = xb[n], cy = xb[NN + n], cz = xb[2 * NN + n];
    nrm[t] = __fadd_rn(__fadd_rn(__fmul_rn(cx, cx), __fmul_rn(cy, cy)),
                       __fmul_rn(cz, cz));
}

// knn1: numpy-f32 mirror, FROZEN per-col distance arithmetic; float4 scan.
__global__ void knn1_k(const float* __restrict__ x, const float* __restrict__ nrm,
                       int* __restrict__ idx) {
    __shared__ float vlds[2][2048];
    int lane = threadIdx.x & 63, w = threadIdx.x >> 6;
    int b = blockIdx.y, r = blockIdx.x * 2 + w;
    const float* xb = x + (size_t)b * 3 * NN;
    const float* nb_ = nrm + (size_t)b * NN;
    float rx = xb[r], ry = xb[NN + r], rz = xb[2 * NN + r];
    float xxi = nb_[r];
    float* vrow = vlds[w];
    unsigned long long ka = 0ULL, kb = 0ULL;
    #pragma unroll 1
    for (int s = 0; s < 8; ++s) {
        int base = s * 256 + lane * 4;
        float4 cx = *(const float4*)&xb[base];
        float4 cy = *(const float4*)&xb[NN + base];
        float4 cz = *(const float4*)&xb[2 * NN + base];
        float4 xx4 = *(const float4*)&nb_[base];
        float4 nd4;
        {   // col base+0  (frozen chain)
            float dot = fmaf(rz, cz.x, fmaf(ry, cy.x, __fmul_rn(rx, cx.x)));
            float inner = __fmul_rn(-2.f, dot);
            float t1 = __fsub_rn(-xx4.x, inner);
            nd4.x = __fsub_rn(t1, xxi);
        }
        {   // col base+1
            float dot = fmaf(rz, cz.y, fmaf(ry, cy.y, __fmul_rn(rx, cx.y)));
            float inner = __fmul_rn(-2.f, dot);
            float t1 = __fsub_rn(-xx4.y, inner);
            nd4.y = __fsub_rn(t1, xxi);
        }
        {   // col base+2
            float dot = fmaf(rz, cz.z, fmaf(ry, cy.z, __fmul_rn(rx, cx.z)));
            float inner = __fmul_rn(-2.f, dot);
            float t1 = __fsub_rn(-xx4.z, inner);
            nd4.z = __fsub_rn(t1, xxi);
        }
        {   // col base+3
            float dot = fmaf(rz, cz.w, fmaf(ry, cy.w, __fmul_rn(rx, cx.w)));
            float inner = __fmul_rn(-2.f, dot);
            float t1 = __fsub_rn(-xx4.w, inner);
            nd4.w = __fsub_rn(t1, xxi);
        }
        *(float4*)&vrow[base] = nd4;
        top2k_upd(pkey(nd4.x, base + 0), ka, kb);
        top2k_upd(pkey(nd4.y, base + 1), ka, kb);
        top2k_upd(pkey(nd4.z, base + 2), ka, kb);
        top2k_upd(pkey(nd4.w, base + 3), ka, kb);
    }
    topk20_key(vrow, lane, ka, kb, idx + ((size_t)b * NN + r) * KK);
}

// xx for a 64-channel slice. FROZEN.
__global__ void norms23_k(const float* __restrict__ x123t, int coff,
                          float* __restrict__ nrm) {
    int t = blockIdx.x * 256 + threadIdx.x;   // 32768 points
    const float* r = x123t + (size_t)t * 192 + coff;
    float acc = 0.f;
    #pragma unroll 1
    for (int c = 0; c < 64; ++c)
        acc = __fadd_rn(acc, __fmul_rn(r[c], r[c]));
    nrm[t] = acc;
}

// ---------------------------------------------------------------------------
// pd GEMM (knn2/3 distances). FROZEN chain + epilogue.
// ---------------------------------------------------------------------------
__global__ __launch_bounds__(256) void gemm_pd_k(const float* __restrict__ dout,
        int coff, const float* __restrict__ nrm, float* __restrict__ pd, int b0) {
    __shared__ float As[64][68];
    __shared__ float Bs[64][68];
    int b = b0 + blockIdx.z;
    int rb = blockIdx.y * 64, cb = blockIdx.x * 64;
    const float* doutc = dout + (size_t)(b * 192 + coff) * NN;
    int tid = threadIdx.x;
    int cq = tid >> 4, qd = (tid & 15) * 4;
    #pragma unroll
    for (int cc = 0; cc < 64; cc += 16) {
        float4 a = *(const float4*)(doutc + (size_t)(cc + cq) * NN + rb + qd);
        As[cc + cq][qd + 0] = a.x; As[cc + cq][qd + 1] = a.y;
        As[cc + cq][qd + 2] = a.z; As[cc + cq][qd + 3] = a.w;
        float4 bv = *(const float4*)(doutc + (size_t)(cc + cq) * NN + cb + qd);
        Bs[cc + cq][qd + 0] = bv.x; Bs[cc + cq][qd + 1] = bv.y;
        Bs[cc + cq][qd + 2] = bv.z; Bs[cc + cq][qd + 3] = bv.w;
    }
    __syncthreads();
    int tx = tid & 15, ty = tid >> 4;
    float acc[4][4];
    #pragma unroll
    for (int i = 0; i < 4; ++i)
        #pragma unroll
        for (int j = 0; j < 4; ++j) acc[i][j] = 0.f;
    #pragma unroll 4
    for (int c = 0; c < 64; ++c) {
        float4 av4 = *(const float4*)&As[c][ty * 4];
        float4 bv4 = *(const float4*)&Bs[c][tx * 4];
        float aa[4] = {av4.x, av4.y, av4.z, av4.w};
        float bb[4] = {bv4.x, bv4.y, bv4.z, bv4.w};
        #pragma unroll
        for (int i = 0; i < 4; ++i)
            #pragma unroll
            for (int j = 0; j < 4; ++j)
                acc[i][j] = fmaf(aa[i], bb[j], acc[i][j]);  // ascending-c chain
    }
    const float* nb_ = nrm + (size_t)b * NN;
    #pragma unroll
    for (int i = 0; i < 4; ++i) {
        int r = rb + ty * 4 + i;
        float xxi = nb_[r];
        float4 o4;
        float* o = (float*)&o4;
        #pragma unroll
        for (int j = 0; j < 4; ++j) {
            float xxj = nb_[cb + tx * 4 + j];
            float inner = __fmul_rn(-2.f, acc[i][j]);
            float t1 = __fsub_rn(-xxj, inner);
            o[j] = __fsub_rn(t1, xxi);
        }
        *(float4*)(pd + ((size_t)blockIdx.z * NN + r) * NN + cb + tx * 4) = o4;
    }
}

// selection from materialized pd chunk (packed-key, float4 scan)
__global__ void select_k(const float* __restrict__ pd, int* __restrict__ idx, int b0) {
    __shared__ float vlds[4][2048];
    int lane = threadIdx.x & 63, w = threadIdx.x >> 6;
    int bb = blockIdx.y, r = blockIdx.x * 4 + w;
    const float* row = pd + ((size_t)bb * NN + r) * NN;
    float* vrow = vlds[w];
    unsigned long long ka = 0ULL, kb = 0ULL;
    #pragma unroll 1
    for (int s = 0; s < 8; ++s) {
        int base = s * 256 + lane * 4;
        float4 v4 = *(const float4*)&row[base];
        *(float4*)&vrow[base] = v4;
        top2k_upd(pkey(v4.x, base + 0), ka, kb);
        top2k_upd(pkey(v4.y, base + 1), ka, kb);
        top2k_upd(pkey(v4.z, base + 2), ka, kb);
        top2k_upd(pkey(v4.w, base + 3), ka, kb);
    }
    topk20_key(vrow, lane, ka, kb, idx + ((size_t)(b0 + bb) * NN + r) * KK);
}

// ---------------------------------------------------------------------------
// EdgeConv via A/B decomposition:
//   h[n,k,o] = A[n][o] + B[idx[n][k]][o];  max_k commutes with + (monotone).
// ---------------------------------------------------------------------------
__global__ __launch_bounds__(256) void ab1_k(const float* __restrict__ x,
        const double* __restrict__ wd2, double* __restrict__ Ad,
        double* __restrict__ Bd) {
    int tid = threadIdx.x, lane = tid & 63, w = tid >> 6;
    int p = blockIdx.x * 4 + w, b = p >> 11, n = p & 2047;
    const float* xb = x + (size_t)b * 3 * NN;
    double c0 = (double)xb[n], c1 = (double)xb[NN + n], c2 = (double)xb[2 * NN + n];
    double A = wd2[384 + lane];
    A = fma(wd2[192 + 0 * 64 + lane], c0, A);
    A = fma(wd2[192 + 1 * 64 + lane], c1, A);
    A = fma(wd2[192 + 2 * 64 + lane], c2, A);
    double B = wd2[0 * 64 + lane] * c0;
    B = fma(wd2[1 * 64 + lane], c1, B);
    B = fma(wd2[2 * 64 + lane], c2, B);
    Ad[(size_t)p * 64 + lane] = A;
    Bd[(size_t)p * 64 + lane] = B;
}

// conv2/conv3 A/B: block = 4 waves x 16 points. W (main) staged in LDS;
// Wd (delta) read from global (L1/L2-hot).
__global__ __launch_bounds__(256) void ab23_k(const float* __restrict__ x123t,
        const double* __restrict__ wd2, int coff, int woffW, int woffWd, int goff,
        double* __restrict__ Ad, double* __restrict__ Bd) {
    __shared__ double Ws[4096];      // 32 KB
    __shared__ double ctr[4][64];    // 2 KB
    int tid = threadIdx.x, lane = tid & 63, w = tid >> 6;
    for (int i = tid; i < 4096; i += 256) Ws[i] = wd2[woffW + i];
    __syncthreads();
    int p0 = blockIdx.x * 64 + w * 16;
    #pragma unroll 1
    for (int it = 0; it < 16; ++it) {
        int p = p0 + it, b = p >> 11, n = p & 2047;
        ctr[w][lane] = (double)x123t[((size_t)b * NN + n) * 192 + coff + lane];
        double a0 = wd2[goff + lane], a1 = 0, a2 = 0, a3 = 0;
        double q0 = 0, q1 = 0, q2 = 0, q3 = 0;
        #pragma unroll
        for (int c = 0; c < 64; c += 4) {
            double x0 = ctr[w][c + 0], x1 = ctr[w][c + 1];
            double x2 = ctr[w][c + 2], x3 = ctr[w][c + 3];
            a0 = fma(wd2[woffWd + (c + 0) * 64 + lane], x0, a0);
            a1 = fma(wd2[woffWd + (c + 1) * 64 + lane], x1, a1);
            a2 = fma(wd2[woffWd + (c + 2) * 64 + lane], x2, a2);
            a3 = fma(wd2[woffWd + (c + 3) * 64 + lane], x3, a3);
            q0 = fma(Ws[(c + 0) * 64 + lane], x0, q0);
            q1 = fma(Ws[(c + 1) * 64 + lane], x1, q1);
            q2 = fma(Ws[(c + 2) * 64 + lane], x2, q2);
            q3 = fma(Ws[(c + 3) * 64 + lane], x3, q3);
        }
        Ad[(size_t)p * 64 + lane] = (a0 + a1) + (a2 + a3);
        Bd[(size_t)p * 64 + lane] = (q0 + q1) + (q2 + q3);
    }
}

__global__ __launch_bounds__(256) void gmax_k(const double* __restrict__ Ad,
        const double* __restrict__ Bd, const int* __restrict__ idxb, int cho,
        float* __restrict__ dout, float* __restrict__ x123t_o) {
    int tid = threadIdx.x, lane = tid & 63, w = tid >> 6;
    int p = blockIdx.x * 4 + w, b = p >> 11, n = p & 2047;
    const int* ip = idxb + (size_t)p * KK;
    size_t boff = (size_t)(b << 11);
    double m = DNEG;
    int nbc = ip[0];
    double v = Bd[(boff + nbc) * 64 + lane];
    #pragma unroll 1
    for (int kk = 0; kk < KK; ++kk) {
        double cur = v;
        if (kk < KK - 1) {
            int nbn = ip[kk + 1];
            v = Bd[(boff + nbn) * 64 + lane];
        }
        m = fmax(m, cur);
    }
    double out = Ad[(size_t)p * 64 + lane] + m;
    dout[((size_t)b * 192 + cho + lane) * NN + n] = (float)out;
    x123t_o[((size_t)b * NN + n) * 192 + cho + lane] = (float)out;
}

// ---------------------------------------------------------------------------
// Final conv1d (1024x192) as LDS-tiled f32 GEMM, 64o x 64n per block, KC=32.
// ---------------------------------------------------------------------------
#define KC 32
__global__ __launch_bounds__(256) void w6_k(const float* __restrict__ x123t,
                                            const float* __restrict__ w6,
                                            float* __restrict__ partial6) {
    __shared__ float xs[KC][68];
    __shared__ float wsb[KC][68];
    __shared__ float red[64][17];
    int tid = threadIdx.x;
    int ntile = blockIdx.x & 31, ot = (blockIdx.x >> 5) & 15, b = blockIdx.x >> 9;
    int n0 = ntile * 64, o0 = ot * 64;
    int ln = tid >> 2, lc = (tid & 3) * 8;
    const float* xrow = x123t + ((size_t)b * NN + n0 + ln) * 192 + lc;
    const float* wrow = w6 + (size_t)(o0 + ln) * 192 + lc;
    float acc[4][4];
    #pragma unroll
    for (int i = 0; i < 4; ++i)
        #pragma unroll
        for (int j = 0; j < 4; ++j) acc[i][j] = 0.f;
    int to = tid & 15, tn = tid >> 4;
    for (int cc = 0; cc < 192; cc += KC) {
        float4 xa = *(const float4*)(xrow + cc);
        float4 xb4 = *(const float4*)(xrow + cc + 4);
        float4 wa = *(const float4*)(wrow + cc);
        float4 wb4 = *(const float4*)(wrow + cc + 4);
        __syncthreads();
        xs[lc + 0][ln] = xa.x; xs[lc + 1][ln] = xa.y;
        xs[lc + 2][ln] = xa.z; xs[lc + 3][ln] = xa.w;
        xs[lc + 4][ln] = xb4.x; xs[lc + 5][ln] = xb4.y;
        xs[lc + 6][ln] = xb4.z; xs[lc + 7][ln] = xb4.w;
        wsb[lc + 0][ln] = wa.x; wsb[lc + 1][ln] = wa.y;
        wsb[lc + 2][ln] = wa.z; wsb[lc + 3][ln] = wa.w;
        wsb[lc + 4][ln] = wb4.x; wsb[lc + 5][ln] = wb4.y;
        wsb[lc + 6][ln] = wb4.z; wsb[lc + 7][ln] = wb4.w;
        __syncthreads();
        #pragma unroll
        for (int k = 0; k < KC; ++k) {
            float4 wv = *(const float4*)&wsb[k][to * 4];
            float4 xv = *(const float4*)&xs[k][tn * 4];
            float wr[4] = {wv.x, wv.y, wv.z, wv.w};
            float xr[4] = {xv.x, xv.y, xv.z, xv.w};
            #pragma unroll
            for (int i = 0; i < 4; ++i)
                #pragma unroll
                for (int j = 0; j < 4; ++j)
                    acc[i][j] = fmaf(wr[i], xr[j], acc[i][j]);
        }
    }
    #pragma unroll
    for (int i = 0; i < 4; ++i) {
        float mm = fmaxf(fmaxf(acc[i][0], acc[i][1]), fmaxf(acc[i][2], acc[i][3]));
        red[to * 4 + i][tn] = mm;
    }
    __syncthreads();
    if (tid < 64) {
        float mm = red[tid][0];
        #pragma unroll
        for (int t = 1; t < 16; ++t) mm = fmaxf(mm, red[tid][t]);
        partial6[((size_t)b * 1024 + o0 + tid) * 32 + ntile] = mm;
    }
}

__global__ void final_k(const float* __restrict__ partial6, const float* __restrict__ b6,
                        float* __restrict__ dout) {
    int t = blockIdx.x * 256 + threadIdx.x;  // < 16*1024
    int o = t & 1023;
    float m = NEG_INF;
    #pragma unroll 1
    for (int nt = 0; nt < 32; ++nt) m = fmaxf(m, partial6[(size_t)t * 32 + nt]);
    dout[(size_t)BB * 192 * NN + t] = m + b6[o];
}

// ---------------------------------------------------------------------------
extern "C" void kernel_launch(void* const* d_in, const int* in_sizes, int n_in,
                              void* d_out_, int out_size, void* d_ws, size_t ws_size,
                              hipStream_t stream) {
    (void)in_sizes; (void)n_in; (void)out_size; (void)ws_size;
    const float* x  = (const float*)d_in[0];
    const float* w1 = (const float*)d_in[1];
    const float* b1 = (const float*)d_in[2];
    const float* w2 = (const float*)d_in[3];
    const float* b2 = (const float*)d_in[4];
    const float* w3 = (const float*)d_in[5];
    const float* b3 = (const float*)d_in[6];
    const float* w4 = (const float*)d_in[7];
    const float* b4 = (const float*)d_in[8];
    const float* w5 = (const float*)d_in[9];
    const float* b5 = (const float*)d_in[10];
    const float* w6 = (const float*)d_in[11];
    const float* b6 = (const float*)d_in[12];
    float* dout = (float*)d_out_;

    char* ws = (char*)d_ws;
    float*  x123t    = (float*)(ws + 0);           // 25,165,824 B
    int*    idxb     = (int*)(ws + 25165824);      //  2,621,440 B
    float*  nrm      = (float*)(ws + 27787264);    //    131,072 B
    float*  partial6 = (float*)(ws + 27918336);    //  2,097,152 B
    double* wd2      = (double*)(ws + 30015488);   //    135,680 B
    // region: pd (4 batches x 16MB) OR Ad+Bd (16MB each). Never live together.
    char*   region   = ws + 30151168;              // 67,108,864 B
    float*  pd = (float*)region;
    double* Ad = (double*)region;
    double* Bd = (double*)(region + 16777216);
    const int nb = 4;

    prep_cmp<<<1, 256, 0, stream>>>(w1, b1, w2, b2, w3, b3, w4, b4, w5, b5, wd2);

    // ---- block 1 ----
    norms1_k<<<128, 256, 0, stream>>>(x, nrm);
    knn1_k<<<dim3(1024, BB), 128, 0, stream>>>(x, nrm, idxb);
    ab1_k<<<8192, 256, 0, stream>>>(x, wd2, Ad, Bd);
    gmax_k<<<8192, 256, 0, stream>>>(Ad, Bd, idxb, 0, dout, x123t);

    // ---- knn on x1 (tiled GEMM + select, frozen arithmetic) ----
    norms23_k<<<128, 256, 0, stream>>>(x123t, 0, nrm);
    for (int b0 = 0; b0 < BB; b0 += nb) {
        gemm_pd_k<<<dim3(32, 32, nb), 256, 0, stream>>>(dout, 0, nrm, pd, b0);
        select_k<<<dim3(512, nb), 256, 0, stream>>>(pd, idxb, b0);
    }
    // ---- block 2 (A/B overwrite pd region; pd dead after select) ----
    ab23_k<<<512, 256, 0, stream>>>(x123t, wd2, 0, 448, 4544, 8640, Ad, Bd);
    gmax_k<<<8192, 256, 0, stream>>>(Ad, Bd, idxb, 64, dout, x123t);

    // ---- knn on x2 ----
    norms23_k<<<128, 256, 0, stream>>>(x123t, 64, nrm);
    for (int b0 = 0; b0 < BB; b0 += nb) {
        gemm_pd_k<<<dim3(32, 32, nb), 256, 0, stream>>>(dout, 64, nrm, pd, b0);
        select_k<<<dim3(512, nb), 256, 0, stream>>>(pd, idxb, b0);
    }
    // ---- block 3 ----
    ab23_k<<<512, 256, 0, stream>>>(x123t, wd2, 64, 8704, 12800, 16896, Ad, Bd);
    gmax_k<<<8192, 256, 0, stream>>>(Ad, Bd, idxb, 128, dout, x123t);

    // ---- final conv1d + global max ----
    w6_k<<<8192, 256, 0, stream>>>(x123t, w6, partial6);
    final_k<<<64, 256, 0, stream>>>(partial6, b6, dout);
}

// Round 20
// 1266.103 us; speedup vs baseline: 1.5072x; 1.0727x over previous
//
#include <hip/hip_runtime.h>

// Problem constants
#define BB 16
#define NN 2048
#define KK 20

#define NEG_INF (-3.402823466e+38f)
#define DNEG (-1.0e300)

// ---------------------------------------------------------------------------
// Composed fp64 weights (layout in wd2, doubles):
//  M1[3][64]@0   Md1[3][64]@192 (=Mh1-M1)   g01[64]@384
//  M2[64][64]@448   Md2[64][64]@4544 (=Mh2-M2)   g02[64]@8640
//  W5[64][64]@8704 (=w5lo[c][o])  W5d[64][64]@12800 (=w5hi-w5lo)  b5d[64]@16896
// ---------------------------------------------------------------------------
__global__ void prep_cmp(const float* __restrict__ w1, const float* __restrict__ b1,
                         const float* __restrict__ w2, const float* __restrict__ b2,
                         const float* __restrict__ w3, const float* __restrict__ b3,
                         const float* __restrict__ w4, const float* __restrict__ b4,
                         const float* __restrict__ w5, const float* __restrict__ b5,
                         double* __restrict__ wd2) {
    int t = threadIdx.x;
    for (int i = t; i < 192; i += 256) {
        int c = i >> 6, o = i & 63;
        double s = 0, sh = 0;
        for (int j = 0; j < 64; ++j) {
            double w2v = (double)w2[o * 64 + j];
            s  = fma(w2v, (double)w1[j * 6 + c], s);
            sh = fma(w2v, (double)w1[j * 6 + 3 + c], sh);
        }
        wd2[i] = s;
        wd2[192 + i] = sh - s;
    }
    for (int i = t; i < 64; i += 256) {
        double s = (double)b2[i];
        for (int j = 0; j < 64; ++j)
            s = fma((double)w2[i * 64 + j], (double)b1[j], s);
        wd2[384 + i] = s;
        double s2 = (double)b4[i];
        for (int j = 0; j < 64; ++j)
            s2 = fma((double)w4[i * 64 + j], (double)b3[j], s2);
        wd2[8640 + i] = s2;
        wd2[16896 + i] = (double)b5[i];
    }
    for (int i = t; i < 4096; i += 256) {
        int c = i >> 6, o = i & 63;
        double s = 0, sh = 0;
        for (int j = 0; j < 64; ++j) {
            double w4v = (double)w4[o * 64 + j];
            s  = fma(w4v, (double)w3[j * 128 + c], s);
            sh = fma(w4v, (double)w3[j * 128 + 64 + c], sh);
        }
        wd2[448 + i] = s;         // M2[c][o]
        wd2[4544 + i] = sh - s;   // Md2[c][o]
        double lo = (double)w5[o * 128 + c];
        wd2[8704 + i] = lo;                                  // W5[c][o]
        wd2[12800 + i] = (double)w5[o * 128 + 64 + c] - lo;  // W5d[c][o]
    }
}

// ---------------------------------------------------------------------------
// Packed-key top-20 selection. key = (orderable(value) << 32) | (2047 - col).
// Max key == max value with lowest-col tie-break. Keys unique -> one owner.
// ---------------------------------------------------------------------------
__device__ __forceinline__ unsigned long long pkey(float v, int col) {
    float vc = __fadd_rn(v, 0.0f);   // -0 -> +0 (real instruction)
    unsigned u = __float_as_uint(vc);
    unsigned s = (unsigned)((int)u >> 31);
    unsigned m = u ^ (s | 0x80000000u);
    return ((unsigned long long)m << 32) | (unsigned)(2047 - col);
}

__device__ __forceinline__ void top2k_upd(unsigned long long k,
        unsigned long long& ka, unsigned long long& kb) {
    bool gta = k > ka;
    bool gtb = k > kb;
    unsigned long long nkb = gta ? ka : (gtb ? k : kb);
    ka = gta ? k : ka;
    kb = nkb;
}

__device__ __forceinline__ void topk20_key(float* vrow, int lane,
        unsigned long long ka, unsigned long long kb, int* outp) {
    int myout = 0;
    #pragma unroll 1
    for (int it = 0; it < 20; ++it) {
        unsigned long long wk = ka;
        #pragma unroll
        for (int d = 32; d; d >>= 1) {
            unsigned long long o = __shfl_xor(wk, d);
            wk = (o > wk) ? o : wk;
        }
        int widx = 2047 - (int)(wk & 0xFFFFFFFFull);
        if (lane == it) myout = widx;
        if (ka == wk) {                  // unique owner pops + marks removed
            vrow[widx] = NEG_INF;
            ka = kb;
            kb = 0ULL;
        }
        if (ka == 0ULL) {                // rare: lane's top-2 exhausted
            kb = 0ULL;
            #pragma unroll 1
            for (int s = 0; s < 8; ++s) {    // blocked float4 mapping
                int base = s * 256 + lane * 4;
                float4 v4 = *(const float4*)&vrow[base];
                top2k_upd(pkey(v4.x, base + 0), ka, kb);
                top2k_upd(pkey(v4.y, base + 1), ka, kb);
                top2k_upd(pkey(v4.z, base + 2), ka, kb);
                top2k_upd(pkey(v4.w, base + 3), ka, kb);
            }
        }
    }
    if (lane < 20) outp[lane] = myout;
}

// ---------------------------------------------------------------------------
// xx for raw x (C=3): FROZEN chain fadd(fadd(mul,mul),mul).
// ---------------------------------------------------------------------------
__global__ void norms1_k(const float* __restrict__ x, float* __restrict__ nrm) {
    int t = blockIdx.x * 256 + threadIdx.x;   // 32768 points
    int b = t >> 11, n = t & 2047;
    const float* xb = x + (size_t)b * 3 * NN;
    float cx = xb[n], cy = xb[NN + n], cz = xb[2 * NN + n];
    nrm[t] = __fadd_rn(__fadd_rn(__fmul_rn(cx, cx), __fmul_rn(cy, cy)),
                       __fmul_rn(cz, cz));
}

// knn1: numpy-f32 mirror, FROZEN per-col distance arithmetic; float4 scan.
__global__ void knn1_k(const float* __restrict__ x, const float* __restrict__ nrm,
                       int* __restrict__ idx) {
    __shared__ float vlds[2][2048];
    int lane = threadIdx.x & 63, w = threadIdx.x >> 6;
    int b = blockIdx.y, r = blockIdx.x * 2 + w;
    const float* xb = x + (size_t)b * 3 * NN;
    const float* nb_ = nrm + (size_t)b * NN;
    float rx = xb[r], ry = xb[NN + r], rz = xb[2 * NN + r];
    float xxi = nb_[r];
    float* vrow = vlds[w];
    unsigned long long ka = 0ULL, kb = 0ULL;
    #pragma unroll 1
    for (int s = 0; s < 8; ++s) {
        int base = s * 256 + lane * 4;
        float4 cx = *(const float4*)&xb[base];
        float4 cy = *(const float4*)&xb[NN + base];
        float4 cz = *(const float4*)&xb[2 * NN + base];
        float4 xx4 = *(const float4*)&nb_[base];
        float4 nd4;
        {   // col base+0  (frozen chain)
            float dot = fmaf(rz, cz.x, fmaf(ry, cy.x, __fmul_rn(rx, cx.x)));
            float inner = __fmul_rn(-2.f, dot);
            float t1 = __fsub_rn(-xx4.x, inner);
            nd4.x = __fsub_rn(t1, xxi);
        }
        {   // col base+1
            float dot = fmaf(rz, cz.y, fmaf(ry, cy.y, __fmul_rn(rx, cx.y)));
            float inner = __fmul_rn(-2.f, dot);
            float t1 = __fsub_rn(-xx4.y, inner);
            nd4.y = __fsub_rn(t1, xxi);
        }
        {   // col base+2
            float dot = fmaf(rz, cz.z, fmaf(ry, cy.z, __fmul_rn(rx, cx.z)));
            float inner = __fmul_rn(-2.f, dot);
            float t1 = __fsub_rn(-xx4.z, inner);
            nd4.z = __fsub_rn(t1, xxi);
        }
        {   // col base+3
            float dot = fmaf(rz, cz.w, fmaf(ry, cy.w, __fmul_rn(rx, cx.w)));
            float inner = __fmul_rn(-2.f, dot);
            float t1 = __fsub_rn(-xx4.w, inner);
            nd4.w = __fsub_rn(t1, xxi);
        }
        *(float4*)&vrow[base] = nd4;
        top2k_upd(pkey(nd4.x, base + 0), ka, kb);
        top2k_upd(pkey(nd4.y, base + 1), ka, kb);
        top2k_upd(pkey(nd4.z, base + 2), ka, kb);
        top2k_upd(pkey(nd4.w, base + 3), ka, kb);
    }
    topk20_key(vrow, lane, ka, kb, idx + ((size_t)b * NN + r) * KK);
}

// xx for a 64-channel slice. FROZEN sequential ascending-c chain; float4 loads.
__global__ void norms23_k(const float* __restrict__ x123t, int coff,
                          float* __restrict__ nrm) {
    int t = blockIdx.x * 256 + threadIdx.x;   // 32768 points
    const float* r = x123t + (size_t)t * 192 + coff;
    float acc = 0.f;
    #pragma unroll 1
    for (int c = 0; c < 64; c += 4) {
        float4 q = *(const float4*)(r + c);
        acc = __fadd_rn(acc, __fmul_rn(q.x, q.x));
        acc = __fadd_rn(acc, __fmul_rn(q.y, q.y));
        acc = __fadd_rn(acc, __fmul_rn(q.z, q.z));
        acc = __fadd_rn(acc, __fmul_rn(q.w, q.w));
    }
    nrm[t] = acc;
}

// ---------------------------------------------------------------------------
// pd GEMM (knn2/3 distances). FROZEN chain + epilogue.
// ---------------------------------------------------------------------------
__global__ __launch_bounds__(256) void gemm_pd_k(const float* __restrict__ dout,
        int coff, const float* __restrict__ nrm, float* __restrict__ pd, int b0) {
    __shared__ float As[64][68];
    __shared__ float Bs[64][68];
    int b = b0 + blockIdx.z;
    int rb = blockIdx.y * 64, cb = blockIdx.x * 64;
    const float* doutc = dout + (size_t)(b * 192 + coff) * NN;
    int tid = threadIdx.x;
    int cq = tid >> 4, qd = (tid & 15) * 4;
    #pragma unroll
    for (int cc = 0; cc < 64; cc += 16) {
        float4 a = *(const float4*)(doutc + (size_t)(cc + cq) * NN + rb + qd);
        As[cc + cq][qd + 0] = a.x; As[cc + cq][qd + 1] = a.y;
        As[cc + cq][qd + 2] = a.z; As[cc + cq][qd + 3] = a.w;
        float4 bv = *(const float4*)(doutc + (size_t)(cc + cq) * NN + cb + qd);
        Bs[cc + cq][qd + 0] = bv.x; Bs[cc + cq][qd + 1] = bv.y;
        Bs[cc + cq][qd + 2] = bv.z; Bs[cc + cq][qd + 3] = bv.w;
    }
    __syncthreads();
    int tx = tid & 15, ty = tid >> 4;
    float acc[4][4];
    #pragma unroll
    for (int i = 0; i < 4; ++i)
        #pragma unroll
        for (int j = 0; j < 4; ++j) acc[i][j] = 0.f;
    #pragma unroll 4
    for (int c = 0; c < 64; ++c) {
        float4 av4 = *(const float4*)&As[c][ty * 4];
        float4 bv4 = *(const float4*)&Bs[c][tx * 4];
        float aa[4] = {av4.x, av4.y, av4.z, av4.w};
        float bb[4] = {bv4.x, bv4.y, bv4.z, bv4.w};
        #pragma unroll
        for (int i = 0; i < 4; ++i)
            #pragma unroll
            for (int j = 0; j < 4; ++j)
                acc[i][j] = fmaf(aa[i], bb[j], acc[i][j]);  // ascending-c chain
    }
    const float* nb_ = nrm + (size_t)b * NN;
    #pragma unroll
    for (int i = 0; i < 4; ++i) {
        int r = rb + ty * 4 + i;
        float xxi = nb_[r];
        float4 o4;
        float* o = (float*)&o4;
        #pragma unroll
        for (int j = 0; j < 4; ++j) {
            float xxj = nb_[cb + tx * 4 + j];
            float inner = __fmul_rn(-2.f, acc[i][j]);
            float t1 = __fsub_rn(-xxj, inner);
            o[j] = __fsub_rn(t1, xxi);
        }
        *(float4*)(pd + ((size_t)blockIdx.z * NN + r) * NN + cb + tx * 4) = o4;
    }
}

// selection from materialized pd chunk (packed-key, float4 scan)
__global__ void select_k(const float* __restrict__ pd, int* __restrict__ idx, int b0) {
    __shared__ float vlds[4][2048];
    int lane = threadIdx.x & 63, w = threadIdx.x >> 6;
    int bb = blockIdx.y, r = blockIdx.x * 4 + w;
    const float* row = pd + ((size_t)bb * NN + r) * NN;
    float* vrow = vlds[w];
    unsigned long long ka = 0ULL, kb = 0ULL;
    #pragma unroll 1
    for (int s = 0; s < 8; ++s) {
        int base = s * 256 + lane * 4;
        float4 v4 = *(const float4*)&row[base];
        *(float4*)&vrow[base] = v4;
        top2k_upd(pkey(v4.x, base + 0), ka, kb);
        top2k_upd(pkey(v4.y, base + 1), ka, kb);
        top2k_upd(pkey(v4.z, base + 2), ka, kb);
        top2k_upd(pkey(v4.w, base + 3), ka, kb);
    }
    topk20_key(vrow, lane, ka, kb, idx + ((size_t)(b0 + bb) * NN + r) * KK);
}

// ---------------------------------------------------------------------------
// EdgeConv via A/B decomposition:
//   h[n,k,o] = A[n][o] + B[idx[n][k]][o];  max_k commutes with + (monotone).
// ---------------------------------------------------------------------------
__global__ __launch_bounds__(256) void ab1_k(const float* __restrict__ x,
        const double* __restrict__ wd2, double* __restrict__ Ad,
        double* __restrict__ Bd) {
    int tid = threadIdx.x, lane = tid & 63, w = tid >> 6;
    int p = blockIdx.x * 4 + w, b = p >> 11, n = p & 2047;
    const float* xb = x + (size_t)b * 3 * NN;
    double c0 = (double)xb[n], c1 = (double)xb[NN + n], c2 = (double)xb[2 * NN + n];
    double A = wd2[384 + lane];
    A = fma(wd2[192 + 0 * 64 + lane], c0, A);
    A = fma(wd2[192 + 1 * 64 + lane], c1, A);
    A = fma(wd2[192 + 2 * 64 + lane], c2, A);
    double B = wd2[0 * 64 + lane] * c0;
    B = fma(wd2[1 * 64 + lane], c1, B);
    B = fma(wd2[2 * 64 + lane], c2, B);
    Ad[(size_t)p * 64 + lane] = A;
    Bd[(size_t)p * 64 + lane] = B;
}

// conv2/conv3 A/B: block = 4 waves x 16 points. W (main) staged in LDS;
// Wd (delta) read from global (L1/L2-hot).
__global__ __launch_bounds__(256) void ab23_k(const float* __restrict__ x123t,
        const double* __restrict__ wd2, int coff, int woffW, int woffWd, int goff,
        double* __restrict__ Ad, double* __restrict__ Bd) {
    __shared__ double Ws[4096];      // 32 KB
    __shared__ double ctr[4][64];    // 2 KB
    int tid = threadIdx.x, lane = tid & 63, w = tid >> 6;
    for (int i = tid; i < 4096; i += 256) Ws[i] = wd2[woffW + i];
    __syncthreads();
    int p0 = blockIdx.x * 64 + w * 16;
    #pragma unroll 1
    for (int it = 0; it < 16; ++it) {
        int p = p0 + it, b = p >> 11, n = p & 2047;
        ctr[w][lane] = (double)x123t[((size_t)b * NN + n) * 192 + coff + lane];
        double a0 = wd2[goff + lane], a1 = 0, a2 = 0, a3 = 0;
        double q0 = 0, q1 = 0, q2 = 0, q3 = 0;
        #pragma unroll
        for (int c = 0; c < 64; c += 4) {
            double x0 = ctr[w][c + 0], x1 = ctr[w][c + 1];
            double x2 = ctr[w][c + 2], x3 = ctr[w][c + 3];
            a0 = fma(wd2[woffWd + (c + 0) * 64 + lane], x0, a0);
            a1 = fma(wd2[woffWd + (c + 1) * 64 + lane], x1, a1);
            a2 = fma(wd2[woffWd + (c + 2) * 64 + lane], x2, a2);
            a3 = fma(wd2[woffWd + (c + 3) * 64 + lane], x3, a3);
            q0 = fma(Ws[(c + 0) * 64 + lane], x0, q0);
            q1 = fma(Ws[(c + 1) * 64 + lane], x1, q1);
            q2 = fma(Ws[(c + 2) * 64 + lane], x2, q2);
            q3 = fma(Ws[(c + 3) * 64 + lane], x3, q3);
        }
        Ad[(size_t)p * 64 + lane] = (a0 + a1) + (a2 + a3);
        Bd[(size_t)p * 64 + lane] = (q0 + q1) + (q2 + q3);
    }
}

__global__ __launch_bounds__(256) void gmax_k(const double* __restrict__ Ad,
        const double* __restrict__ Bd, const int* __restrict__ idxb, int cho,
        float* __restrict__ dout, float* __restrict__ x123t_o) {
    int tid = threadIdx.x, lane = tid & 63, w = tid >> 6;
    int p = blockIdx.x * 4 + w, b = p >> 11, n = p & 2047;
    const int* ip = idxb + (size_t)p * KK;
    size_t boff = (size_t)(b << 11);
    double m = DNEG;
    int nbc = ip[0];
    double v = Bd[(boff + nbc) * 64 + lane];
    #pragma unroll 1
    for (int kk = 0; kk < KK; ++kk) {
        double cur = v;
        if (kk < KK - 1) {
            int nbn = ip[kk + 1];
            v = Bd[(boff + nbn) * 64 + lane];
        }
        m = fmax(m, cur);
    }
    double out = Ad[(size_t)p * 64 + lane] + m;
    dout[((size_t)b * 192 + cho + lane) * NN + n] = (float)out;
    x123t_o[((size_t)b * NN + n) * 192 + cho + lane] = (float)out;
}

// ---------------------------------------------------------------------------
// Final conv1d (1024x192) as LDS-tiled f32 GEMM, 64o x 64n per block, KC=32.
// XOR-swizzled LDS (col ^ (row & 24)): transpose-writes 4-way -> 2-way (free).
// ---------------------------------------------------------------------------
#define KC 32
__global__ __launch_bounds__(256) void w6_k(const float* __restrict__ x123t,
                                            const float* __restrict__ w6,
                                            float* __restrict__ partial6) {
    __shared__ float xs[KC][68];
    __shared__ float wsb[KC][68];
    __shared__ float red[64][17];
    int tid = threadIdx.x;
    int ntile = blockIdx.x & 31, ot = (blockIdx.x >> 5) & 15, b = blockIdx.x >> 9;
    int n0 = ntile * 64, o0 = ot * 64;
    int ln = tid >> 2, lc = (tid & 3) * 8;
    int lnx = ln ^ lc;   // swizzled col (lc = ((row>>3)&3)<<3 for rows lc..lc+7)
    const float* xrow = x123t + ((size_t)b * NN + n0 + ln) * 192 + lc;
    const float* wrow = w6 + (size_t)(o0 + ln) * 192 + lc;
    float acc[4][4];
    #pragma unroll
    for (int i = 0; i < 4; ++i)
        #pragma unroll
        for (int j = 0; j < 4; ++j) acc[i][j] = 0.f;
    int to = tid & 15, tn = tid >> 4;
    for (int cc = 0; cc < 192; cc += KC) {
        float4 xa = *(const float4*)(xrow + cc);
        float4 xb4 = *(const float4*)(xrow + cc + 4);
        float4 wa = *(const float4*)(wrow + cc);
        float4 wb4 = *(const float4*)(wrow + cc + 4);
        __syncthreads();
        xs[lc + 0][lnx] = xa.x; xs[lc + 1][lnx] = xa.y;
        xs[lc + 2][lnx] = xa.z; xs[lc + 3][lnx] = xa.w;
        xs[lc + 4][lnx] = xb4.x; xs[lc + 5][lnx] = xb4.y;
        xs[lc + 6][lnx] = xb4.z; xs[lc + 7][lnx] = xb4.w;
        wsb[lc + 0][lnx] = wa.x; wsb[lc + 1][lnx] = wa.y;
        wsb[lc + 2][lnx] = wa.z; wsb[lc + 3][lnx] = wa.w;
        wsb[lc + 4][lnx] = wb4.x; wsb[lc + 5][lnx] = wb4.y;
        wsb[lc + 6][lnx] = wb4.z; wsb[lc + 7][lnx] = wb4.w;
        __syncthreads();
        #pragma unroll
        for (int k = 0; k < KC; ++k) {
            int kx = k & 24;
            float4 wv = *(const float4*)&wsb[k][(to * 4) ^ kx];
            float4 xv = *(const float4*)&xs[k][(tn * 4) ^ kx];
            float wr[4] = {wv.x, wv.y, wv.z, wv.w};
            float xr[4] = {xv.x, xv.y, xv.z, xv.w};
            #pragma unroll
            for (int i = 0; i < 4; ++i)
                #pragma unroll
                for (int j = 0; j < 4; ++j)
                    acc[i][j] = fmaf(wr[i], xr[j], acc[i][j]);
        }
    }
    #pragma unroll
    for (int i = 0; i < 4; ++i) {
        float mm = fmaxf(fmaxf(acc[i][0], acc[i][1]), fmaxf(acc[i][2], acc[i][3]));
        red[to * 4 + i][tn] = mm;
    }
    __syncthreads();
    if (tid < 64) {
        float mm = red[tid][0];
        #pragma unroll
        for (int t = 1; t < 16; ++t) mm = fmaxf(mm, red[tid][t]);
        partial6[((size_t)b * 1024 + o0 + tid) * 32 + ntile] = mm;
    }
}

__global__ void final_k(const float* __restrict__ partial6, const float* __restrict__ b6,
                        float* __restrict__ dout) {
    int t = blockIdx.x * 256 + threadIdx.x;  // < 16*1024
    int o = t & 1023;
    float m = NEG_INF;
    #pragma unroll 1
    for (int nt = 0; nt < 32; ++nt) m = fmaxf(m, partial6[(size_t)t * 32 + nt]);
    dout[(size_t)BB * 192 * NN + t] = m + b6[o];
}

// ---------------------------------------------------------------------------
extern "C" void kernel_launch(void* const* d_in, const int* in_sizes, int n_in,
                              void* d_out_, int out_size, void* d_ws, size_t ws_size,
                              hipStream_t stream) {
    (void)in_sizes; (void)n_in; (void)out_size;
    const float* x  = (const float*)d_in[0];
    const float* w1 = (const float*)d_in[1];
    const float* b1 = (const float*)d_in[2];
    const float* w2 = (const float*)d_in[3];
    const float* b2 = (const float*)d_in[4];
    const float* w3 = (const float*)d_in[5];
    const float* b3 = (const float*)d_in[6];
    const float* w4 = (const float*)d_in[7];
    const float* b4 = (const float*)d_in[8];
    const float* w5 = (const float*)d_in[9];
    const float* b5 = (const float*)d_in[10];
    const float* w6 = (const float*)d_in[11];
    const float* b6 = (const float*)d_in[12];
    float* dout = (float*)d_out_;

    char* ws = (char*)d_ws;
    float*  x123t    = (float*)(ws + 0);           // 25,165,824 B
    int*    idxb     = (int*)(ws + 25165824);      //  2,621,440 B
    float*  nrm      = (float*)(ws + 27787264);    //    131,072 B
    float*  partial6 = (float*)(ws + 27918336);    //  2,097,152 B
    double* wd2      = (double*)(ws + 30015488);   //    135,680 B
    // region: pd (nb x 16MB) OR Ad+Bd (16MB each). Never live together.
    char*   region   = ws + 30151168;
    float*  pd = (float*)region;
    double* Ad = (double*)region;
    double* Bd = (double*)(region + 16777216);
    long long avail = (long long)ws_size - 30151168LL;
    int nb = (int)(avail / 16777216LL);
    if (nb < 2) nb = 2;    // Ad/Bd require 32MB; >=64MB proven available
    if (nb > 8) nb = 8;

    prep_cmp<<<1, 256, 0, stream>>>(w1, b1, w2, b2, w3, b3, w4, b4, w5, b5, wd2);

    // ---- block 1 ----
    norms1_k<<<128, 256, 0, stream>>>(x, nrm);
    knn1_k<<<dim3(1024, BB), 128, 0, stream>>>(x, nrm, idxb);
    ab1_k<<<8192, 256, 0, stream>>>(x, wd2, Ad, Bd);
    gmax_k<<<8192, 256, 0, stream>>>(Ad, Bd, idxb, 0, dout, x123t);

    // ---- knn on x1 (tiled GEMM + select, frozen arithmetic) ----
    norms23_k<<<128, 256, 0, stream>>>(x123t, 0, nrm);
    for (int b0 = 0; b0 < BB; b0 += nb) {
        int cur = (BB - b0 < nb) ? (BB - b0) : nb;
        gemm_pd_k<<<dim3(32, 32, cur), 256, 0, stream>>>(dout, 0, nrm, pd, b0);
        select_k<<<dim3(512, cur), 256, 0, stream>>>(pd, idxb, b0);
    }
    // ---- block 2 (A/B overwrite pd region; pd dead after select) ----
    ab23_k<<<512, 256, 0, stream>>>(x123t, wd2, 0, 448, 4544, 8640, Ad, Bd);
    gmax_k<<<8192, 256, 0, stream>>>(Ad, Bd, idxb, 64, dout, x123t);

    // ---- knn on x2 ----
    norms23_k<<<128, 256, 0, stream>>>(x123t, 64, nrm);
    for (int b0 = 0; b0 < BB; b0 += nb) {
        int cur = (BB - b0 < nb) ? (BB - b0) : nb;
        gemm_pd_k<<<dim3(32, 32, cur), 256, 0, stream>>>(dout, 64, nrm, pd, b0);
        select_k<<<dim3(512, cur), 256, 0, stream>>>(pd, idxb, b0);
    }
    // ---- block 3 ----
    ab23_k<<<512, 256, 0, stream>>>(x123t, wd2, 64, 8704, 12800, 16896, Ad, Bd);
    gmax_k<<<8192, 256, 0, stream>>>(Ad, Bd, idxb, 128, dout, x123t);

    // ---- final conv1d + global max ----
    w6_k<<<8192, 256, 0, stream>>>(x123t, w6, partial6);
    final_k<<<64, 256, 0, stream>>>(partial6, b6, dout);
}

// Round 21
// 1250.212 us; speedup vs baseline: 1.5263x; 1.0127x over previous
//
#include <hip/hip_runtime.h>

// Problem constants
#define BB 16
#define NN 2048
#define KK 20

#define NEG_INF (-3.402823466e+38f)
#define DNEG (-1.0e300)

// ---------------------------------------------------------------------------
// Composed fp64 weights (layout in wd2, doubles):
//  M1[3][64]@0   Md1[3][64]@192 (=Mh1-M1)   g01[64]@384
//  M2[64][64]@448   Md2[64][64]@4544 (=Mh2-M2)   g02[64]@8640
//  W5[64][64]@8704 (=w5lo[c][o])  W5d[64][64]@12800 (=w5hi-w5lo)  b5d[64]@16896
// ---------------------------------------------------------------------------
__global__ void prep_cmp(const float* __restrict__ w1, const float* __restrict__ b1,
                         const float* __restrict__ w2, const float* __restrict__ b2,
                         const float* __restrict__ w3, const float* __restrict__ b3,
                         const float* __restrict__ w4, const float* __restrict__ b4,
                         const float* __restrict__ w5, const float* __restrict__ b5,
                         double* __restrict__ wd2) {
    int t = threadIdx.x;
    for (int i = t; i < 192; i += 256) {
        int c = i >> 6, o = i & 63;
        double s = 0, sh = 0;
        for (int j = 0; j < 64; ++j) {
            double w2v = (double)w2[o * 64 + j];
            s  = fma(w2v, (double)w1[j * 6 + c], s);
            sh = fma(w2v, (double)w1[j * 6 + 3 + c], sh);
        }
        wd2[i] = s;
        wd2[192 + i] = sh - s;
    }
    for (int i = t; i < 64; i += 256) {
        double s = (double)b2[i];
        for (int j = 0; j < 64; ++j)
            s = fma((double)w2[i * 64 + j], (double)b1[j], s);
        wd2[384 + i] = s;
        double s2 = (double)b4[i];
        for (int j = 0; j < 64; ++j)
            s2 = fma((double)w4[i * 64 + j], (double)b3[j], s2);
        wd2[8640 + i] = s2;
        wd2[16896 + i] = (double)b5[i];
    }
    for (int i = t; i < 4096; i += 256) {
        int c = i >> 6, o = i & 63;
        double s = 0, sh = 0;
        for (int j = 0; j < 64; ++j) {
            double w4v = (double)w4[o * 64 + j];
            s  = fma(w4v, (double)w3[j * 128 + c], s);
            sh = fma(w4v, (double)w3[j * 128 + 64 + c], sh);
        }
        wd2[448 + i] = s;         // M2[c][o]
        wd2[4544 + i] = sh - s;   // Md2[c][o]
        double lo = (double)w5[o * 128 + c];
        wd2[8704 + i] = lo;                                  // W5[c][o]
        wd2[12800 + i] = (double)w5[o * 128 + 64 + c] - lo;  // W5d[c][o]
    }
}

// ---------------------------------------------------------------------------
// Packed-key top-20 selection. key = (orderable(value) << 32) | (2047 - col).
// ---------------------------------------------------------------------------
__device__ __forceinline__ unsigned long long pkey(float v, int col) {
    float vc = __fadd_rn(v, 0.0f);   // -0 -> +0 (real instruction)
    unsigned u = __float_as_uint(vc);
    unsigned s = (unsigned)((int)u >> 31);
    unsigned m = u ^ (s | 0x80000000u);
    return ((unsigned long long)m << 32) | (unsigned)(2047 - col);
}

__device__ __forceinline__ void top2k_upd(unsigned long long k,
        unsigned long long& ka, unsigned long long& kb) {
    bool gta = k > ka;
    bool gtb = k > kb;
    unsigned long long nkb = gta ? ka : (gtb ? k : kb);
    ka = gta ? k : ka;
    kb = nkb;
}

__device__ __forceinline__ void topk20_key(float* vrow, int lane,
        unsigned long long ka, unsigned long long kb, int* outp) {
    int myout = 0;
    #pragma unroll 1
    for (int it = 0; it < 20; ++it) {
        unsigned long long wk = ka;
        #pragma unroll
        for (int d = 32; d; d >>= 1) {
            unsigned long long o = __shfl_xor(wk, d);
            wk = (o > wk) ? o : wk;
        }
        int widx = 2047 - (int)(wk & 0xFFFFFFFFull);
        if (lane == it) myout = widx;
        if (ka == wk) {                  // unique owner pops + marks removed
            vrow[widx] = NEG_INF;
            ka = kb;
            kb = 0ULL;
        }
        if (ka == 0ULL) {                // rare: lane's top-2 exhausted
            kb = 0ULL;
            #pragma unroll 1
            for (int s = 0; s < 8; ++s) {    // blocked float4 mapping
                int base = s * 256 + lane * 4;
                float4 v4 = *(const float4*)&vrow[base];
                top2k_upd(pkey(v4.x, base + 0), ka, kb);
                top2k_upd(pkey(v4.y, base + 1), ka, kb);
                top2k_upd(pkey(v4.z, base + 2), ka, kb);
                top2k_upd(pkey(v4.w, base + 3), ka, kb);
            }
        }
    }
    if (lane < 20) outp[lane] = myout;
}

// ---------------------------------------------------------------------------
// xx for raw x (C=3): FROZEN chain fadd(fadd(mul,mul),mul).
// ---------------------------------------------------------------------------
__global__ void norms1_k(const float* __restrict__ x, float* __restrict__ nrm) {
    int t = blockIdx.x * 256 + threadIdx.x;   // 32768 points
    int b = t >> 11, n = t & 2047;
    const float* xb = x + (size_t)b * 3 * NN;
    float cx = xb[n], cy = xb[NN + n], cz = xb[2 * NN + n];
    nrm[t] = __fadd_rn(__fadd_rn(__fmul_rn(cx, cx), __fmul_rn(cy, cy)),
                       __fmul_rn(cz, cz));
}

// knn1: numpy-f32 mirror, FROZEN per-col distance arithmetic; float4 scan.
__global__ void knn1_k(const float* __restrict__ x, const float* __restrict__ nrm,
                       int* __restrict__ idx) {
    __shared__ float vlds[2][2048];
    int lane = threadIdx.x & 63, w = threadIdx.x >> 6;
    int b = blockIdx.y, r = blockIdx.x * 2 + w;
    const float* xb = x + (size_t)b * 3 * NN;
    const float* nb_ = nrm + (size_t)b * NN;
    float rx = xb[r], ry = xb[NN + r], rz = xb[2 * NN + r];
    float xxi = nb_[r];
    float* vrow = vlds[w];
    unsigned long long ka = 0ULL, kb = 0ULL;
    #pragma unroll 1
    for (int s = 0; s < 8; ++s) {
        int base = s * 256 + lane * 4;
        float4 cx = *(const float4*)&xb[base];
        float4 cy = *(const float4*)&xb[NN + base];
        float4 cz = *(const float4*)&xb[2 * NN + base];
        float4 xx4 = *(const float4*)&nb_[base];
        float4 nd4;
        {   // col base+0  (frozen chain)
            float dot = fmaf(rz, cz.x, fmaf(ry, cy.x, __fmul_rn(rx, cx.x)));
            float inner = __fmul_rn(-2.f, dot);
            float t1 = __fsub_rn(-xx4.x, inner);
            nd4.x = __fsub_rn(t1, xxi);
        }
        {   // col base+1
            float dot = fmaf(rz, cz.y, fmaf(ry, cy.y, __fmul_rn(rx, cx.y)));
            float inner = __fmul_rn(-2.f, dot);
            float t1 = __fsub_rn(-xx4.y, inner);
            nd4.y = __fsub_rn(t1, xxi);
        }
        {   // col base+2
            float dot = fmaf(rz, cz.z, fmaf(ry, cy.z, __fmul_rn(rx, cx.z)));
            float inner = __fmul_rn(-2.f, dot);
            float t1 = __fsub_rn(-xx4.z, inner);
            nd4.z = __fsub_rn(t1, xxi);
        }
        {   // col base+3
            float dot = fmaf(rz, cz.w, fmaf(ry, cy.w, __fmul_rn(rx, cx.w)));
            float inner = __fmul_rn(-2.f, dot);
            float t1 = __fsub_rn(-xx4.w, inner);
            nd4.w = __fsub_rn(t1, xxi);
        }
        *(float4*)&vrow[base] = nd4;
        top2k_upd(pkey(nd4.x, base + 0), ka, kb);
        top2k_upd(pkey(nd4.y, base + 1), ka, kb);
        top2k_upd(pkey(nd4.z, base + 2), ka, kb);
        top2k_upd(pkey(nd4.w, base + 3), ka, kb);
    }
    topk20_key(vrow, lane, ka, kb, idx + ((size_t)b * NN + r) * KK);
}

// xx for a 64-channel slice. FROZEN sequential ascending-c chain; float4 loads.
__global__ void norms23_k(const float* __restrict__ x123t, int coff,
                          float* __restrict__ nrm) {
    int t = blockIdx.x * 256 + threadIdx.x;   // 32768 points
    const float* r = x123t + (size_t)t * 192 + coff;
    float acc = 0.f;
    #pragma unroll 1
    for (int c = 0; c < 64; c += 4) {
        float4 q = *(const float4*)(r + c);
        acc = __fadd_rn(acc, __fmul_rn(q.x, q.x));
        acc = __fadd_rn(acc, __fmul_rn(q.y, q.y));
        acc = __fadd_rn(acc, __fmul_rn(q.z, q.z));
        acc = __fadd_rn(acc, __fmul_rn(q.w, q.w));
    }
    nrm[t] = acc;
}

// ---------------------------------------------------------------------------
// pd GEMM (knn2/3 distances). FROZEN chain + epilogue.
// ---------------------------------------------------------------------------
__global__ __launch_bounds__(256) void gemm_pd_k(const float* __restrict__ dout,
        int coff, const float* __restrict__ nrm, float* __restrict__ pd, int b0) {
    __shared__ float As[64][68];
    __shared__ float Bs[64][68];
    int b = b0 + blockIdx.z;
    int rb = blockIdx.y * 64, cb = blockIdx.x * 64;
    const float* doutc = dout + (size_t)(b * 192 + coff) * NN;
    int tid = threadIdx.x;
    int cq = tid >> 4, qd = (tid & 15) * 4;
    #pragma unroll
    for (int cc = 0; cc < 64; cc += 16) {
        float4 a = *(const float4*)(doutc + (size_t)(cc + cq) * NN + rb + qd);
        As[cc + cq][qd + 0] = a.x; As[cc + cq][qd + 1] = a.y;
        As[cc + cq][qd + 2] = a.z; As[cc + cq][qd + 3] = a.w;
        float4 bv = *(const float4*)(doutc + (size_t)(cc + cq) * NN + cb + qd);
        Bs[cc + cq][qd + 0] = bv.x; Bs[cc + cq][qd + 1] = bv.y;
        Bs[cc + cq][qd + 2] = bv.z; Bs[cc + cq][qd + 3] = bv.w;
    }
    __syncthreads();
    int tx = tid & 15, ty = tid >> 4;
    float acc[4][4];
    #pragma unroll
    for (int i = 0; i < 4; ++i)
        #pragma unroll
        for (int j = 0; j < 4; ++j) acc[i][j] = 0.f;
    #pragma unroll 4
    for (int c = 0; c < 64; ++c) {
        float4 av4 = *(const float4*)&As[c][ty * 4];
        float4 bv4 = *(const float4*)&Bs[c][tx * 4];
        float aa[4] = {av4.x, av4.y, av4.z, av4.w};
        float bb[4] = {bv4.x, bv4.y, bv4.z, bv4.w};
        #pragma unroll
        for (int i = 0; i < 4; ++i)
            #pragma unroll
            for (int j = 0; j < 4; ++j)
                acc[i][j] = fmaf(aa[i], bb[j], acc[i][j]);  // ascending-c chain
    }
    const float* nb_ = nrm + (size_t)b * NN;
    #pragma unroll
    for (int i = 0; i < 4; ++i) {
        int r = rb + ty * 4 + i;
        float xxi = nb_[r];
        float4 o4;
        float* o = (float*)&o4;
        #pragma unroll
        for (int j = 0; j < 4; ++j) {
            float xxj = nb_[cb + tx * 4 + j];
            float inner = __fmul_rn(-2.f, acc[i][j]);
            float t1 = __fsub_rn(-xxj, inner);
            o[j] = __fsub_rn(t1, xxi);
        }
        *(float4*)(pd + ((size_t)blockIdx.z * NN + r) * NN + cb + tx * 4) = o4;
    }
}

// selection from materialized pd chunk (packed-key, float4 scan)
__global__ void select_k(const float* __restrict__ pd, int* __restrict__ idx, int b0) {
    __shared__ float vlds[4][2048];
    int lane = threadIdx.x & 63, w = threadIdx.x >> 6;
    int bb = blockIdx.y, r = blockIdx.x * 4 + w;
    const float* row = pd + ((size_t)bb * NN + r) * NN;
    float* vrow = vlds[w];
    unsigned long long ka = 0ULL, kb = 0ULL;
    #pragma unroll 1
    for (int s = 0; s < 8; ++s) {
        int base = s * 256 + lane * 4;
        float4 v4 = *(const float4*)&row[base];
        *(float4*)&vrow[base] = v4;
        top2k_upd(pkey(v4.x, base + 0), ka, kb);
        top2k_upd(pkey(v4.y, base + 1), ka, kb);
        top2k_upd(pkey(v4.z, base + 2), ka, kb);
        top2k_upd(pkey(v4.w, base + 3), ka, kb);
    }
    topk20_key(vrow, lane, ka, kb, idx + ((size_t)(b0 + bb) * NN + r) * KK);
}

// ---------------------------------------------------------------------------
// EdgeConv via A/B decomposition:
//   h[n,k,o] = A[n][o] + B[idx[n][k]][o];  max_k commutes with + (monotone).
// ---------------------------------------------------------------------------
__global__ __launch_bounds__(256) void ab1_k(const float* __restrict__ x,
        const double* __restrict__ wd2, double* __restrict__ Ad,
        double* __restrict__ Bd) {
    int tid = threadIdx.x, lane = tid & 63, w = tid >> 6;
    int p = blockIdx.x * 4 + w, b = p >> 11, n = p & 2047;
    const float* xb = x + (size_t)b * 3 * NN;
    double c0 = (double)xb[n], c1 = (double)xb[NN + n], c2 = (double)xb[2 * NN + n];
    double A = wd2[384 + lane];
    A = fma(wd2[192 + 0 * 64 + lane], c0, A);
    A = fma(wd2[192 + 1 * 64 + lane], c1, A);
    A = fma(wd2[192 + 2 * 64 + lane], c2, A);
    double B = wd2[0 * 64 + lane] * c0;
    B = fma(wd2[1 * 64 + lane], c1, B);
    B = fma(wd2[2 * 64 + lane], c2, B);
    Ad[(size_t)p * 64 + lane] = A;
    Bd[(size_t)p * 64 + lane] = B;
}

// conv2/conv3 A/B: block = 4 waves x 16 points. W (main) staged in LDS;
// Wd (delta) read from global (L1/L2-hot).
__global__ __launch_bounds__(256) void ab23_k(const float* __restrict__ x123t,
        const double* __restrict__ wd2, int coff, int woffW, int woffWd, int goff,
        double* __restrict__ Ad, double* __restrict__ Bd) {
    __shared__ double Ws[4096];      // 32 KB
    __shared__ double ctr[4][64];    // 2 KB
    int tid = threadIdx.x, lane = tid & 63, w = tid >> 6;
    for (int i = tid; i < 4096; i += 256) Ws[i] = wd2[woffW + i];
    __syncthreads();
    int p0 = blockIdx.x * 64 + w * 16;
    #pragma unroll 1
    for (int it = 0; it < 16; ++it) {
        int p = p0 + it, b = p >> 11, n = p & 2047;
        ctr[w][lane] = (double)x123t[((size_t)b * NN + n) * 192 + coff + lane];
        double a0 = wd2[goff + lane], a1 = 0, a2 = 0, a3 = 0;
        double q0 = 0, q1 = 0, q2 = 0, q3 = 0;
        #pragma unroll
        for (int c = 0; c < 64; c += 4) {
            double x0 = ctr[w][c + 0], x1 = ctr[w][c + 1];
            double x2 = ctr[w][c + 2], x3 = ctr[w][c + 3];
            a0 = fma(wd2[woffWd + (c + 0) * 64 + lane], x0, a0);
            a1 = fma(wd2[woffWd + (c + 1) * 64 + lane], x1, a1);
            a2 = fma(wd2[woffWd + (c + 2) * 64 + lane], x2, a2);
            a3 = fma(wd2[woffWd + (c + 3) * 64 + lane], x3, a3);
            q0 = fma(Ws[(c + 0) * 64 + lane], x0, q0);
            q1 = fma(Ws[(c + 1) * 64 + lane], x1, q1);
            q2 = fma(Ws[(c + 2) * 64 + lane], x2, q2);
            q3 = fma(Ws[(c + 3) * 64 + lane], x3, q3);
        }
        Ad[(size_t)p * 64 + lane] = (a0 + a1) + (a2 + a3);
        Bd[(size_t)p * 64 + lane] = (q0 + q1) + (q2 + q3);
    }
}

__global__ __launch_bounds__(256) void gmax_k(const double* __restrict__ Ad,
        const double* __restrict__ Bd, const int* __restrict__ idxb, int cho,
        float* __restrict__ dout, float* __restrict__ x123t_o) {
    int tid = threadIdx.x, lane = tid & 63, w = tid >> 6;
    int p = blockIdx.x * 4 + w, b = p >> 11, n = p & 2047;
    const int* ip = idxb + (size_t)p * KK;
    size_t boff = (size_t)(b << 11);
    double m = DNEG;
    int nbc = ip[0];
    double v = Bd[(boff + nbc) * 64 + lane];
    #pragma unroll 1
    for (int kk = 0; kk < KK; ++kk) {
        double cur = v;
        if (kk < KK - 1) {
            int nbn = ip[kk + 1];
            v = Bd[(boff + nbn) * 64 + lane];
        }
        m = fmax(m, cur);
    }
    double out = Ad[(size_t)p * 64 + lane] + m;
    dout[((size_t)b * 192 + cho + lane) * NN + n] = (float)out;
    x123t_o[((size_t)b * NN + n) * 192 + cho + lane] = (float)out;
}

// ---------------------------------------------------------------------------
// Final conv1d (1024x192) as LDS-tiled f32 GEMM, 64o x 128n per block, KC=32.
// Thread tile 4o x 8n: 32 FMA per 3 LDS b128 reads. XOR-swizzled LDS.
// ---------------------------------------------------------------------------
#define KC 32
__global__ __launch_bounds__(256) void w6_k(const float* __restrict__ x123t,
                                            const float* __restrict__ w6,
                                            float* __restrict__ partial6) {
    __shared__ float xs[KC][136];   // 128 n + pad (stride mod 32 = 8)
    __shared__ float wsb[KC][68];   // 64 o + pad (stride mod 32 = 4)
    __shared__ float red[64][17];
    int tid = threadIdx.x;
    int ntile = blockIdx.x & 15, ot = (blockIdx.x >> 4) & 15, b = blockIdx.x >> 8;
    int n0 = ntile * 128, o0 = ot * 64;
    int ln2 = tid >> 1, lc2 = (tid & 1) * 16;   // x: 128 rows(n) x 16 c each
    int lw = tid >> 2, lcw = (tid & 3) * 8;     // w: 64 rows(o) x 8 c each
    const float* xrow = x123t + ((size_t)b * NN + n0 + ln2) * 192 + lc2;
    const float* wrow = w6 + (size_t)(o0 + lw) * 192 + lcw;
    float acc[4][8];
    #pragma unroll
    for (int i = 0; i < 4; ++i)
        #pragma unroll
        for (int j = 0; j < 8; ++j) acc[i][j] = 0.f;
    int to = tid & 15, tn = tid >> 4;   // o = o0+to*4+i, n = n0+tn*8+j
    for (int cc = 0; cc < 192; cc += KC) {
        float4 xa = *(const float4*)(xrow + cc);
        float4 xb4 = *(const float4*)(xrow + cc + 4);
        float4 xc4 = *(const float4*)(xrow + cc + 8);
        float4 xd4 = *(const float4*)(xrow + cc + 12);
        float4 wa = *(const float4*)(wrow + cc);
        float4 wb4 = *(const float4*)(wrow + cc + 4);
        __syncthreads();
        // xs[c][n]: c rows lc2..lc2+15, swizzled col ln2 ^ (row & 24)
        {
            float v[16] = {xa.x, xa.y, xa.z, xa.w, xb4.x, xb4.y, xb4.z, xb4.w,
                           xc4.x, xc4.y, xc4.z, xc4.w, xd4.x, xd4.y, xd4.z, xd4.w};
            #pragma unroll
            for (int q = 0; q < 16; ++q) {
                int row = lc2 + q;
                xs[row][ln2 ^ (row & 24)] = v[q];
            }
        }
        {
            float v[8] = {wa.x, wa.y, wa.z, wa.w, wb4.x, wb4.y, wb4.z, wb4.w};
            #pragma unroll
            for (int q = 0; q < 8; ++q) {
                int row = lcw + q;
                wsb[row][lw ^ (row & 24)] = v[q];
            }
        }
        __syncthreads();
        #pragma unroll
        for (int k = 0; k < KC; ++k) {
            int kx = k & 24;
            float4 wv = *(const float4*)&wsb[k][(to * 4) ^ kx];
            float4 xv1 = *(const float4*)&xs[k][(tn * 8) ^ kx];
            float4 xv2 = *(const float4*)&xs[k][((tn * 8) ^ kx) + 4];
            float wr[4] = {wv.x, wv.y, wv.z, wv.w};
            float xr[8] = {xv1.x, xv1.y, xv1.z, xv1.w,
                           xv2.x, xv2.y, xv2.z, xv2.w};
            #pragma unroll
            for (int i = 0; i < 4; ++i)
                #pragma unroll
                for (int j = 0; j < 8; ++j)
                    acc[i][j] = fmaf(wr[i], xr[j], acc[i][j]);
        }
    }
    #pragma unroll
    for (int i = 0; i < 4; ++i) {
        float m0 = fmaxf(fmaxf(acc[i][0], acc[i][1]), fmaxf(acc[i][2], acc[i][3]));
        float m1 = fmaxf(fmaxf(acc[i][4], acc[i][5]), fmaxf(acc[i][6], acc[i][7]));
        red[to * 4 + i][tn] = fmaxf(m0, m1);
    }
    __syncthreads();
    if (tid < 64) {
        float mm = red[tid][0];
        #pragma unroll
        for (int t = 1; t < 16; ++t) mm = fmaxf(mm, red[tid][t]);
        partial6[((size_t)b * 1024 + o0 + tid) * 16 + ntile] = mm;
    }
}

__global__ void final_k(const float* __restrict__ partial6, const float* __restrict__ b6,
                        float* __restrict__ dout) {
    int t = blockIdx.x * 256 + threadIdx.x;  // < 16*1024
    int o = t & 1023;
    float m = NEG_INF;
    #pragma unroll 1
    for (int nt = 0; nt < 16; ++nt) m = fmaxf(m, partial6[(size_t)t * 16 + nt]);
    dout[(size_t)BB * 192 * NN + t] = m + b6[o];
}

// ---------------------------------------------------------------------------
extern "C" void kernel_launch(void* const* d_in, const int* in_sizes, int n_in,
                              void* d_out_, int out_size, void* d_ws, size_t ws_size,
                              hipStream_t stream) {
    (void)in_sizes; (void)n_in; (void)out_size;
    const float* x  = (const float*)d_in[0];
    const float* w1 = (const float*)d_in[1];
    const float* b1 = (const float*)d_in[2];
    const float* w2 = (const float*)d_in[3];
    const float* b2 = (const float*)d_in[4];
    const float* w3 = (const float*)d_in[5];
    const float* b3 = (const float*)d_in[6];
    const float* w4 = (const float*)d_in[7];
    const float* b4 = (const float*)d_in[8];
    const float* w5 = (const float*)d_in[9];
    const float* b5 = (const float*)d_in[10];
    const float* w6 = (const float*)d_in[11];
    const float* b6 = (const float*)d_in[12];
    float* dout = (float*)d_out_;

    char* ws = (char*)d_ws;
    float*  x123t    = (float*)(ws + 0);           // 25,165,824 B
    int*    idxb     = (int*)(ws + 25165824);      //  2,621,440 B
    float*  nrm      = (float*)(ws + 27787264);    //    131,072 B
    float*  partial6 = (float*)(ws + 27918336);    //  2,097,152 B
    double* wd2      = (double*)(ws + 30015488);   //    135,680 B
    // region: pd (nb x 16MB) OR Ad+Bd (16MB each). Never live together.
    char*   region   = ws + 30151168;
    float*  pd = (float*)region;
    double* Ad = (double*)region;
    double* Bd = (double*)(region + 16777216);
    long long avail = (long long)ws_size - 30151168LL;
    int nb = (int)(avail / 16777216LL);
    if (nb < 2) nb = 2;    // Ad/Bd require 32MB; >=64MB proven available
    if (nb > 8) nb = 8;

    prep_cmp<<<1, 256, 0, stream>>>(w1, b1, w2, b2, w3, b3, w4, b4, w5, b5, wd2);

    // ---- block 1 ----
    norms1_k<<<128, 256, 0, stream>>>(x, nrm);
    knn1_k<<<dim3(1024, BB), 128, 0, stream>>>(x, nrm, idxb);
    ab1_k<<<8192, 256, 0, stream>>>(x, wd2, Ad, Bd);
    gmax_k<<<8192, 256, 0, stream>>>(Ad, Bd, idxb, 0, dout, x123t);

    // ---- knn on x1 (tiled GEMM + select, frozen arithmetic) ----
    norms23_k<<<128, 256, 0, stream>>>(x123t, 0, nrm);
    for (int b0 = 0; b0 < BB; b0 += nb) {
        int cur = (BB - b0 < nb) ? (BB - b0) : nb;
        gemm_pd_k<<<dim3(32, 32, cur), 256, 0, stream>>>(dout, 0, nrm, pd, b0);
        select_k<<<dim3(512, cur), 256, 0, stream>>>(pd, idxb, b0);
    }
    // ---- block 2 (A/B overwrite pd region; pd dead after select) ----
    ab23_k<<<512, 256, 0, stream>>>(x123t, wd2, 0, 448, 4544, 8640, Ad, Bd);
    gmax_k<<<8192, 256, 0, stream>>>(Ad, Bd, idxb, 64, dout, x123t);

    // ---- knn on x2 ----
    norms23_k<<<128, 256, 0, stream>>>(x123t, 64, nrm);
    for (int b0 = 0; b0 < BB; b0 += nb) {
        int cur = (BB - b0 < nb) ? (BB - b0) : nb;
        gemm_pd_k<<<dim3(32, 32, cur), 256, 0, stream>>>(dout, 64, nrm, pd, b0);
        select_k<<<dim3(512, cur), 256, 0, stream>>>(pd, idxb, b0);
    }
    // ---- block 3 ----
    ab23_k<<<512, 256, 0, stream>>>(x123t, wd2, 64, 8704, 12800, 16896, Ad, Bd);
    gmax_k<<<8192, 256, 0, stream>>>(Ad, Bd, idxb, 128, dout, x123t);

    // ---- final conv1d + global max ----
    w6_k<<<4096, 256, 0, stream>>>(x123t, w6, partial6);
    final_k<<<64, 256, 0, stream>>>(partial6, b6, dout);
}

// Round 22
// 1233.602 us; speedup vs baseline: 1.5469x; 1.0135x over previous
//
#include <hip/hip_runtime.h>

// Problem constants
#define BB 16
#define NN 2048
#define KK 20

#define NEG_INF (-3.402823466e+38f)
#define DNEG (-1.0e300)

// ---------------------------------------------------------------------------
// Composed fp64 weights (layout in wd2, doubles):
//  M1[3][64]@0   Md1[3][64]@192 (=Mh1-M1)   g01[64]@384
//  M2[64][64]@448   Md2[64][64]@4544 (=Mh2-M2)   g02[64]@8640
//  W5[64][64]@8704 (=w5lo[c][o])  W5d[64][64]@12800 (=w5hi-w5lo)  b5d[64]@16896
// ---------------------------------------------------------------------------
__global__ void prep_cmp(const float* __restrict__ w1, const float* __restrict__ b1,
                         const float* __restrict__ w2, const float* __restrict__ b2,
                         const float* __restrict__ w3, const float* __restrict__ b3,
                         const float* __restrict__ w4, const float* __restrict__ b4,
                         const float* __restrict__ w5, const float* __restrict__ b5,
                         double* __restrict__ wd2) {
    int t = threadIdx.x;
    for (int i = t; i < 192; i += 256) {
        int c = i >> 6, o = i & 63;
        double s = 0, sh = 0;
        for (int j = 0; j < 64; ++j) {
            double w2v = (double)w2[o * 64 + j];
            s  = fma(w2v, (double)w1[j * 6 + c], s);
            sh = fma(w2v, (double)w1[j * 6 + 3 + c], sh);
        }
        wd2[i] = s;
        wd2[192 + i] = sh - s;
    }
    for (int i = t; i < 64; i += 256) {
        double s = (double)b2[i];
        for (int j = 0; j < 64; ++j)
            s = fma((double)w2[i * 64 + j], (double)b1[j], s);
        wd2[384 + i] = s;
        double s2 = (double)b4[i];
        for (int j = 0; j < 64; ++j)
            s2 = fma((double)w4[i * 64 + j], (double)b3[j], s2);
        wd2[8640 + i] = s2;
        wd2[16896 + i] = (double)b5[i];
    }
    for (int i = t; i < 4096; i += 256) {
        int c = i >> 6, o = i & 63;
        double s = 0, sh = 0;
        for (int j = 0; j < 64; ++j) {
            double w4v = (double)w4[o * 64 + j];
            s  = fma(w4v, (double)w3[j * 128 + c], s);
            sh = fma(w4v, (double)w3[j * 128 + 64 + c], sh);
        }
        wd2[448 + i] = s;         // M2[c][o]
        wd2[4544 + i] = sh - s;   // Md2[c][o]
        double lo = (double)w5[o * 128 + c];
        wd2[8704 + i] = lo;                                  // W5[c][o]
        wd2[12800 + i] = (double)w5[o * 128 + 64 + c] - lo;  // W5d[c][o]
    }
}

// ---------------------------------------------------------------------------
// Packed-key top-20 selection. key = (orderable(value) << 32) | (2047 - col).
// Winners pop in strictly decreasing key order -> popped set == {k >= wk}.
// Rescan rebuilds lane top-2 from ORIGINAL candidates filtered by k < wk
// (exact equivalent of NEG_INF-marking; no LDS mirror needed).
// ---------------------------------------------------------------------------
__device__ __forceinline__ unsigned long long pkey(float v, int col) {
    float vc = __fadd_rn(v, 0.0f);   // -0 -> +0 (real instruction)
    unsigned u = __float_as_uint(vc);
    unsigned s = (unsigned)((int)u >> 31);
    unsigned m = u ^ (s | 0x80000000u);
    return ((unsigned long long)m << 32) | (unsigned)(2047 - col);
}

__device__ __forceinline__ void top2k_upd(unsigned long long k,
        unsigned long long& ka, unsigned long long& kb) {
    bool gta = k > ka;
    bool gtb = k > kb;
    unsigned long long nkb = gta ? ka : (gtb ? k : kb);
    ka = gta ? k : ka;
    kb = nkb;
}

// ---------------------------------------------------------------------------
// xx for raw x (C=3): FROZEN chain fadd(fadd(mul,mul),mul).
// ---------------------------------------------------------------------------
__global__ void norms1_k(const float* __restrict__ x, float* __restrict__ nrm) {
    int t = blockIdx.x * 256 + threadIdx.x;   // 32768 points
    int b = t >> 11, n = t & 2047;
    const float* xb = x + (size_t)b * 3 * NN;
    float cx = xb[n], cy = xb[NN + n], cz = xb[2 * NN + n];
    nrm[t] = __fadd_rn(__fadd_rn(__fmul_rn(cx, cx), __fmul_rn(cy, cy)),
                       __fmul_rn(cz, cz));
}

// knn1: numpy-f32 mirror, FROZEN per-col distance arithmetic; float4 scan;
// LDS-free extraction (recompute rescan with k < wk filter).
__global__ __launch_bounds__(256) void knn1_k(const float* __restrict__ x,
        const float* __restrict__ nrm, int* __restrict__ idx) {
    int lane = threadIdx.x & 63, w = threadIdx.x >> 6;
    int b = blockIdx.y, r = blockIdx.x * 4 + w;
    const float* xb = x + (size_t)b * 3 * NN;
    const float* nb_ = nrm + (size_t)b * NN;
    float rx = xb[r], ry = xb[NN + r], rz = xb[2 * NN + r];
    float xxi = nb_[r];
    unsigned long long ka = 0ULL, kb = 0ULL;
    #pragma unroll 1
    for (int s = 0; s < 8; ++s) {
        int base = s * 256 + lane * 4;
        float4 cx = *(const float4*)&xb[base];
        float4 cy = *(const float4*)&xb[NN + base];
        float4 cz = *(const float4*)&xb[2 * NN + base];
        float4 xx4 = *(const float4*)&nb_[base];
        {   // col base+0  (frozen chain)
            float dot = fmaf(rz, cz.x, fmaf(ry, cy.x, __fmul_rn(rx, cx.x)));
            float inner = __fmul_rn(-2.f, dot);
            float t1 = __fsub_rn(-xx4.x, inner);
            top2k_upd(pkey(__fsub_rn(t1, xxi), base + 0), ka, kb);
        }
        {   // col base+1
            float dot = fmaf(rz, cz.y, fmaf(ry, cy.y, __fmul_rn(rx, cx.y)));
            float inner = __fmul_rn(-2.f, dot);
            float t1 = __fsub_rn(-xx4.y, inner);
            top2k_upd(pkey(__fsub_rn(t1, xxi), base + 1), ka, kb);
        }
        {   // col base+2
            float dot = fmaf(rz, cz.z, fmaf(ry, cy.z, __fmul_rn(rx, cx.z)));
            float inner = __fmul_rn(-2.f, dot);
            float t1 = __fsub_rn(-xx4.z, inner);
            top2k_upd(pkey(__fsub_rn(t1, xxi), base + 2), ka, kb);
        }
        {   // col base+3
            float dot = fmaf(rz, cz.w, fmaf(ry, cy.w, __fmul_rn(rx, cx.w)));
            float inner = __fmul_rn(-2.f, dot);
            float t1 = __fsub_rn(-xx4.w, inner);
            top2k_upd(pkey(__fsub_rn(t1, xxi), base + 3), ka, kb);
        }
    }
    // extraction: 20 stable global maxima; rescan recomputes frozen chain
    int myout = 0;
    #pragma unroll 1
    for (int it = 0; it < 20; ++it) {
        unsigned long long wk = ka;
        #pragma unroll
        for (int d = 32; d; d >>= 1) {
            unsigned long long o = __shfl_xor(wk, d);
            wk = (o > wk) ? o : wk;
        }
        if (lane == it) myout = 2047 - (int)(wk & 0xFFFFFFFFull);
        if (ka == wk) { ka = kb; kb = 0ULL; }
        if (ka == 0ULL) {                // rare: lane's top-2 exhausted
            kb = 0ULL;
            #pragma unroll 1
            for (int s = 0; s < 8; ++s) {
                int base = s * 256 + lane * 4;
                float4 cx = *(const float4*)&xb[base];
                float4 cy = *(const float4*)&xb[NN + base];
                float4 cz = *(const float4*)&xb[2 * NN + base];
                float4 xx4 = *(const float4*)&nb_[base];
                {
                    float dot = fmaf(rz, cz.x, fmaf(ry, cy.x, __fmul_rn(rx, cx.x)));
                    float inner = __fmul_rn(-2.f, dot);
                    float t1 = __fsub_rn(-xx4.x, inner);
                    unsigned long long k = pkey(__fsub_rn(t1, xxi), base + 0);
                    if (k < wk) top2k_upd(k, ka, kb);
                }
                {
                    float dot = fmaf(rz, cz.y, fmaf(ry, cy.y, __fmul_rn(rx, cx.y)));
                    float inner = __fmul_rn(-2.f, dot);
                    float t1 = __fsub_rn(-xx4.y, inner);
                    unsigned long long k = pkey(__fsub_rn(t1, xxi), base + 1);
                    if (k < wk) top2k_upd(k, ka, kb);
                }
                {
                    float dot = fmaf(rz, cz.z, fmaf(ry, cy.z, __fmul_rn(rx, cx.z)));
                    float inner = __fmul_rn(-2.f, dot);
                    float t1 = __fsub_rn(-xx4.z, inner);
                    unsigned long long k = pkey(__fsub_rn(t1, xxi), base + 2);
                    if (k < wk) top2k_upd(k, ka, kb);
                }
                {
                    float dot = fmaf(rz, cz.w, fmaf(ry, cy.w, __fmul_rn(rx, cx.w)));
                    float inner = __fmul_rn(-2.f, dot);
                    float t1 = __fsub_rn(-xx4.w, inner);
                    unsigned long long k = pkey(__fsub_rn(t1, xxi), base + 3);
                    if (k < wk) top2k_upd(k, ka, kb);
                }
            }
        }
    }
    if (lane < 20) idx[((size_t)b * NN + r) * KK + lane] = myout;
}

// xx for a 64-channel slice. FROZEN sequential ascending-c chain; float4 loads.
__global__ void norms23_k(const float* __restrict__ x123t, int coff,
                          float* __restrict__ nrm) {
    int t = blockIdx.x * 256 + threadIdx.x;   // 32768 points
    const float* r = x123t + (size_t)t * 192 + coff;
    float acc = 0.f;
    #pragma unroll 1
    for (int c = 0; c < 64; c += 4) {
        float4 q = *(const float4*)(r + c);
        acc = __fadd_rn(acc, __fmul_rn(q.x, q.x));
        acc = __fadd_rn(acc, __fmul_rn(q.y, q.y));
        acc = __fadd_rn(acc, __fmul_rn(q.z, q.z));
        acc = __fadd_rn(acc, __fmul_rn(q.w, q.w));
    }
    nrm[t] = acc;
}

// ---------------------------------------------------------------------------
// pd GEMM (knn2/3 distances). FROZEN chain + epilogue.
// ---------------------------------------------------------------------------
__global__ __launch_bounds__(256) void gemm_pd_k(const float* __restrict__ dout,
        int coff, const float* __restrict__ nrm, float* __restrict__ pd, int b0) {
    __shared__ float As[64][68];
    __shared__ float Bs[64][68];
    int b = b0 + blockIdx.z;
    int rb = blockIdx.y * 64, cb = blockIdx.x * 64;
    const float* doutc = dout + (size_t)(b * 192 + coff) * NN;
    int tid = threadIdx.x;
    int cq = tid >> 4, qd = (tid & 15) * 4;
    #pragma unroll
    for (int cc = 0; cc < 64; cc += 16) {
        float4 a = *(const float4*)(doutc + (size_t)(cc + cq) * NN + rb + qd);
        As[cc + cq][qd + 0] = a.x; As[cc + cq][qd + 1] = a.y;
        As[cc + cq][qd + 2] = a.z; As[cc + cq][qd + 3] = a.w;
        float4 bv = *(const float4*)(doutc + (size_t)(cc + cq) * NN + cb + qd);
        Bs[cc + cq][qd + 0] = bv.x; Bs[cc + cq][qd + 1] = bv.y;
        Bs[cc + cq][qd + 2] = bv.z; Bs[cc + cq][qd + 3] = bv.w;
    }
    __syncthreads();
    int tx = tid & 15, ty = tid >> 4;
    float acc[4][4];
    #pragma unroll
    for (int i = 0; i < 4; ++i)
        #pragma unroll
        for (int j = 0; j < 4; ++j) acc[i][j] = 0.f;
    #pragma unroll 4
    for (int c = 0; c < 64; ++c) {
        float4 av4 = *(const float4*)&As[c][ty * 4];
        float4 bv4 = *(const float4*)&Bs[c][tx * 4];
        float aa[4] = {av4.x, av4.y, av4.z, av4.w};
        float bb[4] = {bv4.x, bv4.y, bv4.z, bv4.w};
        #pragma unroll
        for (int i = 0; i < 4; ++i)
            #pragma unroll
            for (int j = 0; j < 4; ++j)
                acc[i][j] = fmaf(aa[i], bb[j], acc[i][j]);  // ascending-c chain
    }
    const float* nb_ = nrm + (size_t)b * NN;
    #pragma unroll
    for (int i = 0; i < 4; ++i) {
        int r = rb + ty * 4 + i;
        float xxi = nb_[r];
        float4 o4;
        float* o = (float*)&o4;
        #pragma unroll
        for (int j = 0; j < 4; ++j) {
            float xxj = nb_[cb + tx * 4 + j];
            float inner = __fmul_rn(-2.f, acc[i][j]);
            float t1 = __fsub_rn(-xxj, inner);
            o[j] = __fsub_rn(t1, xxi);
        }
        *(float4*)(pd + ((size_t)blockIdx.z * NN + r) * NN + cb + tx * 4) = o4;
    }
}

// selection from materialized pd chunk: LDS-free, global re-read rescan.
__global__ __launch_bounds__(256) void select_k(const float* __restrict__ pd,
        int* __restrict__ idx, int b0) {
    int lane = threadIdx.x & 63, w = threadIdx.x >> 6;
    int bb = blockIdx.y, r = blockIdx.x * 4 + w;
    const float* row = pd + ((size_t)bb * NN + r) * NN;
    unsigned long long ka = 0ULL, kb = 0ULL;
    #pragma unroll 1
    for (int s = 0; s < 8; ++s) {
        int base = s * 256 + lane * 4;
        float4 v4 = *(const float4*)&row[base];
        top2k_upd(pkey(v4.x, base + 0), ka, kb);
        top2k_upd(pkey(v4.y, base + 1), ka, kb);
        top2k_upd(pkey(v4.z, base + 2), ka, kb);
        top2k_upd(pkey(v4.w, base + 3), ka, kb);
    }
    int myout = 0;
    #pragma unroll 1
    for (int it = 0; it < 20; ++it) {
        unsigned long long wk = ka;
        #pragma unroll
        for (int d = 32; d; d >>= 1) {
            unsigned long long o = __shfl_xor(wk, d);
            wk = (o > wk) ? o : wk;
        }
        if (lane == it) myout = 2047 - (int)(wk & 0xFFFFFFFFull);
        if (ka == wk) { ka = kb; kb = 0ULL; }
        if (ka == 0ULL) {                // rare: re-read row with k < wk filter
            kb = 0ULL;
            #pragma unroll 1
            for (int s = 0; s < 8; ++s) {
                int base = s * 256 + lane * 4;
                float4 v4 = *(const float4*)&row[base];
                unsigned long long k0 = pkey(v4.x, base + 0);
                if (k0 < wk) top2k_upd(k0, ka, kb);
                unsigned long long k1 = pkey(v4.y, base + 1);
                if (k1 < wk) top2k_upd(k1, ka, kb);
                unsigned long long k2 = pkey(v4.z, base + 2);
                if (k2 < wk) top2k_upd(k2, ka, kb);
                unsigned long long k3 = pkey(v4.w, base + 3);
                if (k3 < wk) top2k_upd(k3, ka, kb);
            }
        }
    }
    if (lane < 20) idx[((size_t)(b0 + bb) * NN + r) * KK + lane] = myout;
}

// ---------------------------------------------------------------------------
// EdgeConv via A/B decomposition:
//   h[n,k,o] = A[n][o] + B[idx[n][k]][o];  max_k commutes with + (monotone).
// ---------------------------------------------------------------------------
__global__ __launch_bounds__(256) void ab1_k(const float* __restrict__ x,
        const double* __restrict__ wd2, double* __restrict__ Ad,
        double* __restrict__ Bd) {
    int tid = threadIdx.x, lane = tid & 63, w = tid >> 6;
    int p = blockIdx.x * 4 + w, b = p >> 11, n = p & 2047;
    const float* xb = x + (size_t)b * 3 * NN;
    double c0 = (double)xb[n], c1 = (double)xb[NN + n], c2 = (double)xb[2 * NN + n];
    double A = wd2[384 + lane];
    A = fma(wd2[192 + 0 * 64 + lane], c0, A);
    A = fma(wd2[192 + 1 * 64 + lane], c1, A);
    A = fma(wd2[192 + 2 * 64 + lane], c2, A);
    double B = wd2[0 * 64 + lane] * c0;
    B = fma(wd2[1 * 64 + lane], c1, B);
    B = fma(wd2[2 * 64 + lane], c2, B);
    Ad[(size_t)p * 64 + lane] = A;
    Bd[(size_t)p * 64 + lane] = B;
}

// conv2/conv3 A/B: block = 4 waves x 16 points. W (main) staged in LDS;
// Wd (delta) read from global (L1/L2-hot).
__global__ __launch_bounds__(256) void ab23_k(const float* __restrict__ x123t,
        const double* __restrict__ wd2, int coff, int woffW, int woffWd, int goff,
        double* __restrict__ Ad, double* __restrict__ Bd) {
    __shared__ double Ws[4096];      // 32 KB
    __shared__ double ctr[4][64];    // 2 KB
    int tid = threadIdx.x, lane = tid & 63, w = tid >> 6;
    for (int i = tid; i < 4096; i += 256) Ws[i] = wd2[woffW + i];
    __syncthreads();
    int p0 = blockIdx.x * 64 + w * 16;
    #pragma unroll 1
    for (int it = 0; it < 16; ++it) {
        int p = p0 + it, b = p >> 11, n = p & 2047;
        ctr[w][lane] = (double)x123t[((size_t)b * NN + n) * 192 + coff + lane];
        double a0 = wd2[goff + lane], a1 = 0, a2 = 0, a3 = 0;
        double q0 = 0, q1 = 0, q2 = 0, q3 = 0;
        #pragma unroll
        for (int c = 0; c < 64; c += 4) {
            double x0 = ctr[w][c + 0], x1 = ctr[w][c + 1];
            double x2 = ctr[w][c + 2], x3 = ctr[w][c + 3];
            a0 = fma(wd2[woffWd + (c + 0) * 64 + lane], x0, a0);
            a1 = fma(wd2[woffWd + (c + 1) * 64 + lane], x1, a1);
            a2 = fma(wd2[woffWd + (c + 2) * 64 + lane], x2, a2);
            a3 = fma(wd2[woffWd + (c + 3) * 64 + lane], x3, a3);
            q0 = fma(Ws[(c + 0) * 64 + lane], x0, q0);
            q1 = fma(Ws[(c + 1) * 64 + lane], x1, q1);
            q2 = fma(Ws[(c + 2) * 64 + lane], x2, q2);
            q3 = fma(Ws[(c + 3) * 64 + lane], x3, q3);
        }
        Ad[(size_t)p * 64 + lane] = (a0 + a1) + (a2 + a3);
        Bd[(size_t)p * 64 + lane] = (q0 + q1) + (q2 + q3);
    }
}

__global__ __launch_bounds__(256) void gmax_k(const double* __restrict__ Ad,
        const double* __restrict__ Bd, const int* __restrict__ idxb, int cho,
        float* __restrict__ dout, float* __restrict__ x123t_o) {
    int tid = threadIdx.x, lane = tid & 63, w = tid >> 6;
    int p = blockIdx.x * 4 + w, b = p >> 11, n = p & 2047;
    const int* ip = idxb + (size_t)p * KK;
    size_t boff = (size_t)(b << 11);
    double m = DNEG;
    int nbc = ip[0];
    double v = Bd[(boff + nbc) * 64 + lane];
    #pragma unroll 1
    for (int kk = 0; kk < KK; ++kk) {
        double cur = v;
        if (kk < KK - 1) {
            int nbn = ip[kk + 1];
            v = Bd[(boff + nbn) * 64 + lane];
        }
        m = fmax(m, cur);
    }
    double out = Ad[(size_t)p * 64 + lane] + m;
    dout[((size_t)b * 192 + cho + lane) * NN + n] = (float)out;
    x123t_o[((size_t)b * NN + n) * 192 + cho + lane] = (float)out;
}

// ---------------------------------------------------------------------------
// Final conv1d (1024x192) as LDS-tiled f32 GEMM, 64o x 128n per block, KC=32.
// Thread tile 4o x 8n: 32 FMA per 3 LDS b128 reads. XOR-swizzled LDS.
// ---------------------------------------------------------------------------
#define KC 32
__global__ __launch_bounds__(256) void w6_k(const float* __restrict__ x123t,
                                            const float* __restrict__ w6,
                                            float* __restrict__ partial6) {
    __shared__ float xs[KC][136];   // 128 n + pad (stride mod 32 = 8)
    __shared__ float wsb[KC][68];   // 64 o + pad (stride mod 32 = 4)
    __shared__ float red[64][17];
    int tid = threadIdx.x;
    int ntile = blockIdx.x & 15, ot = (blockIdx.x >> 4) & 15, b = blockIdx.x >> 8;
    int n0 = ntile * 128, o0 = ot * 64;
    int ln2 = tid >> 1, lc2 = (tid & 1) * 16;   // x: 128 rows(n) x 16 c each
    int lw = tid >> 2, lcw = (tid & 3) * 8;     // w: 64 rows(o) x 8 c each
    const float* xrow = x123t + ((size_t)b * NN + n0 + ln2) * 192 + lc2;
    const float* wrow = w6 + (size_t)(o0 + lw) * 192 + lcw;
    float acc[4][8];
    #pragma unroll
    for (int i = 0; i < 4; ++i)
        #pragma unroll
        for (int j = 0; j < 8; ++j) acc[i][j] = 0.f;
    int to = tid & 15, tn = tid >> 4;   // o = o0+to*4+i, n = n0+tn*8+j
    for (int cc = 0; cc < 192; cc += KC) {
        float4 xa = *(const float4*)(xrow + cc);
        float4 xb4 = *(const float4*)(xrow + cc + 4);
        float4 xc4 = *(const float4*)(xrow + cc + 8);
        float4 xd4 = *(const float4*)(xrow + cc + 12);
        float4 wa = *(const float4*)(wrow + cc);
        float4 wb4 = *(const float4*)(wrow + cc + 4);
        __syncthreads();
        {
            float v[16] = {xa.x, xa.y, xa.z, xa.w, xb4.x, xb4.y, xb4.z, xb4.w,
                           xc4.x, xc4.y, xc4.z, xc4.w, xd4.x, xd4.y, xd4.z, xd4.w};
            #pragma unroll
            for (int q = 0; q < 16; ++q) {
                int row = lc2 + q;
                xs[row][ln2 ^ (row & 24)] = v[q];
            }
        }
        {
            float v[8] = {wa.x, wa.y, wa.z, wa.w, wb4.x, wb4.y, wb4.z, wb4.w};
            #pragma unroll
            for (int q = 0; q < 8; ++q) {
                int row = lcw + q;
                wsb[row][lw ^ (row & 24)] = v[q];
            }
        }
        __syncthreads();
        #pragma unroll
        for (int k = 0; k < KC; ++k) {
            int kx = k & 24;
            float4 wv = *(const float4*)&wsb[k][(to * 4) ^ kx];
            float4 xv1 = *(const float4*)&xs[k][(tn * 8) ^ kx];
            float4 xv2 = *(const float4*)&xs[k][((tn * 8) ^ kx) + 4];
            float wr[4] = {wv.x, wv.y, wv.z, wv.w};
            float xr[8] = {xv1.x, xv1.y, xv1.z, xv1.w,
                           xv2.x, xv2.y, xv2.z, xv2.w};
            #pragma unroll
            for (int i = 0; i < 4; ++i)
                #pragma unroll
                for (int j = 0; j < 8; ++j)
                    acc[i][j] = fmaf(wr[i], xr[j], acc[i][j]);
        }
    }
    #pragma unroll
    for (int i = 0; i < 4; ++i) {
        float m0 = fmaxf(fmaxf(acc[i][0], acc[i][1]), fmaxf(acc[i][2], acc[i][3]));
        float m1 = fmaxf(fmaxf(acc[i][4], acc[i][5]), fmaxf(acc[i][6], acc[i][7]));
        red[to * 4 + i][tn] = fmaxf(m0, m1);
    }
    __syncthreads();
    if (tid < 64) {
        float mm = red[tid][0];
        #pragma unroll
        for (int t = 1; t < 16; ++t) mm = fmaxf(mm, red[tid][t]);
        partial6[((size_t)b * 1024 + o0 + tid) * 16 + ntile] = mm;
    }
}

__global__ void final_k(const float* __restrict__ partial6, const float* __restrict__ b6,
                        float* __restrict__ dout) {
    int t = blockIdx.x * 256 + threadIdx.x;  // < 16*1024
    int o = t & 1023;
    float m = NEG_INF;
    #pragma unroll 1
    for (int nt = 0; nt < 16; ++nt) m = fmaxf(m, partial6[(size_t)t * 16 + nt]);
    dout[(size_t)BB * 192 * NN + t] = m + b6[o];
}

// ---------------------------------------------------------------------------
extern "C" void kernel_launch(void* const* d_in, const int* in_sizes, int n_in,
                              void* d_out_, int out_size, void* d_ws, size_t ws_size,
                              hipStream_t stream) {
    (void)in_sizes; (void)n_in; (void)out_size;
    const float* x  = (const float*)d_in[0];
    const float* w1 = (const float*)d_in[1];
    const float* b1 = (const float*)d_in[2];
    const float* w2 = (const float*)d_in[3];
    const float* b2 = (const float*)d_in[4];
    const float* w3 = (const float*)d_in[5];
    const float* b3 = (const float*)d_in[6];
    const float* w4 = (const float*)d_in[7];
    const float* b4 = (const float*)d_in[8];
    const float* w5 = (const float*)d_in[9];
    const float* b5 = (const float*)d_in[10];
    const float* w6 = (const float*)d_in[11];
    const float* b6 = (const float*)d_in[12];
    float* dout = (float*)d_out_;

    char* ws = (char*)d_ws;
    float*  x123t    = (float*)(ws + 0);           // 25,165,824 B
    int*    idxb     = (int*)(ws + 25165824);      //  2,621,440 B
    float*  nrm      = (float*)(ws + 27787264);    //    131,072 B
    float*  partial6 = (float*)(ws + 27918336);    //  2,097,152 B
    double* wd2      = (double*)(ws + 30015488);   //    135,680 B
    // region: pd (nb x 16MB) OR Ad+Bd (16MB each). Never live together.
    char*   region   = ws + 30151168;
    float*  pd = (float*)region;
    double* Ad = (double*)region;
    double* Bd = (double*)(region + 16777216);
    long long avail = (long long)ws_size - 30151168LL;
    int nb = (int)(avail / 16777216LL);
    if (nb < 2) nb = 2;    // Ad/Bd require 32MB; >=64MB proven available
    if (nb > 8) nb = 8;

    prep_cmp<<<1, 256, 0, stream>>>(w1, b1, w2, b2, w3, b3, w4, b4, w5, b5, wd2);

    // ---- block 1 ----
    norms1_k<<<128, 256, 0, stream>>>(x, nrm);
    knn1_k<<<dim3(512, BB), 256, 0, stream>>>(x, nrm, idxb);
    ab1_k<<<8192, 256, 0, stream>>>(x, wd2, Ad, Bd);
    gmax_k<<<8192, 256, 0, stream>>>(Ad, Bd, idxb, 0, dout, x123t);

    // ---- knn on x1 (tiled GEMM + select, frozen arithmetic) ----
    norms23_k<<<128, 256, 0, stream>>>(x123t, 0, nrm);
    for (int b0 = 0; b0 < BB; b0 += nb) {
        int cur = (BB - b0 < nb) ? (BB - b0) : nb;
        gemm_pd_k<<<dim3(32, 32, cur), 256, 0, stream>>>(dout, 0, nrm, pd, b0);
        select_k<<<dim3(512, cur), 256, 0, stream>>>(pd, idxb, b0);
    }
    // ---- block 2 (A/B overwrite pd region; pd dead after select) ----
    ab23_k<<<512, 256, 0, stream>>>(x123t, wd2, 0, 448, 4544, 8640, Ad, Bd);
    gmax_k<<<8192, 256, 0, stream>>>(Ad, Bd, idxb, 64, dout, x123t);

    // ---- knn on x2 ----
    norms23_k<<<128, 256, 0, stream>>>(x123t, 64, nrm);
    for (int b0 = 0; b0 < BB; b0 += nb) {
        int cur = (BB - b0 < nb) ? (BB - b0) : nb;
        gemm_pd_k<<<dim3(32, 32, cur), 256, 0, stream>>>(dout, 64, nrm, pd, b0);
        select_k<<<dim3(512, cur), 256, 0, stream>>>(pd, idxb, b0);
    }
    // ---- block 3 ----
    ab23_k<<<512, 256, 0, stream>>>(x123t, wd2, 64, 8704, 12800, 16896, Ad, Bd);
    gmax_k<<<8192, 256, 0, stream>>>(Ad, Bd, idxb, 128, dout, x123t);

    // ---- final conv1d + global max ----
    w6_k<<<4096, 256, 0, stream>>>(x123t, w6, partial6);
    final_k<<<64, 256, 0, stream>>>(partial6, b6, dout);
}

// Round 23
// 1222.998 us; speedup vs baseline: 1.5603x; 1.0087x over previous
//
#include <hip/hip_runtime.h>

// Problem constants
#define BB 16
#define NN 2048
#define KK 20

#define NEG_INF (-3.402823466e+38f)
#define DNEG (-1.0e300)

// ---------------------------------------------------------------------------
// Composed fp64 weights (layout in wd2, doubles):
//  M1[3][64]@0   Md1[3][64]@192 (=Mh1-M1)   g01[64]@384
//  M2[64][64]@448   Md2[64][64]@4544 (=Mh2-M2)   g02[64]@8640
//  W5[64][64]@8704 (=w5lo[c][o])  W5d[64][64]@12800 (=w5hi-w5lo)  b5d[64]@16896
// ---------------------------------------------------------------------------
__global__ void prep_cmp(const float* __restrict__ w1, const float* __restrict__ b1,
                         const float* __restrict__ w2, const float* __restrict__ b2,
                         const float* __restrict__ w3, const float* __restrict__ b3,
                         const float* __restrict__ w4, const float* __restrict__ b4,
                         const float* __restrict__ w5, const float* __restrict__ b5,
                         double* __restrict__ wd2) {
    int t = threadIdx.x;
    for (int i = t; i < 192; i += 256) {
        int c = i >> 6, o = i & 63;
        double s = 0, sh = 0;
        for (int j = 0; j < 64; ++j) {
            double w2v = (double)w2[o * 64 + j];
            s  = fma(w2v, (double)w1[j * 6 + c], s);
            sh = fma(w2v, (double)w1[j * 6 + 3 + c], sh);
        }
        wd2[i] = s;
        wd2[192 + i] = sh - s;
    }
    for (int i = t; i < 64; i += 256) {
        double s = (double)b2[i];
        for (int j = 0; j < 64; ++j)
            s = fma((double)w2[i * 64 + j], (double)b1[j], s);
        wd2[384 + i] = s;
        double s2 = (double)b4[i];
        for (int j = 0; j < 64; ++j)
            s2 = fma((double)w4[i * 64 + j], (double)b3[j], s2);
        wd2[8640 + i] = s2;
        wd2[16896 + i] = (double)b5[i];
    }
    for (int i = t; i < 4096; i += 256) {
        int c = i >> 6, o = i & 63;
        double s = 0, sh = 0;
        for (int j = 0; j < 64; ++j) {
            double w4v = (double)w4[o * 64 + j];
            s  = fma(w4v, (double)w3[j * 128 + c], s);
            sh = fma(w4v, (double)w3[j * 128 + 64 + c], sh);
        }
        wd2[448 + i] = s;         // M2[c][o]
        wd2[4544 + i] = sh - s;   // Md2[c][o]
        double lo = (double)w5[o * 128 + c];
        wd2[8704 + i] = lo;                                  // W5[c][o]
        wd2[12800 + i] = (double)w5[o * 128 + 64 + c] - lo;  // W5d[c][o]
    }
}

// ---------------------------------------------------------------------------
// Packed-key top-20 selection. key = (orderable(value) << 32) | (2047 - col).
// Winners pop in strictly decreasing key order -> popped set == {k >= wk}.
// Rescan rebuilds lane top-2 from ORIGINAL candidates filtered by k < wk.
// ---------------------------------------------------------------------------
__device__ __forceinline__ unsigned long long pkey(float v, int col) {
    float vc = __fadd_rn(v, 0.0f);   // -0 -> +0 (real instruction)
    unsigned u = __float_as_uint(vc);
    unsigned s = (unsigned)((int)u >> 31);
    unsigned m = u ^ (s | 0x80000000u);
    return ((unsigned long long)m << 32) | (unsigned)(2047 - col);
}

__device__ __forceinline__ void top2k_upd(unsigned long long k,
        unsigned long long& ka, unsigned long long& kb) {
    bool gta = k > ka;
    bool gtb = k > kb;
    unsigned long long nkb = gta ? ka : (gtb ? k : kb);
    ka = gta ? k : ka;
    kb = nkb;
}

// ---------------------------------------------------------------------------
// xx for raw x (C=3): FROZEN chain fadd(fadd(mul,mul),mul).
// ---------------------------------------------------------------------------
__global__ void norms1_k(const float* __restrict__ x, float* __restrict__ nrm) {
    int t = blockIdx.x * 256 + threadIdx.x;   // 32768 points
    int b = t >> 11, n = t & 2047;
    const float* xb = x + (size_t)b * 3 * NN;
    float cx = xb[n], cy = xb[NN + n], cz = xb[2 * NN + n];
    nrm[t] = __fadd_rn(__fadd_rn(__fmul_rn(cx, cx), __fmul_rn(cy, cy)),
                       __fmul_rn(cz, cz));
}

// knn1: numpy-f32 mirror, FROZEN per-col distance arithmetic; float4 scan
// fully unrolled (scheduling only; values bit-identical); LDS-free extraction.
__global__ __launch_bounds__(256) void knn1_k(const float* __restrict__ x,
        const float* __restrict__ nrm, int* __restrict__ idx) {
    int lane = threadIdx.x & 63, w = threadIdx.x >> 6;
    int b = blockIdx.y, r = blockIdx.x * 4 + w;
    const float* xb = x + (size_t)b * 3 * NN;
    const float* nb_ = nrm + (size_t)b * NN;
    float rx = xb[r], ry = xb[NN + r], rz = xb[2 * NN + r];
    float xxi = nb_[r];
    unsigned long long ka = 0ULL, kb = 0ULL;
    #pragma unroll
    for (int s = 0; s < 8; ++s) {
        int base = s * 256 + lane * 4;
        float4 cx = *(const float4*)&xb[base];
        float4 cy = *(const float4*)&xb[NN + base];
        float4 cz = *(const float4*)&xb[2 * NN + base];
        float4 xx4 = *(const float4*)&nb_[base];
        {   // col base+0  (frozen chain)
            float dot = fmaf(rz, cz.x, fmaf(ry, cy.x, __fmul_rn(rx, cx.x)));
            float inner = __fmul_rn(-2.f, dot);
            float t1 = __fsub_rn(-xx4.x, inner);
            top2k_upd(pkey(__fsub_rn(t1, xxi), base + 0), ka, kb);
        }
        {   // col base+1
            float dot = fmaf(rz, cz.y, fmaf(ry, cy.y, __fmul_rn(rx, cx.y)));
            float inner = __fmul_rn(-2.f, dot);
            float t1 = __fsub_rn(-xx4.y, inner);
            top2k_upd(pkey(__fsub_rn(t1, xxi), base + 1), ka, kb);
        }
        {   // col base+2
            float dot = fmaf(rz, cz.z, fmaf(ry, cy.z, __fmul_rn(rx, cx.z)));
            float inner = __fmul_rn(-2.f, dot);
            float t1 = __fsub_rn(-xx4.z, inner);
            top2k_upd(pkey(__fsub_rn(t1, xxi), base + 2), ka, kb);
        }
        {   // col base+3
            float dot = fmaf(rz, cz.w, fmaf(ry, cy.w, __fmul_rn(rx, cx.w)));
            float inner = __fmul_rn(-2.f, dot);
            float t1 = __fsub_rn(-xx4.w, inner);
            top2k_upd(pkey(__fsub_rn(t1, xxi), base + 3), ka, kb);
        }
    }
    // extraction: 20 stable global maxima; rescan recomputes frozen chain
    int myout = 0;
    #pragma unroll 1
    for (int it = 0; it < 20; ++it) {
        unsigned long long wk = ka;
        #pragma unroll
        for (int d = 32; d; d >>= 1) {
            unsigned long long o = __shfl_xor(wk, d);
            wk = (o > wk) ? o : wk;
        }
        if (lane == it) myout = 2047 - (int)(wk & 0xFFFFFFFFull);
        if (ka == wk) { ka = kb; kb = 0ULL; }
        if (ka == 0ULL) {                // rare: lane's top-2 exhausted
            kb = 0ULL;
            #pragma unroll 1
            for (int s = 0; s < 8; ++s) {
                int base = s * 256 + lane * 4;
                float4 cx = *(const float4*)&xb[base];
                float4 cy = *(const float4*)&xb[NN + base];
                float4 cz = *(const float4*)&xb[2 * NN + base];
                float4 xx4 = *(const float4*)&nb_[base];
                {
                    float dot = fmaf(rz, cz.x, fmaf(ry, cy.x, __fmul_rn(rx, cx.x)));
                    float inner = __fmul_rn(-2.f, dot);
                    float t1 = __fsub_rn(-xx4.x, inner);
                    unsigned long long k = pkey(__fsub_rn(t1, xxi), base + 0);
                    if (k < wk) top2k_upd(k, ka, kb);
                }
                {
                    float dot = fmaf(rz, cz.y, fmaf(ry, cy.y, __fmul_rn(rx, cx.y)));
                    float inner = __fmul_rn(-2.f, dot);
                    float t1 = __fsub_rn(-xx4.y, inner);
                    unsigned long long k = pkey(__fsub_rn(t1, xxi), base + 1);
                    if (k < wk) top2k_upd(k, ka, kb);
                }
                {
                    float dot = fmaf(rz, cz.z, fmaf(ry, cy.z, __fmul_rn(rx, cx.z)));
                    float inner = __fmul_rn(-2.f, dot);
                    float t1 = __fsub_rn(-xx4.z, inner);
                    unsigned long long k = pkey(__fsub_rn(t1, xxi), base + 2);
                    if (k < wk) top2k_upd(k, ka, kb);
                }
                {
                    float dot = fmaf(rz, cz.w, fmaf(ry, cy.w, __fmul_rn(rx, cx.w)));
                    float inner = __fmul_rn(-2.f, dot);
                    float t1 = __fsub_rn(-xx4.w, inner);
                    unsigned long long k = pkey(__fsub_rn(t1, xxi), base + 3);
                    if (k < wk) top2k_upd(k, ka, kb);
                }
            }
        }
    }
    if (lane < 20) idx[((size_t)b * NN + r) * KK + lane] = myout;
}

// xx for a 64-channel slice. FROZEN sequential ascending-c chain; float4 loads.
__global__ void norms23_k(const float* __restrict__ x123t, int coff,
                          float* __restrict__ nrm) {
    int t = blockIdx.x * 256 + threadIdx.x;   // 32768 points
    const float* r = x123t + (size_t)t * 192 + coff;
    float acc = 0.f;
    #pragma unroll 1
    for (int c = 0; c < 64; c += 4) {
        float4 q = *(const float4*)(r + c);
        acc = __fadd_rn(acc, __fmul_rn(q.x, q.x));
        acc = __fadd_rn(acc, __fmul_rn(q.y, q.y));
        acc = __fadd_rn(acc, __fmul_rn(q.z, q.z));
        acc = __fadd_rn(acc, __fmul_rn(q.w, q.w));
    }
    nrm[t] = acc;
}

// ---------------------------------------------------------------------------
// pd GEMM (knn2/3 distances). FROZEN chain + epilogue.
// ---------------------------------------------------------------------------
__global__ __launch_bounds__(256) void gemm_pd_k(const float* __restrict__ dout,
        int coff, const float* __restrict__ nrm, float* __restrict__ pd, int b0) {
    __shared__ float As[64][68];
    __shared__ float Bs[64][68];
    int b = b0 + blockIdx.z;
    int rb = blockIdx.y * 64, cb = blockIdx.x * 64;
    const float* doutc = dout + (size_t)(b * 192 + coff) * NN;
    int tid = threadIdx.x;
    int cq = tid >> 4, qd = (tid & 15) * 4;
    #pragma unroll
    for (int cc = 0; cc < 64; cc += 16) {
        float4 a = *(const float4*)(doutc + (size_t)(cc + cq) * NN + rb + qd);
        As[cc + cq][qd + 0] = a.x; As[cc + cq][qd + 1] = a.y;
        As[cc + cq][qd + 2] = a.z; As[cc + cq][qd + 3] = a.w;
        float4 bv = *(const float4*)(doutc + (size_t)(cc + cq) * NN + cb + qd);
        Bs[cc + cq][qd + 0] = bv.x; Bs[cc + cq][qd + 1] = bv.y;
        Bs[cc + cq][qd + 2] = bv.z; Bs[cc + cq][qd + 3] = bv.w;
    }
    __syncthreads();
    int tx = tid & 15, ty = tid >> 4;
    float acc[4][4];
    #pragma unroll
    for (int i = 0; i < 4; ++i)
        #pragma unroll
        for (int j = 0; j < 4; ++j) acc[i][j] = 0.f;
    #pragma unroll 4
    for (int c = 0; c < 64; ++c) {
        float4 av4 = *(const float4*)&As[c][ty * 4];
        float4 bv4 = *(const float4*)&Bs[c][tx * 4];
        float aa[4] = {av4.x, av4.y, av4.z, av4.w};
        float bb[4] = {bv4.x, bv4.y, bv4.z, bv4.w};
        #pragma unroll
        for (int i = 0; i < 4; ++i)
            #pragma unroll
            for (int j = 0; j < 4; ++j)
                acc[i][j] = fmaf(aa[i], bb[j], acc[i][j]);  // ascending-c chain
    }
    const float* nb_ = nrm + (size_t)b * NN;
    #pragma unroll
    for (int i = 0; i < 4; ++i) {
        int r = rb + ty * 4 + i;
        float xxi = nb_[r];
        float4 o4;
        float* o = (float*)&o4;
        #pragma unroll
        for (int j = 0; j < 4; ++j) {
            float xxj = nb_[cb + tx * 4 + j];
            float inner = __fmul_rn(-2.f, acc[i][j]);
            float t1 = __fsub_rn(-xxj, inner);
            o[j] = __fsub_rn(t1, xxi);
        }
        *(float4*)(pd + ((size_t)blockIdx.z * NN + r) * NN + cb + tx * 4) = o4;
    }
}

// selection from materialized pd chunk: LDS-free, global re-read rescan;
// scan fully unrolled (scheduling only).
__global__ __launch_bounds__(256) void select_k(const float* __restrict__ pd,
        int* __restrict__ idx, int b0) {
    int lane = threadIdx.x & 63, w = threadIdx.x >> 6;
    int bb = blockIdx.y, r = blockIdx.x * 4 + w;
    const float* row = pd + ((size_t)bb * NN + r) * NN;
    unsigned long long ka = 0ULL, kb = 0ULL;
    #pragma unroll
    for (int s = 0; s < 8; ++s) {
        int base = s * 256 + lane * 4;
        float4 v4 = *(const float4*)&row[base];
        top2k_upd(pkey(v4.x, base + 0), ka, kb);
        top2k_upd(pkey(v4.y, base + 1), ka, kb);
        top2k_upd(pkey(v4.z, base + 2), ka, kb);
        top2k_upd(pkey(v4.w, base + 3), ka, kb);
    }
    int myout = 0;
    #pragma unroll 1
    for (int it = 0; it < 20; ++it) {
        unsigned long long wk = ka;
        #pragma unroll
        for (int d = 32; d; d >>= 1) {
            unsigned long long o = __shfl_xor(wk, d);
            wk = (o > wk) ? o : wk;
        }
        if (lane == it) myout = 2047 - (int)(wk & 0xFFFFFFFFull);
        if (ka == wk) { ka = kb; kb = 0ULL; }
        if (ka == 0ULL) {                // rare: re-read row with k < wk filter
            kb = 0ULL;
            #pragma unroll 1
            for (int s = 0; s < 8; ++s) {
                int base = s * 256 + lane * 4;
                float4 v4 = *(const float4*)&row[base];
                unsigned long long k0 = pkey(v4.x, base + 0);
                if (k0 < wk) top2k_upd(k0, ka, kb);
                unsigned long long k1 = pkey(v4.y, base + 1);
                if (k1 < wk) top2k_upd(k1, ka, kb);
                unsigned long long k2 = pkey(v4.z, base + 2);
                if (k2 < wk) top2k_upd(k2, ka, kb);
                unsigned long long k3 = pkey(v4.w, base + 3);
                if (k3 < wk) top2k_upd(k3, ka, kb);
            }
        }
    }
    if (lane < 20) idx[((size_t)(b0 + bb) * NN + r) * KK + lane] = myout;
}

// ---------------------------------------------------------------------------
// EdgeConv via A/B decomposition:
//   h[n,k,o] = A[n][o] + B[idx[n][k]][o];  max_k commutes with + (monotone).
// ---------------------------------------------------------------------------
__global__ __launch_bounds__(256) void ab1_k(const float* __restrict__ x,
        const double* __restrict__ wd2, double* __restrict__ Ad,
        double* __restrict__ Bd) {
    int tid = threadIdx.x, lane = tid & 63, w = tid >> 6;
    int p = blockIdx.x * 4 + w, b = p >> 11, n = p & 2047;
    const float* xb = x + (size_t)b * 3 * NN;
    double c0 = (double)xb[n], c1 = (double)xb[NN + n], c2 = (double)xb[2 * NN + n];
    double A = wd2[384 + lane];
    A = fma(wd2[192 + 0 * 64 + lane], c0, A);
    A = fma(wd2[192 + 1 * 64 + lane], c1, A);
    A = fma(wd2[192 + 2 * 64 + lane], c2, A);
    double B = wd2[0 * 64 + lane] * c0;
    B = fma(wd2[1 * 64 + lane], c1, B);
    B = fma(wd2[2 * 64 + lane], c2, B);
    Ad[(size_t)p * 64 + lane] = A;
    Bd[(size_t)p * 64 + lane] = B;
}

// conv2/conv3 A/B: block = 4 waves x 16 points. W (main) staged in LDS;
// Wd (delta) read from global (L1/L2-hot).
__global__ __launch_bounds__(256) void ab23_k(const float* __restrict__ x123t,
        const double* __restrict__ wd2, int coff, int woffW, int woffWd, int goff,
        double* __restrict__ Ad, double* __restrict__ Bd) {
    __shared__ double Ws[4096];      // 32 KB
    __shared__ double ctr[4][64];    // 2 KB
    int tid = threadIdx.x, lane = tid & 63, w = tid >> 6;
    for (int i = tid; i < 4096; i += 256) Ws[i] = wd2[woffW + i];
    __syncthreads();
    int p0 = blockIdx.x * 64 + w * 16;
    #pragma unroll 1
    for (int it = 0; it < 16; ++it) {
        int p = p0 + it, b = p >> 11, n = p & 2047;
        ctr[w][lane] = (double)x123t[((size_t)b * NN + n) * 192 + coff + lane];
        double a0 = wd2[goff + lane], a1 = 0, a2 = 0, a3 = 0;
        double q0 = 0, q1 = 0, q2 = 0, q3 = 0;
        #pragma unroll
        for (int c = 0; c < 64; c += 4) {
            double x0 = ctr[w][c + 0], x1 = ctr[w][c + 1];
            double x2 = ctr[w][c + 2], x3 = ctr[w][c + 3];
            a0 = fma(wd2[woffWd + (c + 0) * 64 + lane], x0, a0);
            a1 = fma(wd2[woffWd + (c + 1) * 64 + lane], x1, a1);
            a2 = fma(wd2[woffWd + (c + 2) * 64 + lane], x2, a2);
            a3 = fma(wd2[woffWd + (c + 3) * 64 + lane], x3, a3);
            q0 = fma(Ws[(c + 0) * 64 + lane], x0, q0);
            q1 = fma(Ws[(c + 1) * 64 + lane], x1, q1);
            q2 = fma(Ws[(c + 2) * 64 + lane], x2, q2);
            q3 = fma(Ws[(c + 3) * 64 + lane], x3, q3);
        }
        Ad[(size_t)p * 64 + lane] = (a0 + a1) + (a2 + a3);
        Bd[(size_t)p * 64 + lane] = (q0 + q1) + (q2 + q3);
    }
}

__global__ __launch_bounds__(256) void gmax_k(const double* __restrict__ Ad,
        const double* __restrict__ Bd, const int* __restrict__ idxb, int cho,
        float* __restrict__ dout, float* __restrict__ x123t_o) {
    int tid = threadIdx.x, lane = tid & 63, w = tid >> 6;
    int p = blockIdx.x * 4 + w, b = p >> 11, n = p & 2047;
    const int* ip = idxb + (size_t)p * KK;
    size_t boff = (size_t)(b << 11);
    double m = DNEG;
    int nbc = ip[0];
    double v = Bd[(boff + nbc) * 64 + lane];
    #pragma unroll 1
    for (int kk = 0; kk < KK; ++kk) {
        double cur = v;
        if (kk < KK - 1) {
            int nbn = ip[kk + 1];
            v = Bd[(boff + nbn) * 64 + lane];
        }
        m = fmax(m, cur);
    }
    double out = Ad[(size_t)p * 64 + lane] + m;
    dout[((size_t)b * 192 + cho + lane) * NN + n] = (float)out;
    x123t_o[((size_t)b * NN + n) * 192 + cho + lane] = (float)out;
}

// ---------------------------------------------------------------------------
// Final conv1d (1024x192) as LDS-tiled f32 GEMM, 64o x 128n per block, KC=32.
// Thread tile 4o x 8n: 32 FMA per 3 LDS b128 reads. XOR-swizzled LDS.
// ---------------------------------------------------------------------------
#define KC 32
__global__ __launch_bounds__(256) void w6_k(const float* __restrict__ x123t,
                                            const float* __restrict__ w6,
                                            float* __restrict__ partial6) {
    __shared__ float xs[KC][136];   // 128 n + pad (stride mod 32 = 8)
    __shared__ float wsb[KC][68];   // 64 o + pad (stride mod 32 = 4)
    __shared__ float red[64][17];
    int tid = threadIdx.x;
    int ntile = blockIdx.x & 15, ot = (blockIdx.x >> 4) & 15, b = blockIdx.x >> 8;
    int n0 = ntile * 128, o0 = ot * 64;
    int ln2 = tid >> 1, lc2 = (tid & 1) * 16;   // x: 128 rows(n) x 16 c each
    int lw = tid >> 2, lcw = (tid & 3) * 8;     // w: 64 rows(o) x 8 c each
    const float* xrow = x123t + ((size_t)b * NN + n0 + ln2) * 192 + lc2;
    const float* wrow = w6 + (size_t)(o0 + lw) * 192 + lcw;
    float acc[4][8];
    #pragma unroll
    for (int i = 0; i < 4; ++i)
        #pragma unroll
        for (int j = 0; j < 8; ++j) acc[i][j] = 0.f;
    int to = tid & 15, tn = tid >> 4;   // o = o0+to*4+i, n = n0+tn*8+j
    for (int cc = 0; cc < 192; cc += KC) {
        float4 xa = *(const float4*)(xrow + cc);
        float4 xb4 = *(const float4*)(xrow + cc + 4);
        float4 xc4 = *(const float4*)(xrow + cc + 8);
        float4 xd4 = *(const float4*)(xrow + cc + 12);
        float4 wa = *(const float4*)(wrow + cc);
        float4 wb4 = *(const float4*)(wrow + cc + 4);
        __syncthreads();
        {
            float v[16] = {xa.x, xa.y, xa.z, xa.w, xb4.x, xb4.y, xb4.z, xb4.w,
                           xc4.x, xc4.y, xc4.z, xc4.w, xd4.x, xd4.y, xd4.z, xd4.w};
            #pragma unroll
            for (int q = 0; q < 16; ++q) {
                int row = lc2 + q;
                xs[row][ln2 ^ (row & 24)] = v[q];
            }
        }
        {
            float v[8] = {wa.x, wa.y, wa.z, wa.w, wb4.x, wb4.y, wb4.z, wb4.w};
            #pragma unroll
            for (int q = 0; q < 8; ++q) {
                int row = lcw + q;
                wsb[row][lw ^ (row & 24)] = v[q];
            }
        }
        __syncthreads();
        #pragma unroll
        for (int k = 0; k < KC; ++k) {
            int kx = k & 24;
            float4 wv = *(const float4*)&wsb[k][(to * 4) ^ kx];
            float4 xv1 = *(const float4*)&xs[k][(tn * 8) ^ kx];
            float4 xv2 = *(const float4*)&xs[k][((tn * 8) ^ kx) + 4];
            float wr[4] = {wv.x, wv.y, wv.z, wv.w};
            float xr[8] = {xv1.x, xv1.y, xv1.z, xv1.w,
                           xv2.x, xv2.y, xv2.z, xv2.w};
            #pragma unroll
            for (int i = 0; i < 4; ++i)
                #pragma unroll
                for (int j = 0; j < 8; ++j)
                    acc[i][j] = fmaf(wr[i], xr[j], acc[i][j]);
        }
    }
    #pragma unroll
    for (int i = 0; i < 4; ++i) {
        float m0 = fmaxf(fmaxf(acc[i][0], acc[i][1]), fmaxf(acc[i][2], acc[i][3]));
        float m1 = fmaxf(fmaxf(acc[i][4], acc[i][5]), fmaxf(acc[i][6], acc[i][7]));
        red[to * 4 + i][tn] = fmaxf(m0, m1);
    }
    __syncthreads();
    if (tid < 64) {
        float mm = red[tid][0];
        #pragma unroll
        for (int t = 1; t < 16; ++t) mm = fmaxf(mm, red[tid][t]);
        partial6[((size_t)b * 1024 + o0 + tid) * 16 + ntile] = mm;
    }
}

__global__ void final_k(const float* __restrict__ partial6, const float* __restrict__ b6,
                        float* __restrict__ dout) {
    int t = blockIdx.x * 256 + threadIdx.x;  // < 16*1024
    int o = t & 1023;
    float m = NEG_INF;
    #pragma unroll 1
    for (int nt = 0; nt < 16; ++nt) m = fmaxf(m, partial6[(size_t)t * 16 + nt]);
    dout[(size_t)BB * 192 * NN + t] = m + b6[o];
}

// ---------------------------------------------------------------------------
extern "C" void kernel_launch(void* const* d_in, const int* in_sizes, int n_in,
                              void* d_out_, int out_size, void* d_ws, size_t ws_size,
                              hipStream_t stream) {
    (void)in_sizes; (void)n_in; (void)out_size;
    const float* x  = (const float*)d_in[0];
    const float* w1 = (const float*)d_in[1];
    const float* b1 = (const float*)d_in[2];
    const float* w2 = (const float*)d_in[3];
    const float* b2 = (const float*)d_in[4];
    const float* w3 = (const float*)d_in[5];
    const float* b3 = (const float*)d_in[6];
    const float* w4 = (const float*)d_in[7];
    const float* b4 = (const float*)d_in[8];
    const float* w5 = (const float*)d_in[9];
    const float* b5 = (const float*)d_in[10];
    const float* w6 = (const float*)d_in[11];
    const float* b6 = (const float*)d_in[12];
    float* dout = (float*)d_out_;

    char* ws = (char*)d_ws;
    float*  x123t    = (float*)(ws + 0);           // 25,165,824 B
    int*    idxb     = (int*)(ws + 25165824);      //  2,621,440 B
    float*  nrm      = (float*)(ws + 27787264);    //    131,072 B
    float*  partial6 = (float*)(ws + 27918336);    //  2,097,152 B
    double* wd2      = (double*)(ws + 30015488);   //    135,680 B
    // region: pd (nb x 16MB) OR Ad+Bd (16MB each). Never live together.
    char*   region   = ws + 30151168;
    float*  pd = (float*)region;
    double* Ad = (double*)region;
    double* Bd = (double*)(region + 16777216);
    long long avail = (long long)ws_size - 30151168LL;
    int nb = (int)(avail / 16777216LL);
    if (nb < 2) nb = 2;    // Ad/Bd require 32MB; >=64MB proven available
    if (nb > 8) nb = 8;

    prep_cmp<<<1, 256, 0, stream>>>(w1, b1, w2, b2, w3, b3, w4, b4, w5, b5, wd2);

    // ---- block 1 ----
    norms1_k<<<128, 256, 0, stream>>>(x, nrm);
    knn1_k<<<dim3(512, BB), 256, 0, stream>>>(x, nrm, idxb);
    ab1_k<<<8192, 256, 0, stream>>>(x, wd2, Ad, Bd);
    gmax_k<<<8192, 256, 0, stream>>>(Ad, Bd, idxb, 0, dout, x123t);

    // ---- knn on x1 (tiled GEMM + select, frozen arithmetic) ----
    norms23_k<<<128, 256, 0, stream>>>(x123t, 0, nrm);
    for (int b0 = 0; b0 < BB; b0 += nb) {
        int cur = (BB - b0 < nb) ? (BB - b0) : nb;
        gemm_pd_k<<<dim3(32, 32, cur), 256, 0, stream>>>(dout, 0, nrm, pd, b0);
        select_k<<<dim3(512, cur), 256, 0, stream>>>(pd, idxb, b0);
    }
    // ---- block 2 (A/B overwrite pd region; pd dead after select) ----
    ab23_k<<<512, 256, 0, stream>>>(x123t, wd2, 0, 448, 4544, 8640, Ad, Bd);
    gmax_k<<<8192, 256, 0, stream>>>(Ad, Bd, idxb, 64, dout, x123t);

    // ---- knn on x2 ----
    norms23_k<<<128, 256, 0, stream>>>(x123t, 64, nrm);
    for (int b0 = 0; b0 < BB; b0 += nb) {
        int cur = (BB - b0 < nb) ? (BB - b0) : nb;
        gemm_pd_k<<<dim3(32, 32, cur), 256, 0, stream>>>(dout, 64, nrm, pd, b0);
        select_k<<<dim3(512, cur), 256, 0, stream>>>(pd, idxb, b0);
    }
    // ---- block 3 ----
    ab23_k<<<512, 256, 0, stream>>>(x123t, wd2, 64, 8704, 12800, 16896, Ad, Bd);
    gmax_k<<<8192, 256, 0, stream>>>(Ad, Bd, idxb, 128, dout, x123t);

    // ---- final conv1d + global max ----
    w6_k<<<4096, 256, 0, stream>>>(x123t, w6, partial6);
    final_k<<<64, 256, 0, stream>>>(partial6, b6, dout);
}